// Round 6
// baseline (4616.148 us; speedup 1.0000x reference)
//
#include <hip/hip_runtime.h>
#include <hip/hip_bf16.h>

#define NN 50000
#define EE 400000
#define EPSF 1e-5f
#define NB 196   // (NN+255)/256

typedef unsigned short u16;
typedef __attribute__((ext_vector_type(8))) short bf16x8;
typedef __attribute__((ext_vector_type(4))) float f32x4;

__device__ __forceinline__ float b2f(u16 u) { return __uint_as_float(((unsigned)u) << 16); }
__device__ __forceinline__ u16 f2b(float f) {
  unsigned x = __float_as_uint(f);
  unsigned r = x + 0x7FFFu + ((x >> 16) & 1u);   // RNE
  return (u16)(r >> 16);
}
__device__ __forceinline__ unsigned pack2(float lo, float hi) {
  return (unsigned)f2b(lo) | ((unsigned)f2b(hi) << 16);
}
__device__ __forceinline__ void gl16(const void* g, void* l) {
  __builtin_amdgcn_global_load_lds(
      (const __attribute__((address_space(1))) void*)g,
      (__attribute__((address_space(3))) void*)l, 16, 0, 0);
}

// ---------------------------------------------------------------- conv_in
__global__ __launch_bounds__(256) void k_convin(
    const float* __restrict__ X, u16* __restrict__ out,
    const float* __restrict__ Wi, const float* __restrict__ bi)
{
  __shared__ float xs[1024];
  __shared__ float wi[16 * 33];
  const int tid = threadIdx.x;
  for (int idx = tid; idx < 512; idx += 256) {
    int co = idx >> 4, ci = idx & 15;
    wi[ci * 33 + co] = Wi[idx];
  }
  const long xbase = (long)blockIdx.x * 1024;
  ((float4*)xs)[tid] = ((const float4*)(X + xbase))[tid];
  __syncthreads();
  const int nl = tid >> 5, c = tid & 31;
  float acc[8];
  {
    float bc = bi[c];
#pragma unroll
    for (int t = 0; t < 8; ++t) acc[t] = bc;
  }
  const float* xrow = xs + (nl << 7);
  for (int ci = 0; ci < 16; ++ci) {
    float w = wi[ci * 33 + c];
    float4 xa = *(const float4*)(xrow + ci * 8);
    float4 xb = *(const float4*)(xrow + ci * 8 + 4);
    acc[0] += xa.x * w; acc[1] += xa.y * w; acc[2] += xa.z * w; acc[3] += xa.w * w;
    acc[4] += xb.x * w; acc[5] += xb.y * w; acc[6] += xb.z * w; acc[7] += xb.w * w;
  }
  uint4 o;
  o.x = pack2(acc[0], acc[1]); o.y = pack2(acc[2], acc[3]);
  o.z = pack2(acc[4], acc[5]); o.w = pack2(acc[6], acc[7]);
  *(uint4*)(out + (long)blockIdx.x * 2048 + tid * 8) = o;
}

// ---------------------------------------------------------------- degree / dinv
__global__ void k_deg(const int* __restrict__ dst, int* __restrict__ degi)
{
  int e = blockIdx.x * 256 + threadIdx.x;
  if (e < EE) atomicAdd(degi + dst[e], 1);
}
__global__ void k_dinv(const int* __restrict__ degi, float* __restrict__ dinv)
{
  int n = blockIdx.x * 256 + threadIdx.x;
  if (n < NN) dinv[n] = rsqrtf((float)degi[n] + 1.0f);
}

// ---------------------------------------------------------------- CSR build
__global__ __launch_bounds__(256) void k_psum(const int* __restrict__ degi,
                                              int* __restrict__ bsum)
{
  __shared__ int red[4];
  const int tid = threadIdx.x;
  int i = blockIdx.x * 256 + tid;
  int v = (i < NN) ? degi[i] : 0;
#pragma unroll
  for (int d = 32; d >= 1; d >>= 1) v += __shfl_down(v, d);
  if ((tid & 63) == 0) red[tid >> 6] = v;
  __syncthreads();
  if (tid == 0) bsum[blockIdx.x] = red[0] + red[1] + red[2] + red[3];
}

__global__ __launch_bounds__(256) void k_bscan(const int* __restrict__ bsum,
                                               int* __restrict__ boff)
{
  __shared__ int wsum[4];
  const int tid = threadIdx.x, lane = tid & 63, wv = tid >> 6;
  int v = (tid < NB) ? bsum[tid] : 0;
  int s = v;
#pragma unroll
  for (int d = 1; d < 64; d <<= 1) { int t = __shfl_up(s, d); if (lane >= d) s += t; }
  if (lane == 63) wsum[wv] = s;
  __syncthreads();
  int wo = 0;
  for (int w = 0; w < wv; ++w) wo += wsum[w];
  if (tid < NB) boff[tid] = wo + s - v;
}

__global__ __launch_bounds__(256) void k_scan2(const int* __restrict__ degi,
                                               const int* __restrict__ boff,
                                               int* __restrict__ rowptr,
                                               int* __restrict__ cursor)
{
  __shared__ int wsum[4];
  const int tid = threadIdx.x, lane = tid & 63, wv = tid >> 6;
  int i = blockIdx.x * 256 + tid;
  int v = (i < NN) ? degi[i] : 0;
  int s = v;
#pragma unroll
  for (int d = 1; d < 64; d <<= 1) { int t = __shfl_up(s, d); if (lane >= d) s += t; }
  if (lane == 63) wsum[wv] = s;
  __syncthreads();
  int wo = 0;
  for (int w = 0; w < wv; ++w) wo += wsum[w];
  int excl = boff[blockIdx.x] + wo + (s - v);
  if (i < NN) { rowptr[i] = excl; cursor[i] = excl; }
  if (i == NN) rowptr[NN] = excl;
}

__global__ void k_fill(const int* __restrict__ src, const int* __restrict__ dst,
                       const float* __restrict__ dinv,
                       int* __restrict__ cursor,
                       int* __restrict__ eidx, float* __restrict__ enrm)
{
  int e = blockIdx.x * 256 + threadIdx.x;
  if (e < EE) {
    int s = src[e], d = dst[e];
    int p = atomicAdd(cursor + d, 1);
    eidx[p] = s;
    enrm[p] = dinv[s] * dinv[d];
  }
}

// ---------------------------------------------------------------- GCN gather (bf16 in, bf16 out)
__global__ __launch_bounds__(256) void k_gather(
    const u16* __restrict__ hw, u16* __restrict__ out,
    const int* __restrict__ rowptr, const int* __restrict__ eidx,
    const float* __restrict__ enrm, const float* __restrict__ dinv)
{
  const int wid = (blockIdx.x << 2) + (threadIdx.x >> 6);
  if (wid >= NN) return;
  const int lane = threadIdx.x & 63;
  const int c0 = lane << 2;
  float a0, a1, a2, a3;
  {
    float d2 = dinv[wid]; d2 *= d2;
    uint2 v = *(const uint2*)(hw + (long)wid * 256 + c0);
    a0 = d2 * b2f((u16)(v.x & 0xFFFF)); a1 = d2 * b2f((u16)(v.x >> 16));
    a2 = d2 * b2f((u16)(v.y & 0xFFFF)); a3 = d2 * b2f((u16)(v.y >> 16));
  }
  int p = rowptr[wid];
  const int end = rowptr[wid + 1];
  for (; p + 1 < end; p += 2) {
    int s0 = eidx[p], s1 = eidx[p + 1];
    float n0 = enrm[p], n1 = enrm[p + 1];
    uint2 v0 = *(const uint2*)(hw + (long)s0 * 256 + c0);
    uint2 v1 = *(const uint2*)(hw + (long)s1 * 256 + c0);
    a0 += n0 * b2f((u16)(v0.x & 0xFFFF)) + n1 * b2f((u16)(v1.x & 0xFFFF));
    a1 += n0 * b2f((u16)(v0.x >> 16))    + n1 * b2f((u16)(v1.x >> 16));
    a2 += n0 * b2f((u16)(v0.y & 0xFFFF)) + n1 * b2f((u16)(v1.y & 0xFFFF));
    a3 += n0 * b2f((u16)(v0.y >> 16))    + n1 * b2f((u16)(v1.y >> 16));
  }
  if (p < end) {
    int s0 = eidx[p];
    float n0 = enrm[p];
    uint2 v0 = *(const uint2*)(hw + (long)s0 * 256 + c0);
    a0 += n0 * b2f((u16)(v0.x & 0xFFFF));
    a1 += n0 * b2f((u16)(v0.x >> 16));
    a2 += n0 * b2f((u16)(v0.y & 0xFFFF));
    a3 += n0 * b2f((u16)(v0.y >> 16));
  }
  uint2 o; o.x = pack2(a0, a1); o.y = pack2(a2, a3);
  *(uint2*)(out + (long)wid * 256 + c0) = o;
}

// ---------------------------------------------------------------- gated conv via MFMA
// out[n][co][t] = relu(P*sigmoid(Q)+R); conv c: D[co][(n,t)] = Wc[co][k]*B[k][(n,t)], K=96
// A-frags stored WAVE-LINEAR in LDS (conflict-free b128 reads); no reg caching (no spill).
template<int FOLD>
__global__ __launch_bounds__(256, 2) void k_gatedm(
    const u16* __restrict__ in, u16* __restrict__ out,
    const float* __restrict__ Wg,   // (3,32,32,3) [conv][co][ci][dt]
    const float* __restrict__ bg,   // (3,32)
    const float* __restrict__ aff, const float* __restrict__ bff,  // per-f(256) or null
    float* __restrict__ s1, float* __restrict__ s2)                // [32]
{
  __shared__ u16 xT[32 * 488];   // [node][t'(12 rows, stride 40)][ci 32]; rows 0,9 zero pad
  __shared__ u16 aw[1152 * 8];   // [(conv*2+mf)*3+s][lane 64][8]  wave-linear A-frags, 18KB
  __shared__ float bgl[96];
  const int tid = threadIdx.x;

  // weight reorder -> wave-linear bf16 A-frag layout:
  // frag (conv,mf,s): lane l holds A[row=mf*16+(l&15)][k=s*32+(l>>4)*8+j], k=dt*32+ci
  for (int idx = tid; idx < 9216; idx += 256) {
    int conv = idx / 3072;
    int rem = idx - conv * 3072;
    int co = rem / 96;
    int r2 = rem - co * 96;
    int ci = r2 / 3;
    int dt = r2 - ci * 3;
    int mf = co >> 4;
    int l = (co & 15) | ((ci >> 3) << 4);
    int j = ci & 7;
    aw[((((conv << 1) + mf) * 3 + dt) * 64 + l) * 8 + j] = f2b(Wg[idx]);
  }
  if (tid < 96) bgl[tid] = bg[tid];

  // x staging: thread = (node_l = tid>>3, cig = tid&7 -> ci0 = cig*4)
  {
    const int node_l = tid >> 3;
    const int cig = tid & 7;
    long ng = (long)blockIdx.x * 32 + node_l;
    long nc = ng < NN ? ng : (NN - 1);
    const u16* src = in + nc * 256 + (cig << 2) * 8;
    uint4 rv[4];
#pragma unroll
    for (int i = 0; i < 4; ++i) rv[i] = *(const uint4*)(src + i * 8);
    u16* rp = (u16*)rv;
    if (FOLD) {
#pragma unroll
      for (int i = 0; i < 4; ++i) {
        const int f = ((cig << 2) + i) << 3;
        float4 aa = *(const float4*)(aff + f);
        float4 ab = *(const float4*)(aff + f + 4);
        float4 ba = *(const float4*)(bff + f);
        float4 bb = *(const float4*)(bff + f + 4);
        float axs[8] = {aa.x, aa.y, aa.z, aa.w, ab.x, ab.y, ab.z, ab.w};
        float bxs[8] = {ba.x, ba.y, ba.z, ba.w, bb.x, bb.y, bb.z, bb.w};
#pragma unroll
        for (int t = 0; t < 8; ++t)
          rp[i * 8 + t] = f2b(fmaf(axs[t], b2f(rp[i * 8 + t]), bxs[t]));
      }
    }
    u16* xb = xT + node_l * 488 + (cig << 2);
#pragma unroll
    for (int t = 0; t < 8; ++t) {
      ushort4 wv;
      wv.x = rp[t]; wv.y = rp[8 + t]; wv.z = rp[16 + t]; wv.w = rp[24 + t];
      *(ushort4*)(xb + (t + 1) * 40) = wv;
    }
    ushort4 z4 = {0, 0, 0, 0};
    *(ushort4*)(xb) = z4;
    *(ushort4*)(xb + 9 * 40) = z4;
  }
  __syncthreads();

  const int l = tid & 63, w = tid >> 6;
  const int mynode = (l >> 3) & 1, t = l & 7;
  float hs[8] = {0, 0, 0, 0, 0, 0, 0, 0}, hq[8] = {0, 0, 0, 0, 0, 0, 0, 0};
  const u16* awl = aw + l * 8;

  for (int p = 0; p < 4; ++p) {
    const int nl0 = (w << 3) + (p << 1);
    const u16* tb = xT + (nl0 + mynode) * 488 + t * 40 + ((l >> 4) << 3);
    f32x4 acc[3][2];
#pragma unroll
    for (int conv = 0; conv < 3; ++conv)
#pragma unroll
      for (int mf = 0; mf < 2; ++mf) acc[conv][mf] = (f32x4){0.f, 0.f, 0.f, 0.f};
#pragma unroll
    for (int s = 0; s < 3; ++s) {
      bf16x8 bfv = *(const bf16x8*)(tb + s * 40);
#pragma unroll
      for (int conv = 0; conv < 3; ++conv)
#pragma unroll
        for (int mf = 0; mf < 2; ++mf) {
          bf16x8 afv = *(const bf16x8*)(awl + ((((conv << 1) + mf) * 3 + s) << 9));
          acc[conv][mf] = __builtin_amdgcn_mfma_f32_16x16x32_bf16(
              afv, bfv, acc[conv][mf], 0, 0, 0);
        }
    }
    long ng = (long)blockIdx.x * 32 + nl0 + mynode;
    bool valid = ng < NN;
    float vm = valid ? 1.0f : 0.0f;
    u16* op = out + ng * 256 + t;
#pragma unroll
    for (int mf = 0; mf < 2; ++mf)
#pragma unroll
      for (int reg = 0; reg < 4; ++reg) {
        int r = mf * 4 + reg;
        int co = mf * 16 + ((l >> 4) << 2) + reg;
        float pp = acc[0][mf][reg] + bgl[co];
        float qq = acc[1][mf][reg] + bgl[32 + co];
        float rr = acc[2][mf][reg] + bgl[64 + co];
        float sg = 1.0f / (1.0f + __expf(-qq));
        float h = fmaxf(fmaf(pp, sg, rr), 0.0f);
        hs[r] += vm * h;
        hq[r] += vm * h * h;
        if (valid) op[co * 8] = f2b(h);
      }
  }
  // per-co stats: reduce across 16 lanes sharing l>>4
#pragma unroll
  for (int d = 1; d < 16; d <<= 1)
#pragma unroll
    for (int r = 0; r < 8; ++r) {
      hs[r] += __shfl_xor(hs[r], d);
      hq[r] += __shfl_xor(hq[r], d);
    }
  if ((l & 15) == 0) {
#pragma unroll
    for (int mf = 0; mf < 2; ++mf)
#pragma unroll
      for (int reg = 0; reg < 4; ++reg) {
        int co = mf * 16 + ((l >> 4) << 2) + reg;
        atomicAdd(s1 + co, hs[mf * 4 + reg]);
        atomicAdd(s2 + co, hq[mf * 4 + reg]);
      }
  }
}

// ---------------------------------------------------------------- bn finalize
__global__ void k_bnfin(const float* __restrict__ s1, const float* __restrict__ s2,
                        const float* __restrict__ g, const float* __restrict__ b,
                        float cntInv, int nf, int expand,
                        float* __restrict__ A, float* __restrict__ B)
{
  int f = threadIdx.x;
  if (f < nf) {
    int c = expand ? (f >> 3) : f;
    float m = s1[c] * cntInv;
    float var = s2[c] * cntInv - m * m;
    float a = g[c] / sqrtf(var + EPSF);
    A[f] = a;
    B[f] = b[c] - m * a;
  }
}

// ---------------------------------------------------------------- W fold: WT[j][k]=aff[k]*W[k][j]
__global__ __launch_bounds__(256) void k_wfold(
    const float* __restrict__ W, const float* __restrict__ aff,
    u16* __restrict__ WT)
{
  __shared__ float tile[64][68];
  __shared__ float affl[64];
  const int b = blockIdx.x;
  const int kx = (b & 3) * 64, jx = (b >> 2) * 64;
  const int t = threadIdx.x;
  if (t < 64) affl[t] = aff[kx + t];
  {
    int r = t >> 2, c0 = (t & 3) * 16;
#pragma unroll
    for (int i = 0; i < 4; ++i) {
      float4 v = *(const float4*)(W + (long)(kx + r) * 256 + jx + c0 + i * 4);
      tile[r][c0 + i * 4 + 0] = v.x; tile[r][c0 + i * 4 + 1] = v.y;
      tile[r][c0 + i * 4 + 2] = v.z; tile[r][c0 + i * 4 + 3] = v.w;
    }
  }
  __syncthreads();
  {
    int jl = t >> 2, k0 = (t & 3) * 16;
    u16 tmp[16];
#pragma unroll
    for (int kk = 0; kk < 16; ++kk)
      tmp[kk] = f2b(affl[k0 + kk] * tile[k0 + kk][jl]);
    u16* dst = WT + (long)(jx + jl) * 256 + kx + k0;
    *(uint4*)dst = ((uint4*)tmp)[0];
    *(uint4*)(dst + 8) = ((uint4*)tmp)[1];
  }
}

__global__ void k_rowbias(const float* __restrict__ W, const float* __restrict__ bff,
                          float* __restrict__ rb)
{
  int j = threadIdx.x;
  int k0 = blockIdx.x * 32;
  float s = 0.0f;
  for (int kk = 0; kk < 32; ++kk) s += bff[k0 + kk] * W[(long)(k0 + kk) * 256 + j];
  atomicAdd(rb + j, s);
}

// ---------------------------------------------------------------- MFMA GEMM: out = A @ WT^T + rb
__global__ __launch_bounds__(512, 2) void k_gemmm(
    const u16* __restrict__ A, const u16* __restrict__ WT,
    const float* __restrict__ rowbias, u16* __restrict__ Out)
{
  __shared__ u16 At[128 * 64];   // [row][k 64], 16B-chunk XOR-swizzled by row&7
  __shared__ u16 Bt[256 * 64];   // [j][k 64], same swizzle
  const int tid = threadIdx.x, l = tid & 63, w = tid >> 6;
  const long n0 = (long)blockIdx.x * 128;
  const int wr = (w & 1) << 6, wc = (w >> 1) << 6;
  f32x4 acc[4][4];
#pragma unroll
  for (int i = 0; i < 4; ++i)
#pragma unroll
    for (int j = 0; j < 4; ++j) acc[i][j] = (f32x4){0.f, 0.f, 0.f, 0.f};
  float rb[4];
#pragma unroll
  for (int cf = 0; cf < 4; ++cf) rb[cf] = rowbias[wc + (cf << 4) + (l & 15)];

  for (int kt = 0; kt < 4; ++kt) {
    if (kt) __syncthreads();
#pragma unroll
    for (int i = 0; i < 2; ++i) {
      int row = (w << 4) + (i << 3) + (l >> 3);
      int sg = (l & 7) ^ (row & 7);
      long n = n0 + row; if (n >= NN) n = NN - 1;
      gl16(A + n * 256 + kt * 64 + sg * 8, At + ((w << 4) + (i << 3)) * 64);
    }
#pragma unroll
    for (int i = 0; i < 4; ++i) {
      int row = (w << 5) + (i << 3) + (l >> 3);
      int sg = (l & 7) ^ (row & 7);
      gl16(WT + (long)row * 256 + kt * 64 + sg * 8, Bt + ((w << 5) + (i << 3)) * 64);
    }
    __syncthreads();
#pragma unroll
    for (int ks = 0; ks < 2; ++ks) {
      bf16x8 af[4], bf[4];
#pragma unroll
      for (int rf = 0; rf < 4; ++rf) {
        int row = wr + (rf << 4) + (l & 15);
        int slot = ((ks << 2) + (l >> 4)) ^ (row & 7);
        af[rf] = *(const bf16x8*)(At + row * 64 + (slot << 3));
      }
#pragma unroll
      for (int cf = 0; cf < 4; ++cf) {
        int row = wc + (cf << 4) + (l & 15);
        int slot = ((ks << 2) + (l >> 4)) ^ (row & 7);
        bf[cf] = *(const bf16x8*)(Bt + row * 64 + (slot << 3));
      }
#pragma unroll
      for (int rf = 0; rf < 4; ++rf)
#pragma unroll
        for (int cf = 0; cf < 4; ++cf)
          acc[rf][cf] = __builtin_amdgcn_mfma_f32_16x16x32_bf16(
              af[rf], bf[cf], acc[rf][cf], 0, 0, 0);
    }
  }
#pragma unroll
  for (int rf = 0; rf < 4; ++rf)
#pragma unroll
    for (int reg = 0; reg < 4; ++reg) {
      long n = n0 + wr + (rf << 4) + ((l >> 4) << 2) + reg;
      if (n < NN) {
        u16* orow = Out + n * 256 + wc + (l & 15);
#pragma unroll
        for (int cf = 0; cf < 4; ++cf)
          orow[cf << 4] = f2b(acc[rf][cf][reg] + rb[cf]);
      }
    }
}

// ---------------------------------------------------------------- per-feature col stats (bf16 in)
__global__ void k_colstats(const u16* __restrict__ x, int rows,
                           float* __restrict__ s1, float* __restrict__ s2)
{
  int f = threadIdx.x;
  float a = 0.0f, b = 0.0f;
  for (int n = blockIdx.x; n < rows; n += gridDim.x) {
    float v = b2f(x[(long)n * 256 + f]);
    a += v; b += v * v;
  }
  atomicAdd(s1 + f, a);
  atomicAdd(s2 + f, b);
}

// ---------------------------------------------------------------- finalize layer
__global__ __launch_bounds__(256) void k_final(
    u16* __restrict__ x, const u16* __restrict__ h2,
    const float* __restrict__ resW, const float* __restrict__ resb,
    const float* __restrict__ A2, const float* __restrict__ B2,
    float* __restrict__ xl, int mode)
{
  __shared__ float xs[2048];
  __shared__ float wr[32 * 33];
  const int tid = threadIdx.x;
  for (int idx = tid; idx < 1024; idx += 256) {
    int co = idx >> 5, ci = idx & 31;
    wr[ci * 33 + co] = resW[idx];
  }
  const long base = (long)blockIdx.x * 2048;
  {
    const uint4 v = *((const uint4*)(x + base) + tid);
    float* d = xs + tid * 8;
    d[0] = b2f((u16)(v.x & 0xFFFF)); d[1] = b2f((u16)(v.x >> 16));
    d[2] = b2f((u16)(v.y & 0xFFFF)); d[3] = b2f((u16)(v.y >> 16));
    d[4] = b2f((u16)(v.z & 0xFFFF)); d[5] = b2f((u16)(v.z >> 16));
    d[6] = b2f((u16)(v.w & 0xFFFF)); d[7] = b2f((u16)(v.w >> 16));
  }
  __syncthreads();
  const int nl = tid >> 5, c = tid & 31;
  float r[8];
  {
    float rb = resb[c];
#pragma unroll
    for (int t = 0; t < 8; ++t) r[t] = rb;
  }
  const float* xrow = xs + (nl << 8);
  for (int ci = 0; ci < 32; ++ci) {
    float w = wr[ci * 33 + c];
    float4 xa = *(const float4*)(xrow + ci * 8);
    float4 xb = *(const float4*)(xrow + ci * 8 + 4);
    r[0] += xa.x * w; r[1] += xa.y * w; r[2] += xa.z * w; r[3] += xa.w * w;
    r[4] += xb.x * w; r[5] += xb.y * w; r[6] += xb.z * w; r[7] += xb.w * w;
  }
  float a2 = A2[c], b2 = B2[c];
  float hv[8];
  {
    const uint4 v = *((const uint4*)(h2 + base) + tid);
    hv[0] = b2f((u16)(v.x & 0xFFFF)); hv[1] = b2f((u16)(v.x >> 16));
    hv[2] = b2f((u16)(v.y & 0xFFFF)); hv[3] = b2f((u16)(v.y >> 16));
    hv[4] = b2f((u16)(v.z & 0xFFFF)); hv[5] = b2f((u16)(v.z >> 16));
    hv[6] = b2f((u16)(v.w & 0xFFFF)); hv[7] = b2f((u16)(v.w >> 16));
  }
  if (mode == 0) {
    uint4 o;
    float ov[8];
#pragma unroll
    for (int t = 0; t < 8; ++t) ov[t] = fmaxf(fmaf(a2, hv[t], b2) + r[t], 0.0f);
    o.x = pack2(ov[0], ov[1]); o.y = pack2(ov[2], ov[3]);
    o.z = pack2(ov[4], ov[5]); o.w = pack2(ov[6], ov[7]);
    *(uint4*)(x + base + tid * 8) = o;
  } else {
    float v = fmaf(a2, hv[7], b2) + r[7];
    int n = blockIdx.x * 8 + nl;
    xl[n * 32 + c] = v;
  }
}

// ---------------------------------------------------------------- pooling (sorted graphs)
__global__ __launch_bounds__(256) void k_pool(
    const float* __restrict__ xl, const int* __restrict__ graphs,
    int* __restrict__ cnt, float* __restrict__ sp, unsigned* __restrict__ mxu)
{
  __shared__ float lsum[64 * 32];
  __shared__ unsigned lmax[64 * 32];
  __shared__ int lcnt[64];
  const int tid = threadIdx.x;
  const int n0 = blockIdx.x << 8;
  const int nend = min(n0 + 256, NN);
  const int gmin = graphs[n0];
  const int gmax = graphs[nend - 1];
  const int span = gmax - gmin + 1;
  for (int i = tid; i < span * 32; i += 256) { lsum[i] = 0.0f; lmax[i] = 0u; }
  for (int i = tid; i < span; i += 256) lcnt[i] = 0;
  __syncthreads();
  const int c = tid & 31;
  const int nbase = n0 + ((tid >> 5) << 5);
  int curg = -1; float s = 0.0f; unsigned m = 0u; int cn = 0;
  for (int i = 0; i < 32; ++i) {
    int n = nbase + i;
    if (n >= nend) break;
    int g = graphs[n];
    float v = xl[(n << 5) + c];
    unsigned u = __float_as_uint(v);
    u = (u & 0x80000000u) ? ~u : (u | 0x80000000u);
    if (g != curg) {
      if (curg >= 0) {
        atomicAdd(&lsum[((curg - gmin) << 5) + c], s);
        atomicMax(&lmax[((curg - gmin) << 5) + c], m);
        if (c == 0) atomicAdd(&lcnt[curg - gmin], cn);
      }
      curg = g; s = v; m = u; cn = 1;
    } else {
      s += v; m = (u > m) ? u : m; cn++;
    }
  }
  if (curg >= 0) {
    atomicAdd(&lsum[((curg - gmin) << 5) + c], s);
    atomicMax(&lmax[((curg - gmin) << 5) + c], m);
    if (c == 0) atomicAdd(&lcnt[curg - gmin], cn);
  }
  __syncthreads();
  for (int i = tid; i < span * 32; i += 256) {
    atomicAdd(sp + (gmin << 5) + i, lsum[i]);
    atomicMax(mxu + (gmin << 5) + i, lmax[i]);
  }
  for (int i = tid; i < span; i += 256)
    if (lcnt[i]) atomicAdd(cnt + gmin + i, lcnt[i]);
}

// ---------------------------------------------------------------- MLP head
__global__ __launch_bounds__(128) void k_head(
    const int* __restrict__ cnt, const float* __restrict__ sp,
    const unsigned* __restrict__ mxu,
    const float* __restrict__ W1, const float* __restrict__ b1,
    const float* __restrict__ W2, const float* __restrict__ b2,
    const float* __restrict__ W3, const float* __restrict__ b3,
    float* __restrict__ out)
{
  __shared__ float xg[96], hh1[128], hh2[64];
  const int g = blockIdx.x, tid = threadIdx.x;
  if (tid < 32) {
    float s = sp[g * 32 + tid];
    int cn = cnt[g];
    float mean = s / fmaxf((float)cn, 1.0f);
    float mx = 0.0f;
    if (cn > 0) {
      unsigned u = mxu[g * 32 + tid];
      unsigned ub = (u & 0x80000000u) ? (u ^ 0x80000000u) : ~u;
      mx = __uint_as_float(ub);
    }
    xg[tid] = mean; xg[32 + tid] = mx; xg[64 + tid] = s;
  }
  __syncthreads();
  {
    float a = b1[tid];
    for (int k = 0; k < 96; ++k) a += xg[k] * W1[k * 128 + tid];
    hh1[tid] = fmaxf(a, 0.0f);
  }
  __syncthreads();
  if (tid < 64) {
    float a = b2[tid];
    for (int k = 0; k < 128; ++k) a += hh1[k] * W2[k * 64 + tid];
    hh2[tid] = fmaxf(a, 0.0f);
  }
  __syncthreads();
  if (tid < 64) {
    float p = hh2[tid] * W3[tid];
    for (int off = 32; off; off >>= 1) p += __shfl_down(p, off);
    if (tid == 0) out[g] = p + b3[0];
  }
}

// ================================================================ launch
extern "C" void kernel_launch(void* const* d_in, const int* in_sizes, int n_in,
                              void* d_out, int out_size, void* d_ws, size_t ws_size,
                              hipStream_t stream)
{
  const float* X       = (const float*)d_in[0];
  const int*   edge    = (const int*)d_in[1];
  const int*   graphs  = (const int*)d_in[2];
  const float* W_in    = (const float*)d_in[3];
  const float* b_in    = (const float*)d_in[4];
  const float* res_W   = (const float*)d_in[5];
  const float* res_b   = (const float*)d_in[6];
  const float* g1_W    = (const float*)d_in[7];
  const float* g1_b    = (const float*)d_in[8];
  const float* bn0_g   = (const float*)d_in[9];
  const float* bn0_b   = (const float*)d_in[10];
  const float* gcn_W   = (const float*)d_in[11];
  // d_in[12] = gcn_b: cancels in bn1 (per-feature shift removed by mean over axis 0)
  const float* bn1_g   = (const float*)d_in[13];
  const float* bn1_b   = (const float*)d_in[14];
  const float* g2_W    = (const float*)d_in[15];
  const float* g2_b    = (const float*)d_in[16];
  const float* bn2_g   = (const float*)d_in[17];
  const float* bn2_b   = (const float*)d_in[18];
  const float* out_W1  = (const float*)d_in[19];
  const float* out_b1  = (const float*)d_in[20];
  const float* out_W2  = (const float*)d_in[21];
  const float* out_b2  = (const float*)d_in[22];
  const float* out_W3  = (const float*)d_in[23];
  const float* out_b3  = (const float*)d_in[24];
  float* outp = (float*)d_out;

  const int* srcp = edge;
  const int* dstp = edge + EE;

  // ---- workspace layout (~113 MB) ----
  const long BIGE = (long)NN * 256;              // 12.8M elems
  u16*   P0   = (u16*)d_ws;                      // x bf16
  u16*   P1   = P0 + BIGE;                       // h1 / h2 bf16
  u16*   P2   = P1 + BIGE;                       // gather out bf16
  u16*   P3   = P2 + BIGE;                       // gemm out bf16
  u16*   WT   = P3 + BIGE;                       // 65536 u16
  float* xl   = (float*)(WT + 65536);            // N*32
  float* dinv = xl + (long)NN * 32;              // N
  int*   rowptr = (int*)(dinv + NN);             // N+1
  int*   cursor = rowptr + NN + 1;               // N
  int*   eidx   = cursor + NN;                   // E
  float* enrm   = (float*)(eidx + EE);           // E
  int*   bsum   = (int*)(enrm + EE);             // NB
  int*   boff   = bsum + NB;                     // NB
  int*   degi = boff + NB;                       // N      <- zero region start
  float* stats = (float*)(degi + NN);            // 1280
  int*   cnt  = (int*)(stats + 1280);            // 64
  float* sp   = (float*)(cnt + 64);              // 2048
  unsigned* mxu = (unsigned*)(sp + 2048);        // 2048
  float* rbias = (float*)(mxu + 2048);           // 512    <- zero region end
  float* AFF  = rbias + 512;                     // 256
  float* BFF  = AFF + 256;
  float* A2v  = BFF + 256;
  float* B2v  = A2v + 32;

  const size_t zero_bytes = (size_t)(NN + 1280 + 64 + 2048 + 2048 + 512) * 4;
  hipMemsetAsync(degi, 0, zero_bytes, stream);

  k_convin<<<NN / 8, 256, 0, stream>>>(X, P0, W_in, b_in);
  k_deg<<<(EE + 255) / 256, 256, 0, stream>>>(dstp, degi);
  k_dinv<<<(NN + 255) / 256, 256, 0, stream>>>(degi, dinv);
  k_psum<<<NB, 256, 0, stream>>>(degi, bsum);
  k_bscan<<<1, 256, 0, stream>>>(bsum, boff);
  k_scan2<<<NB, 256, 0, stream>>>(degi, boff, rowptr, cursor);
  k_fill<<<(EE + 255) / 256, 256, 0, stream>>>(srcp, dstp, dinv, cursor, eidx, enrm);

  const int GGRID = (NN + 31) / 32;   // 1563

  for (int l = 0; l < 2; ++l) {
    const float* g1Wl = g1_W + l * 9216;
    const float* g1bl = g1_b + l * 96;
    const float* g2Wl = g2_W + l * 9216;
    const float* g2bl = g2_b + l * 96;
    const float* gWl  = gcn_W + l * 65536;
    float* st = stats + l * 640;
    float* rbl = rbias + l * 256;

    // gated conv 1 (MFMA) + bn0 stats
    k_gatedm<0><<<GGRID, 256, 0, stream>>>(P0, P1, g1Wl, g1bl, nullptr, nullptr,
                                           st + 0, st + 32);
    k_bnfin<<<1, 256, 0, stream>>>(st + 0, st + 32, bn0_g + l * 32, bn0_b + l * 32,
                                   1.0f / 400000.0f, 256, 1, AFF, BFF);
    // fold bn0 into W (transposed bf16) + row bias
    k_wfold<<<16, 256, 0, stream>>>(gWl, AFF, WT);
    k_rowbias<<<8, 256, 0, stream>>>(gWl, BFF, rbl);
    // MFMA GEMM: P3 = P1 @ Wfold + rb
    k_gemmm<<<(NN + 127) / 128, 512, 0, stream>>>(P1, WT, rbl, P3);
    // GCN aggregation: CSR gather (self-loop included)
    k_gather<<<(NN + 3) / 4, 256, 0, stream>>>(P3, P2, rowptr, eidx, enrm, dinv);
    // bn1 stats + fold
    k_colstats<<<512, 256, 0, stream>>>(P2, NN, st + 64, st + 320);
    k_bnfin<<<1, 256, 0, stream>>>(st + 64, st + 320, bn1_g + l * 256, bn1_b + l * 256,
                                   1.0f / (float)NN, 256, 0, AFF, BFF);
    // gated conv 2 (MFMA, bn1 fold on input) + bn2 stats
    k_gatedm<1><<<GGRID, 256, 0, stream>>>(P2, P1, g2Wl, g2bl, AFF, BFF,
                                           st + 576, st + 608);
    k_bnfin<<<1, 256, 0, stream>>>(st + 576, st + 608, bn2_g + l * 32, bn2_b + l * 32,
                                   1.0f / 400000.0f, 32, 0, A2v, B2v);
    // finalize: bn2 + residual(x) + (relu in-place | t=7 slice)
    k_final<<<NN / 8, 256, 0, stream>>>(P0, P1, res_W + l * 1024, res_b + l * 32,
                                        A2v, B2v, xl, (l == 0) ? 0 : 1);
  }

  k_pool<<<(NN + 255) / 256, 256, 0, stream>>>(xl, graphs, cnt, sp, mxu);
  k_head<<<64, 128, 0, stream>>>(cnt, sp, mxu, out_W1, out_b1, out_W2, out_b2,
                                 out_W3, out_b3, outp);

  (void)in_sizes; (void)n_in; (void)out_size; (void)ws_size;
}

// Round 7
// 1326.900 us; speedup vs baseline: 3.4789x; 3.4789x over previous
//
#include <hip/hip_runtime.h>
#include <hip/hip_bf16.h>

#define NN 50000
#define EE 400000
#define EPSF 1e-5f
#define NB 196   // (NN+255)/256

typedef unsigned short u16;
typedef __attribute__((ext_vector_type(8))) short bf16x8;
typedef __attribute__((ext_vector_type(4))) float f32x4;

__device__ __forceinline__ float b2f(u16 u) { return __uint_as_float(((unsigned)u) << 16); }
__device__ __forceinline__ u16 f2b(float f) {
  unsigned x = __float_as_uint(f);
  unsigned r = x + 0x7FFFu + ((x >> 16) & 1u);   // RNE
  return (u16)(r >> 16);
}
__device__ __forceinline__ unsigned pack2(float lo, float hi) {
  return (unsigned)f2b(lo) | ((unsigned)f2b(hi) << 16);
}
__device__ __forceinline__ void gl16(const void* g, void* l) {
  __builtin_amdgcn_global_load_lds(
      (const __attribute__((address_space(1))) void*)g,
      (__attribute__((address_space(3))) void*)l, 16, 0, 0);
}

// ---------------------------------------------------------------- conv_in
__global__ __launch_bounds__(256) void k_convin(
    const float* __restrict__ X, u16* __restrict__ out,
    const float* __restrict__ Wi, const float* __restrict__ bi)
{
  __shared__ float xs[1024];
  __shared__ float wi[16 * 33];
  const int tid = threadIdx.x;
  for (int idx = tid; idx < 512; idx += 256) {
    int co = idx >> 4, ci = idx & 15;
    wi[ci * 33 + co] = Wi[idx];
  }
  const long xbase = (long)blockIdx.x * 1024;
  ((float4*)xs)[tid] = ((const float4*)(X + xbase))[tid];
  __syncthreads();
  const int nl = tid >> 5, c = tid & 31;
  float acc[8];
  {
    float bc = bi[c];
#pragma unroll
    for (int t = 0; t < 8; ++t) acc[t] = bc;
  }
  const float* xrow = xs + (nl << 7);
  for (int ci = 0; ci < 16; ++ci) {
    float w = wi[ci * 33 + c];
    float4 xa = *(const float4*)(xrow + ci * 8);
    float4 xb = *(const float4*)(xrow + ci * 8 + 4);
    acc[0] += xa.x * w; acc[1] += xa.y * w; acc[2] += xa.z * w; acc[3] += xa.w * w;
    acc[4] += xb.x * w; acc[5] += xb.y * w; acc[6] += xb.z * w; acc[7] += xb.w * w;
  }
  uint4 o;
  o.x = pack2(acc[0], acc[1]); o.y = pack2(acc[2], acc[3]);
  o.z = pack2(acc[4], acc[5]); o.w = pack2(acc[6], acc[7]);
  *(uint4*)(out + (long)blockIdx.x * 2048 + tid * 8) = o;
}

// ---------------------------------------------------------------- degree / dinv
__global__ void k_deg(const int* __restrict__ dst, int* __restrict__ degi)
{
  int e = blockIdx.x * 256 + threadIdx.x;
  if (e < EE) atomicAdd(degi + dst[e], 1);
}
__global__ void k_dinv(const int* __restrict__ degi, float* __restrict__ dinv)
{
  int n = blockIdx.x * 256 + threadIdx.x;
  if (n < NN) dinv[n] = rsqrtf((float)degi[n] + 1.0f);
}

// ---------------------------------------------------------------- CSR build
__global__ __launch_bounds__(256) void k_psum(const int* __restrict__ degi,
                                              int* __restrict__ bsum)
{
  __shared__ int red[4];
  const int tid = threadIdx.x;
  int i = blockIdx.x * 256 + tid;
  int v = (i < NN) ? degi[i] : 0;
#pragma unroll
  for (int d = 32; d >= 1; d >>= 1) v += __shfl_down(v, d);
  if ((tid & 63) == 0) red[tid >> 6] = v;
  __syncthreads();
  if (tid == 0) bsum[blockIdx.x] = red[0] + red[1] + red[2] + red[3];
}

__global__ __launch_bounds__(256) void k_bscan(const int* __restrict__ bsum,
                                               int* __restrict__ boff)
{
  __shared__ int wsum[4];
  const int tid = threadIdx.x, lane = tid & 63, wv = tid >> 6;
  int v = (tid < NB) ? bsum[tid] : 0;
  int s = v;
#pragma unroll
  for (int d = 1; d < 64; d <<= 1) { int t = __shfl_up(s, d); if (lane >= d) s += t; }
  if (lane == 63) wsum[wv] = s;
  __syncthreads();
  int wo = 0;
  for (int w = 0; w < wv; ++w) wo += wsum[w];
  if (tid < NB) boff[tid] = wo + s - v;
}

__global__ __launch_bounds__(256) void k_scan2(const int* __restrict__ degi,
                                               const int* __restrict__ boff,
                                               int* __restrict__ rowptr,
                                               int* __restrict__ cursor)
{
  __shared__ int wsum[4];
  const int tid = threadIdx.x, lane = tid & 63, wv = tid >> 6;
  int i = blockIdx.x * 256 + tid;
  int v = (i < NN) ? degi[i] : 0;
  int s = v;
#pragma unroll
  for (int d = 1; d < 64; d <<= 1) { int t = __shfl_up(s, d); if (lane >= d) s += t; }
  if (lane == 63) wsum[wv] = s;
  __syncthreads();
  int wo = 0;
  for (int w = 0; w < wv; ++w) wo += wsum[w];
  int excl = boff[blockIdx.x] + wo + (s - v);
  if (i < NN) { rowptr[i] = excl; cursor[i] = excl; }
  if (i == NN) rowptr[NN] = excl;
}

__global__ void k_fill(const int* __restrict__ src, const int* __restrict__ dst,
                       const float* __restrict__ dinv,
                       int* __restrict__ cursor,
                       int* __restrict__ eidx, float* __restrict__ enrm)
{
  int e = blockIdx.x * 256 + threadIdx.x;
  if (e < EE) {
    int s = src[e], d = dst[e];
    int p = atomicAdd(cursor + d, 1);
    eidx[p] = s;
    enrm[p] = dinv[s] * dinv[d];
  }
}

// ---------------------------------------------------------------- GCN gather (bf16 in, bf16 out)
__global__ __launch_bounds__(256) void k_gather(
    const u16* __restrict__ hw, u16* __restrict__ out,
    const int* __restrict__ rowptr, const int* __restrict__ eidx,
    const float* __restrict__ enrm, const float* __restrict__ dinv)
{
  const int wid = (blockIdx.x << 2) + (threadIdx.x >> 6);
  if (wid >= NN) return;
  const int lane = threadIdx.x & 63;
  const int c0 = lane << 2;
  float a0, a1, a2, a3;
  {
    float d2 = dinv[wid]; d2 *= d2;
    uint2 v = *(const uint2*)(hw + (long)wid * 256 + c0);
    a0 = d2 * b2f((u16)(v.x & 0xFFFF)); a1 = d2 * b2f((u16)(v.x >> 16));
    a2 = d2 * b2f((u16)(v.y & 0xFFFF)); a3 = d2 * b2f((u16)(v.y >> 16));
  }
  int p = rowptr[wid];
  const int end = rowptr[wid + 1];
  for (; p + 1 < end; p += 2) {
    int s0 = eidx[p], s1 = eidx[p + 1];
    float n0 = enrm[p], n1 = enrm[p + 1];
    uint2 v0 = *(const uint2*)(hw + (long)s0 * 256 + c0);
    uint2 v1 = *(const uint2*)(hw + (long)s1 * 256 + c0);
    a0 += n0 * b2f((u16)(v0.x & 0xFFFF)) + n1 * b2f((u16)(v1.x & 0xFFFF));
    a1 += n0 * b2f((u16)(v0.x >> 16))    + n1 * b2f((u16)(v1.x >> 16));
    a2 += n0 * b2f((u16)(v0.y & 0xFFFF)) + n1 * b2f((u16)(v1.y & 0xFFFF));
    a3 += n0 * b2f((u16)(v0.y >> 16))    + n1 * b2f((u16)(v1.y >> 16));
  }
  if (p < end) {
    int s0 = eidx[p];
    float n0 = enrm[p];
    uint2 v0 = *(const uint2*)(hw + (long)s0 * 256 + c0);
    a0 += n0 * b2f((u16)(v0.x & 0xFFFF));
    a1 += n0 * b2f((u16)(v0.x >> 16));
    a2 += n0 * b2f((u16)(v0.y & 0xFFFF));
    a3 += n0 * b2f((u16)(v0.y >> 16));
  }
  uint2 o; o.x = pack2(a0, a1); o.y = pack2(a2, a3);
  *(uint2*)(out + (long)wid * 256 + c0) = o;
}

// ---------------------------------------------------------------- gated conv (VALU, proven r2-r4)
// out(bf16) = relu(P * sigmoid(Q) + R); k=3 pad=1 over t; per-channel stats.
#define CONV_STEP(ACC, W0, W1, W2)                    \
  ACC[0] += xv[0]*W1 + xv[1]*W2;                      \
  ACC[1] += xv[0]*W0 + xv[1]*W1 + xv[2]*W2;           \
  ACC[2] += xv[1]*W0 + xv[2]*W1 + xv[3]*W2;           \
  ACC[3] += xv[2]*W0 + xv[3]*W1 + xv[4]*W2;           \
  ACC[4] += xv[3]*W0 + xv[4]*W1 + xv[5]*W2;           \
  ACC[5] += xv[4]*W0 + xv[5]*W1 + xv[6]*W2;           \
  ACC[6] += xv[5]*W0 + xv[6]*W1 + xv[7]*W2;           \
  ACC[7] += xv[6]*W0 + xv[7]*W1;

template<int FOLD>
__global__ __launch_bounds__(256) void k_gatedv(
    const u16* __restrict__ in, u16* __restrict__ out,
    const float* __restrict__ Wg,   // (3,32,32,3)
    const float* __restrict__ bg,   // (3,32)
    const float* __restrict__ aff, const float* __restrict__ bff, // per-f (256) or null
    float* __restrict__ s1, float* __restrict__ s2)               // [32]
{
  __shared__ float xs[2048];
  __shared__ float wl[3 * 96 * 33];
  __shared__ float red1[128], red2[128];
  const int tid = threadIdx.x;

  for (int idx = tid; idx < 9216; idx += 256) {
    int conv = idx / 3072;
    int r = idx - conv * 3072;
    int co = r / 96;
    int r2 = r - co * 96;                 // ci*3+dt
    wl[conv * 3168 + r2 * 33 + co] = Wg[idx];
  }
  const long base = (long)blockIdx.x * 2048;
  {
    const uint4 v = *((const uint4*)(in + base) + tid);
    float d[8];
    d[0] = b2f((u16)(v.x & 0xFFFF)); d[1] = b2f((u16)(v.x >> 16));
    d[2] = b2f((u16)(v.y & 0xFFFF)); d[3] = b2f((u16)(v.y >> 16));
    d[4] = b2f((u16)(v.z & 0xFFFF)); d[5] = b2f((u16)(v.z >> 16));
    d[6] = b2f((u16)(v.w & 0xFFFF)); d[7] = b2f((u16)(v.w >> 16));
    if (FOLD) {
      const int f0 = (tid & 31) << 3;
#pragma unroll
      for (int j = 0; j < 8; ++j) d[j] = fmaf(aff[f0 + j], d[j], bff[f0 + j]);
    }
    float* dd = xs + tid * 8;
#pragma unroll
    for (int j = 0; j < 8; ++j) dd[j] = d[j];
  }
  __syncthreads();

  const int nl = tid >> 5, c = tid & 31;
  float accP[8], accQ[8], accR[8];
  {
    float bP = bg[c], bQ = bg[32 + c], bR = bg[64 + c];
#pragma unroll
    for (int t = 0; t < 8; ++t) { accP[t] = bP; accQ[t] = bQ; accR[t] = bR; }
  }
  const float* xrow = xs + (nl << 8);
  for (int ci = 0; ci < 32; ++ci) {
    float4 xa = *(const float4*)(xrow + ci * 8);
    float4 xb = *(const float4*)(xrow + ci * 8 + 4);
    float xv[8] = {xa.x, xa.y, xa.z, xa.w, xb.x, xb.y, xb.z, xb.w};
    const float* wb0 = wl + ci * 99 + c;
    {
      float w0 = wb0[0], w1 = wb0[33], w2 = wb0[66];
      CONV_STEP(accP, w0, w1, w2)
    }
    {
      const float* wb = wb0 + 3168;
      float w0 = wb[0], w1 = wb[33], w2 = wb[66];
      CONV_STEP(accQ, w0, w1, w2)
    }
    {
      const float* wb = wb0 + 6336;
      float w0 = wb[0], w1 = wb[33], w2 = wb[66];
      CONV_STEP(accR, w0, w1, w2)
    }
  }
  float hv[8];
  float hsum = 0.0f, hsq = 0.0f;
#pragma unroll
  for (int t = 0; t < 8; ++t) {
    float q = 1.0f / (1.0f + __expf(-accQ[t]));
    float h = fmaxf(accP[t] * q + accR[t], 0.0f);
    hv[t] = h; hsum += h; hsq += h * h;
  }
  {
    uint4 o;
    o.x = pack2(hv[0], hv[1]); o.y = pack2(hv[2], hv[3]);
    o.z = pack2(hv[4], hv[5]); o.w = pack2(hv[6], hv[7]);
    *(uint4*)(out + base + tid * 8) = o;
  }
  float o1 = hsum + __shfl_down(hsum, 32);
  float o2 = hsq + __shfl_down(hsq, 32);
  int wave = tid >> 6, lane = tid & 63;
  if (lane < 32) { red1[wave * 32 + lane] = o1; red2[wave * 32 + lane] = o2; }
  __syncthreads();
  if (tid < 32) {
    float a = red1[tid] + red1[32 + tid] + red1[64 + tid] + red1[96 + tid];
    float b = red2[tid] + red2[32 + tid] + red2[64 + tid] + red2[96 + tid];
    atomicAdd(s1 + tid, a);
    atomicAdd(s2 + tid, b);
  }
}

// ---------------------------------------------------------------- bn finalize
__global__ void k_bnfin(const float* __restrict__ s1, const float* __restrict__ s2,
                        const float* __restrict__ g, const float* __restrict__ b,
                        float cntInv, int nf, int expand,
                        float* __restrict__ A, float* __restrict__ B)
{
  int f = threadIdx.x;
  if (f < nf) {
    int c = expand ? (f >> 3) : f;
    float m = s1[c] * cntInv;
    float var = s2[c] * cntInv - m * m;
    float a = g[c] / sqrtf(var + EPSF);
    A[f] = a;
    B[f] = b[c] - m * a;
  }
}

// ---------------------------------------------------------------- W fold: WT[j][k]=aff[k]*W[k][j]
__global__ __launch_bounds__(256) void k_wfold(
    const float* __restrict__ W, const float* __restrict__ aff,
    u16* __restrict__ WT)
{
  __shared__ float tile[64][68];
  __shared__ float affl[64];
  const int b = blockIdx.x;
  const int kx = (b & 3) * 64, jx = (b >> 2) * 64;
  const int t = threadIdx.x;
  if (t < 64) affl[t] = aff[kx + t];
  {
    int r = t >> 2, c0 = (t & 3) * 16;
#pragma unroll
    for (int i = 0; i < 4; ++i) {
      float4 v = *(const float4*)(W + (long)(kx + r) * 256 + jx + c0 + i * 4);
      tile[r][c0 + i * 4 + 0] = v.x; tile[r][c0 + i * 4 + 1] = v.y;
      tile[r][c0 + i * 4 + 2] = v.z; tile[r][c0 + i * 4 + 3] = v.w;
    }
  }
  __syncthreads();
  {
    int jl = t >> 2, k0 = (t & 3) * 16;
    u16 tmp[16];
#pragma unroll
    for (int kk = 0; kk < 16; ++kk)
      tmp[kk] = f2b(affl[k0 + kk] * tile[k0 + kk][jl]);
    u16* dst = WT + (long)(jx + jl) * 256 + kx + k0;
    *(uint4*)dst = ((uint4*)tmp)[0];
    *(uint4*)(dst + 8) = ((uint4*)tmp)[1];
  }
}

__global__ void k_rowbias(const float* __restrict__ W, const float* __restrict__ bff,
                          float* __restrict__ rb)
{
  int j = threadIdx.x;
  int k0 = blockIdx.x * 32;
  float s = 0.0f;
  for (int kk = 0; kk < 32; ++kk) s += bff[k0 + kk] * W[(long)(k0 + kk) * 256 + j];
  atomicAdd(rb + j, s);
}

// ---------------------------------------------------------------- MFMA GEMM: out = A @ WT^T + rb
__global__ __launch_bounds__(512, 2) void k_gemmm(
    const u16* __restrict__ A, const u16* __restrict__ WT,
    const float* __restrict__ rowbias, u16* __restrict__ Out)
{
  __shared__ u16 At[128 * 64];   // [row][k 64], 16B-chunk XOR-swizzled by row&7
  __shared__ u16 Bt[256 * 64];   // [j][k 64], same swizzle
  const int tid = threadIdx.x, l = tid & 63, w = tid >> 6;
  const long n0 = (long)blockIdx.x * 128;
  const int wr = (w & 1) << 6, wc = (w >> 1) << 6;
  f32x4 acc[4][4];
#pragma unroll
  for (int i = 0; i < 4; ++i)
#pragma unroll
    for (int j = 0; j < 4; ++j) acc[i][j] = (f32x4){0.f, 0.f, 0.f, 0.f};
  float rb[4];
#pragma unroll
  for (int cf = 0; cf < 4; ++cf) rb[cf] = rowbias[wc + (cf << 4) + (l & 15)];

  for (int kt = 0; kt < 4; ++kt) {
    if (kt) __syncthreads();
#pragma unroll
    for (int i = 0; i < 2; ++i) {
      int row = (w << 4) + (i << 3) + (l >> 3);
      int sg = (l & 7) ^ (row & 7);
      long n = n0 + row; if (n >= NN) n = NN - 1;
      gl16(A + n * 256 + kt * 64 + sg * 8, At + ((w << 4) + (i << 3)) * 64);
    }
#pragma unroll
    for (int i = 0; i < 4; ++i) {
      int row = (w << 5) + (i << 3) + (l >> 3);
      int sg = (l & 7) ^ (row & 7);
      gl16(WT + (long)row * 256 + kt * 64 + sg * 8, Bt + ((w << 5) + (i << 3)) * 64);
    }
    __syncthreads();
#pragma unroll
    for (int ks = 0; ks < 2; ++ks) {
      bf16x8 af[4], bf[4];
#pragma unroll
      for (int rf = 0; rf < 4; ++rf) {
        int row = wr + (rf << 4) + (l & 15);
        int slot = ((ks << 2) + (l >> 4)) ^ (row & 7);
        af[rf] = *(const bf16x8*)(At + row * 64 + (slot << 3));
      }
#pragma unroll
      for (int cf = 0; cf < 4; ++cf) {
        int row = wc + (cf << 4) + (l & 15);
        int slot = ((ks << 2) + (l >> 4)) ^ (row & 7);
        bf[cf] = *(const bf16x8*)(Bt + row * 64 + (slot << 3));
      }
#pragma unroll
      for (int rf = 0; rf < 4; ++rf)
#pragma unroll
        for (int cf = 0; cf < 4; ++cf)
          acc[rf][cf] = __builtin_amdgcn_mfma_f32_16x16x32_bf16(
              af[rf], bf[cf], acc[rf][cf], 0, 0, 0);
    }
  }
#pragma unroll
  for (int rf = 0; rf < 4; ++rf)
#pragma unroll
    for (int reg = 0; reg < 4; ++reg) {
      long n = n0 + wr + (rf << 4) + ((l >> 4) << 2) + reg;
      if (n < NN) {
        u16* orow = Out + n * 256 + wc + (l & 15);
#pragma unroll
        for (int cf = 0; cf < 4; ++cf)
          orow[cf << 4] = f2b(acc[rf][cf][reg] + rb[cf]);
      }
    }
}

// ---------------------------------------------------------------- per-feature col stats (bf16 in)
__global__ void k_colstats(const u16* __restrict__ x, int rows,
                           float* __restrict__ s1, float* __restrict__ s2)
{
  int f = threadIdx.x;
  float a = 0.0f, b = 0.0f;
  for (int n = blockIdx.x; n < rows; n += gridDim.x) {
    float v = b2f(x[(long)n * 256 + f]);
    a += v; b += v * v;
  }
  atomicAdd(s1 + f, a);
  atomicAdd(s2 + f, b);
}

// ---------------------------------------------------------------- finalize layer
__global__ __launch_bounds__(256) void k_final(
    u16* __restrict__ x, const u16* __restrict__ h2,
    const float* __restrict__ resW, const float* __restrict__ resb,
    const float* __restrict__ A2, const float* __restrict__ B2,
    float* __restrict__ xl, int mode)
{
  __shared__ float xs[2048];
  __shared__ float wr[32 * 33];
  const int tid = threadIdx.x;
  for (int idx = tid; idx < 1024; idx += 256) {
    int co = idx >> 5, ci = idx & 31;
    wr[ci * 33 + co] = resW[idx];
  }
  const long base = (long)blockIdx.x * 2048;
  {
    const uint4 v = *((const uint4*)(x + base) + tid);
    float* d = xs + tid * 8;
    d[0] = b2f((u16)(v.x & 0xFFFF)); d[1] = b2f((u16)(v.x >> 16));
    d[2] = b2f((u16)(v.y & 0xFFFF)); d[3] = b2f((u16)(v.y >> 16));
    d[4] = b2f((u16)(v.z & 0xFFFF)); d[5] = b2f((u16)(v.z >> 16));
    d[6] = b2f((u16)(v.w & 0xFFFF)); d[7] = b2f((u16)(v.w >> 16));
  }
  __syncthreads();
  const int nl = tid >> 5, c = tid & 31;
  float r[8];
  {
    float rb = resb[c];
#pragma unroll
    for (int t = 0; t < 8; ++t) r[t] = rb;
  }
  const float* xrow = xs + (nl << 8);
  for (int ci = 0; ci < 32; ++ci) {
    float w = wr[ci * 33 + c];
    float4 xa = *(const float4*)(xrow + ci * 8);
    float4 xb = *(const float4*)(xrow + ci * 8 + 4);
    r[0] += xa.x * w; r[1] += xa.y * w; r[2] += xa.z * w; r[3] += xa.w * w;
    r[4] += xb.x * w; r[5] += xb.y * w; r[6] += xb.z * w; r[7] += xb.w * w;
  }
  float a2 = A2[c], b2 = B2[c];
  float hv[8];
  {
    const uint4 v = *((const uint4*)(h2 + base) + tid);
    hv[0] = b2f((u16)(v.x & 0xFFFF)); hv[1] = b2f((u16)(v.x >> 16));
    hv[2] = b2f((u16)(v.y & 0xFFFF)); hv[3] = b2f((u16)(v.y >> 16));
    hv[4] = b2f((u16)(v.z & 0xFFFF)); hv[5] = b2f((u16)(v.z >> 16));
    hv[6] = b2f((u16)(v.w & 0xFFFF)); hv[7] = b2f((u16)(v.w >> 16));
  }
  if (mode == 0) {
    uint4 o;
    float ov[8];
#pragma unroll
    for (int t = 0; t < 8; ++t) ov[t] = fmaxf(fmaf(a2, hv[t], b2) + r[t], 0.0f);
    o.x = pack2(ov[0], ov[1]); o.y = pack2(ov[2], ov[3]);
    o.z = pack2(ov[4], ov[5]); o.w = pack2(ov[6], ov[7]);
    *(uint4*)(x + base + tid * 8) = o;
  } else {
    float v = fmaf(a2, hv[7], b2) + r[7];
    int n = blockIdx.x * 8 + nl;
    xl[n * 32 + c] = v;
  }
}

// ---------------------------------------------------------------- pooling (sorted graphs)
__global__ __launch_bounds__(256) void k_pool(
    const float* __restrict__ xl, const int* __restrict__ graphs,
    int* __restrict__ cnt, float* __restrict__ sp, unsigned* __restrict__ mxu)
{
  __shared__ float lsum[64 * 32];
  __shared__ unsigned lmax[64 * 32];
  __shared__ int lcnt[64];
  const int tid = threadIdx.x;
  const int n0 = blockIdx.x << 8;
  const int nend = min(n0 + 256, NN);
  const int gmin = graphs[n0];
  const int gmax = graphs[nend - 1];
  const int span = gmax - gmin + 1;
  for (int i = tid; i < span * 32; i += 256) { lsum[i] = 0.0f; lmax[i] = 0u; }
  for (int i = tid; i < span; i += 256) lcnt[i] = 0;
  __syncthreads();
  const int c = tid & 31;
  const int nbase = n0 + ((tid >> 5) << 5);
  int curg = -1; float s = 0.0f; unsigned m = 0u; int cn = 0;
  for (int i = 0; i < 32; ++i) {
    int n = nbase + i;
    if (n >= nend) break;
    int g = graphs[n];
    float v = xl[(n << 5) + c];
    unsigned u = __float_as_uint(v);
    u = (u & 0x80000000u) ? ~u : (u | 0x80000000u);
    if (g != curg) {
      if (curg >= 0) {
        atomicAdd(&lsum[((curg - gmin) << 5) + c], s);
        atomicMax(&lmax[((curg - gmin) << 5) + c], m);
        if (c == 0) atomicAdd(&lcnt[curg - gmin], cn);
      }
      curg = g; s = v; m = u; cn = 1;
    } else {
      s += v; m = (u > m) ? u : m; cn++;
    }
  }
  if (curg >= 0) {
    atomicAdd(&lsum[((curg - gmin) << 5) + c], s);
    atomicMax(&lmax[((curg - gmin) << 5) + c], m);
    if (c == 0) atomicAdd(&lcnt[curg - gmin], cn);
  }
  __syncthreads();
  for (int i = tid; i < span * 32; i += 256) {
    atomicAdd(sp + (gmin << 5) + i, lsum[i]);
    atomicMax(mxu + (gmin << 5) + i, lmax[i]);
  }
  for (int i = tid; i < span; i += 256)
    if (lcnt[i]) atomicAdd(cnt + gmin + i, lcnt[i]);
}

// ---------------------------------------------------------------- MLP head
__global__ __launch_bounds__(128) void k_head(
    const int* __restrict__ cnt, const float* __restrict__ sp,
    const unsigned* __restrict__ mxu,
    const float* __restrict__ W1, const float* __restrict__ b1,
    const float* __restrict__ W2, const float* __restrict__ b2,
    const float* __restrict__ W3, const float* __restrict__ b3,
    float* __restrict__ out)
{
  __shared__ float xg[96], hh1[128], hh2[64];
  const int g = blockIdx.x, tid = threadIdx.x;
  if (tid < 32) {
    float s = sp[g * 32 + tid];
    int cn = cnt[g];
    float mean = s / fmaxf((float)cn, 1.0f);
    float mx = 0.0f;
    if (cn > 0) {
      unsigned u = mxu[g * 32 + tid];
      unsigned ub = (u & 0x80000000u) ? (u ^ 0x80000000u) : ~u;
      mx = __uint_as_float(ub);
    }
    xg[tid] = mean; xg[32 + tid] = mx; xg[64 + tid] = s;
  }
  __syncthreads();
  {
    float a = b1[tid];
    for (int k = 0; k < 96; ++k) a += xg[k] * W1[k * 128 + tid];
    hh1[tid] = fmaxf(a, 0.0f);
  }
  __syncthreads();
  if (tid < 64) {
    float a = b2[tid];
    for (int k = 0; k < 128; ++k) a += hh1[k] * W2[k * 64 + tid];
    hh2[tid] = fmaxf(a, 0.0f);
  }
  __syncthreads();
  if (tid < 64) {
    float p = hh2[tid] * W3[tid];
    for (int off = 32; off; off >>= 1) p += __shfl_down(p, off);
    if (tid == 0) out[g] = p + b3[0];
  }
}

// ================================================================ launch
extern "C" void kernel_launch(void* const* d_in, const int* in_sizes, int n_in,
                              void* d_out, int out_size, void* d_ws, size_t ws_size,
                              hipStream_t stream)
{
  const float* X       = (const float*)d_in[0];
  const int*   edge    = (const int*)d_in[1];
  const int*   graphs  = (const int*)d_in[2];
  const float* W_in    = (const float*)d_in[3];
  const float* b_in    = (const float*)d_in[4];
  const float* res_W   = (const float*)d_in[5];
  const float* res_b   = (const float*)d_in[6];
  const float* g1_W    = (const float*)d_in[7];
  const float* g1_b    = (const float*)d_in[8];
  const float* bn0_g   = (const float*)d_in[9];
  const float* bn0_b   = (const float*)d_in[10];
  const float* gcn_W   = (const float*)d_in[11];
  // d_in[12] = gcn_b: cancels in bn1 (per-feature shift removed by mean over axis 0)
  const float* bn1_g   = (const float*)d_in[13];
  const float* bn1_b   = (const float*)d_in[14];
  const float* g2_W    = (const float*)d_in[15];
  const float* g2_b    = (const float*)d_in[16];
  const float* bn2_g   = (const float*)d_in[17];
  const float* bn2_b   = (const float*)d_in[18];
  const float* out_W1  = (const float*)d_in[19];
  const float* out_b1  = (const float*)d_in[20];
  const float* out_W2  = (const float*)d_in[21];
  const float* out_b2  = (const float*)d_in[22];
  const float* out_W3  = (const float*)d_in[23];
  const float* out_b3  = (const float*)d_in[24];
  float* outp = (float*)d_out;

  const int* srcp = edge;
  const int* dstp = edge + EE;

  // ---- workspace layout (~113 MB) ----
  const long BIGE = (long)NN * 256;              // 12.8M elems
  u16*   P0   = (u16*)d_ws;                      // x bf16
  u16*   P1   = P0 + BIGE;                       // h1 / h2 bf16
  u16*   P2   = P1 + BIGE;                       // gather out bf16
  u16*   P3   = P2 + BIGE;                       // gemm out bf16
  u16*   WT   = P3 + BIGE;                       // 65536 u16
  float* xl   = (float*)(WT + 65536);            // N*32
  float* dinv = xl + (long)NN * 32;              // N
  int*   rowptr = (int*)(dinv + NN);             // N+1
  int*   cursor = rowptr + NN + 1;               // N
  int*   eidx   = cursor + NN;                   // E
  float* enrm   = (float*)(eidx + EE);           // E
  int*   bsum   = (int*)(enrm + EE);             // NB
  int*   boff   = bsum + NB;                     // NB
  int*   degi = boff + NB;                       // N      <- zero region start
  float* stats = (float*)(degi + NN);            // 1280
  int*   cnt  = (int*)(stats + 1280);            // 64
  float* sp   = (float*)(cnt + 64);              // 2048
  unsigned* mxu = (unsigned*)(sp + 2048);        // 2048
  float* rbias = (float*)(mxu + 2048);           // 512    <- zero region end
  float* AFF  = rbias + 512;                     // 256
  float* BFF  = AFF + 256;
  float* A2v  = BFF + 256;
  float* B2v  = A2v + 32;

  const size_t zero_bytes = (size_t)(NN + 1280 + 64 + 2048 + 2048 + 512) * 4;
  hipMemsetAsync(degi, 0, zero_bytes, stream);

  k_convin<<<NN / 8, 256, 0, stream>>>(X, P0, W_in, b_in);
  k_deg<<<(EE + 255) / 256, 256, 0, stream>>>(dstp, degi);
  k_dinv<<<(NN + 255) / 256, 256, 0, stream>>>(degi, dinv);
  k_psum<<<NB, 256, 0, stream>>>(degi, bsum);
  k_bscan<<<1, 256, 0, stream>>>(bsum, boff);
  k_scan2<<<NB, 256, 0, stream>>>(degi, boff, rowptr, cursor);
  k_fill<<<(EE + 255) / 256, 256, 0, stream>>>(srcp, dstp, dinv, cursor, eidx, enrm);

  for (int l = 0; l < 2; ++l) {
    const float* g1Wl = g1_W + l * 9216;
    const float* g1bl = g1_b + l * 96;
    const float* g2Wl = g2_W + l * 9216;
    const float* g2bl = g2_b + l * 96;
    const float* gWl  = gcn_W + l * 65536;
    float* st = stats + l * 640;
    float* rbl = rbias + l * 256;

    // gated conv 1 (VALU, bf16 I/O) + bn0 stats
    k_gatedv<0><<<NN / 8, 256, 0, stream>>>(P0, P1, g1Wl, g1bl, nullptr, nullptr,
                                            st + 0, st + 32);
    k_bnfin<<<1, 256, 0, stream>>>(st + 0, st + 32, bn0_g + l * 32, bn0_b + l * 32,
                                   1.0f / 400000.0f, 256, 1, AFF, BFF);
    // fold bn0 into W (transposed bf16) + row bias
    k_wfold<<<16, 256, 0, stream>>>(gWl, AFF, WT);
    k_rowbias<<<8, 256, 0, stream>>>(gWl, BFF, rbl);
    // MFMA GEMM: P3 = P1 @ Wfold + rb
    k_gemmm<<<(NN + 127) / 128, 512, 0, stream>>>(P1, WT, rbl, P3);
    // GCN aggregation: CSR gather (self-loop included)
    k_gather<<<(NN + 3) / 4, 256, 0, stream>>>(P3, P2, rowptr, eidx, enrm, dinv);
    // bn1 stats + fold
    k_colstats<<<512, 256, 0, stream>>>(P2, NN, st + 64, st + 320);
    k_bnfin<<<1, 256, 0, stream>>>(st + 64, st + 320, bn1_g + l * 256, bn1_b + l * 256,
                                   1.0f / (float)NN, 256, 0, AFF, BFF);
    // gated conv 2 (VALU, bn1 fold on input) + bn2 stats
    k_gatedv<1><<<NN / 8, 256, 0, stream>>>(P2, P1, g2Wl, g2bl, AFF, BFF,
                                            st + 576, st + 608);
    k_bnfin<<<1, 256, 0, stream>>>(st + 576, st + 608, bn2_g + l * 32, bn2_b + l * 32,
                                   1.0f / 400000.0f, 32, 0, A2v, B2v);
    // finalize: bn2 + residual(x) + (relu in-place | t=7 slice)
    k_final<<<NN / 8, 256, 0, stream>>>(P0, P1, res_W + l * 1024, res_b + l * 32,
                                        A2v, B2v, xl, (l == 0) ? 0 : 1);
  }

  k_pool<<<(NN + 255) / 256, 256, 0, stream>>>(xl, graphs, cnt, sp, mxu);
  k_head<<<64, 128, 0, stream>>>(cnt, sp, mxu, out_W1, out_b1, out_W2, out_b2,
                                 out_W3, out_b3, outp);

  (void)in_sizes; (void)n_in; (void)out_size; (void)ws_size;
}

// Round 8
// 986.659 us; speedup vs baseline: 4.6786x; 1.3448x over previous
//
#include <hip/hip_runtime.h>
#include <hip/hip_bf16.h>

#define NN 50000
#define EE 400000
#define EPSF 1e-5f
#define NB 196   // (NN+255)/256
#define NGATED 1280   // 5 blocks/CU x 256 CU

typedef unsigned short u16;
typedef __attribute__((ext_vector_type(8))) short bf16x8;
typedef __attribute__((ext_vector_type(4))) float f32x4;

__device__ __forceinline__ float b2f(u16 u) { return __uint_as_float(((unsigned)u) << 16); }
__device__ __forceinline__ u16 f2b(float f) {
  unsigned x = __float_as_uint(f);
  unsigned r = x + 0x7FFFu + ((x >> 16) & 1u);   // RNE
  return (u16)(r >> 16);
}
__device__ __forceinline__ unsigned pack2(float lo, float hi) {
  return (unsigned)f2b(lo) | ((unsigned)f2b(hi) << 16);
}
__device__ __forceinline__ void gl16(const void* g, void* l) {
  __builtin_amdgcn_global_load_lds(
      (const __attribute__((address_space(1))) void*)g,
      (__attribute__((address_space(3))) void*)l, 16, 0, 0);
}

// ---------------------------------------------------------------- conv_in
__global__ __launch_bounds__(256) void k_convin(
    const float* __restrict__ X, u16* __restrict__ out,
    const float* __restrict__ Wi, const float* __restrict__ bi)
{
  __shared__ float xs[1024];
  __shared__ float wi[16 * 33];
  const int tid = threadIdx.x;
  for (int idx = tid; idx < 512; idx += 256) {
    int co = idx >> 4, ci = idx & 15;
    wi[ci * 33 + co] = Wi[idx];
  }
  const long xbase = (long)blockIdx.x * 1024;
  ((float4*)xs)[tid] = ((const float4*)(X + xbase))[tid];
  __syncthreads();
  const int nl = tid >> 5, c = tid & 31;
  float acc[8];
  {
    float bc = bi[c];
#pragma unroll
    for (int t = 0; t < 8; ++t) acc[t] = bc;
  }
  const float* xrow = xs + (nl << 7);
  for (int ci = 0; ci < 16; ++ci) {
    float w = wi[ci * 33 + c];
    float4 xa = *(const float4*)(xrow + ci * 8);
    float4 xb = *(const float4*)(xrow + ci * 8 + 4);
    acc[0] += xa.x * w; acc[1] += xa.y * w; acc[2] += xa.z * w; acc[3] += xa.w * w;
    acc[4] += xb.x * w; acc[5] += xb.y * w; acc[6] += xb.z * w; acc[7] += xb.w * w;
  }
  uint4 o;
  o.x = pack2(acc[0], acc[1]); o.y = pack2(acc[2], acc[3]);
  o.z = pack2(acc[4], acc[5]); o.w = pack2(acc[6], acc[7]);
  *(uint4*)(out + (long)blockIdx.x * 2048 + tid * 8) = o;
}

// ---------------------------------------------------------------- degree / dinv
__global__ void k_deg(const int* __restrict__ dst, int* __restrict__ degi)
{
  int e = blockIdx.x * 256 + threadIdx.x;
  if (e < EE) atomicAdd(degi + dst[e], 1);
}
__global__ void k_dinv(const int* __restrict__ degi, float* __restrict__ dinv)
{
  int n = blockIdx.x * 256 + threadIdx.x;
  if (n < NN) dinv[n] = rsqrtf((float)degi[n] + 1.0f);
}

// ---------------------------------------------------------------- CSR build
__global__ __launch_bounds__(256) void k_psum(const int* __restrict__ degi,
                                              int* __restrict__ bsum)
{
  __shared__ int red[4];
  const int tid = threadIdx.x;
  int i = blockIdx.x * 256 + tid;
  int v = (i < NN) ? degi[i] : 0;
#pragma unroll
  for (int d = 32; d >= 1; d >>= 1) v += __shfl_down(v, d);
  if ((tid & 63) == 0) red[tid >> 6] = v;
  __syncthreads();
  if (tid == 0) bsum[blockIdx.x] = red[0] + red[1] + red[2] + red[3];
}

__global__ __launch_bounds__(256) void k_bscan(const int* __restrict__ bsum,
                                               int* __restrict__ boff)
{
  __shared__ int wsum[4];
  const int tid = threadIdx.x, lane = tid & 63, wv = tid >> 6;
  int v = (tid < NB) ? bsum[tid] : 0;
  int s = v;
#pragma unroll
  for (int d = 1; d < 64; d <<= 1) { int t = __shfl_up(s, d); if (lane >= d) s += t; }
  if (lane == 63) wsum[wv] = s;
  __syncthreads();
  int wo = 0;
  for (int w = 0; w < wv; ++w) wo += wsum[w];
  if (tid < NB) boff[tid] = wo + s - v;
}

__global__ __launch_bounds__(256) void k_scan2(const int* __restrict__ degi,
                                               const int* __restrict__ boff,
                                               int* __restrict__ rowptr,
                                               int* __restrict__ cursor)
{
  __shared__ int wsum[4];
  const int tid = threadIdx.x, lane = tid & 63, wv = tid >> 6;
  int i = blockIdx.x * 256 + tid;
  int v = (i < NN) ? degi[i] : 0;
  int s = v;
#pragma unroll
  for (int d = 1; d < 64; d <<= 1) { int t = __shfl_up(s, d); if (lane >= d) s += t; }
  if (lane == 63) wsum[wv] = s;
  __syncthreads();
  int wo = 0;
  for (int w = 0; w < wv; ++w) wo += wsum[w];
  int excl = boff[blockIdx.x] + wo + (s - v);
  if (i < NN) { rowptr[i] = excl; cursor[i] = excl; }
  if (i == NN) rowptr[NN] = excl;
}

__global__ void k_fill(const int* __restrict__ src, const int* __restrict__ dst,
                       const float* __restrict__ dinv,
                       int* __restrict__ cursor,
                       int* __restrict__ eidx, float* __restrict__ enrm)
{
  int e = blockIdx.x * 256 + threadIdx.x;
  if (e < EE) {
    int s = src[e], d = dst[e];
    int p = atomicAdd(cursor + d, 1);
    eidx[p] = s;
    enrm[p] = dinv[s] * dinv[d];
  }
}

// ---------------------------------------------------------------- GCN gather (bf16 in, bf16 out)
__global__ __launch_bounds__(256) void k_gather(
    const u16* __restrict__ hw, u16* __restrict__ out,
    const int* __restrict__ rowptr, const int* __restrict__ eidx,
    const float* __restrict__ enrm, const float* __restrict__ dinv)
{
  const int wid = (blockIdx.x << 2) + (threadIdx.x >> 6);
  if (wid >= NN) return;
  const int lane = threadIdx.x & 63;
  const int c0 = lane << 2;
  float a0, a1, a2, a3;
  {
    float d2 = dinv[wid]; d2 *= d2;
    uint2 v = *(const uint2*)(hw + (long)wid * 256 + c0);
    a0 = d2 * b2f((u16)(v.x & 0xFFFF)); a1 = d2 * b2f((u16)(v.x >> 16));
    a2 = d2 * b2f((u16)(v.y & 0xFFFF)); a3 = d2 * b2f((u16)(v.y >> 16));
  }
  int p = rowptr[wid];
  const int end = rowptr[wid + 1];
  for (; p + 1 < end; p += 2) {
    int s0 = eidx[p], s1 = eidx[p + 1];
    float n0 = enrm[p], n1 = enrm[p + 1];
    uint2 v0 = *(const uint2*)(hw + (long)s0 * 256 + c0);
    uint2 v1 = *(const uint2*)(hw + (long)s1 * 256 + c0);
    a0 += n0 * b2f((u16)(v0.x & 0xFFFF)) + n1 * b2f((u16)(v1.x & 0xFFFF));
    a1 += n0 * b2f((u16)(v0.x >> 16))    + n1 * b2f((u16)(v1.x >> 16));
    a2 += n0 * b2f((u16)(v0.y & 0xFFFF)) + n1 * b2f((u16)(v1.y & 0xFFFF));
    a3 += n0 * b2f((u16)(v0.y >> 16))    + n1 * b2f((u16)(v1.y >> 16));
  }
  if (p < end) {
    int s0 = eidx[p];
    float n0 = enrm[p];
    uint2 v0 = *(const uint2*)(hw + (long)s0 * 256 + c0);
    a0 += n0 * b2f((u16)(v0.x & 0xFFFF));
    a1 += n0 * b2f((u16)(v0.x >> 16));
    a2 += n0 * b2f((u16)(v0.y & 0xFFFF));
    a3 += n0 * b2f((u16)(v0.y >> 16));
  }
  uint2 o; o.x = pack2(a0, a1); o.y = pack2(a2, a3);
  *(uint2*)(out + (long)wid * 256 + c0) = o;
}

// ---------------------------------------------------------------- gated conv (VALU, bf16 weights in LDS, tile-strided)
// out(bf16) = relu(P * sigmoid(Q) + R); k=3 pad=1 over t; per-channel stats.
#define CONV_STEP(ACC, W0, W1, W2)                    \
  ACC[0] += xv[0]*W1 + xv[1]*W2;                      \
  ACC[1] += xv[0]*W0 + xv[1]*W1 + xv[2]*W2;           \
  ACC[2] += xv[1]*W0 + xv[2]*W1 + xv[3]*W2;           \
  ACC[3] += xv[2]*W0 + xv[3]*W1 + xv[4]*W2;           \
  ACC[4] += xv[3]*W0 + xv[4]*W1 + xv[5]*W2;           \
  ACC[5] += xv[4]*W0 + xv[5]*W1 + xv[6]*W2;           \
  ACC[6] += xv[5]*W0 + xv[6]*W1 + xv[7]*W2;           \
  ACC[7] += xv[6]*W0 + xv[7]*W1;

template<int FOLD>
__global__ __launch_bounds__(256) void k_gatedv(
    const u16* __restrict__ in, u16* __restrict__ out,
    const float* __restrict__ Wg,   // (3,32,32,3)
    const float* __restrict__ bg,   // (3,32)
    const float* __restrict__ aff, const float* __restrict__ bff, // per-f (256) or null
    float* __restrict__ s1, float* __restrict__ s2)               // [32]
{
  __shared__ float xs[2048];            // 8 KB
  __shared__ u16 wl[3 * 3264];          // bf16 weights [(ci*3+dt)*34 + co], 19.6 KB
  __shared__ float red1[128], red2[128];
  const int tid = threadIdx.x;

  // stage weights once per block (bf16)
  for (int idx = tid; idx < 9216; idx += 256) {
    int conv = idx / 3072;
    int r = idx - conv * 3072;
    int co = r / 96;
    int r2 = r - co * 96;                 // ci*3+dt
    wl[conv * 3264 + r2 * 34 + co] = f2b(Wg[idx]);
  }

  const int nl = tid >> 5, c = tid & 31;
  const float bP = bg[c], bQ = bg[32 + c], bR = bg[64 + c];
  float gsum = 0.0f, gsq = 0.0f;        // stats accumulated across tiles

  for (int tile = blockIdx.x; tile < NN / 8; tile += gridDim.x) {
    __syncthreads();                    // xs free from previous tile (1st iter: weights done)
    const long base = (long)tile * 2048;
    {
      const uint4 v = *((const uint4*)(in + base) + tid);
      float d[8];
      d[0] = b2f((u16)(v.x & 0xFFFF)); d[1] = b2f((u16)(v.x >> 16));
      d[2] = b2f((u16)(v.y & 0xFFFF)); d[3] = b2f((u16)(v.y >> 16));
      d[4] = b2f((u16)(v.z & 0xFFFF)); d[5] = b2f((u16)(v.z >> 16));
      d[6] = b2f((u16)(v.w & 0xFFFF)); d[7] = b2f((u16)(v.w >> 16));
      if (FOLD) {
        const int f0 = (tid & 31) << 3;
#pragma unroll
        for (int j = 0; j < 8; ++j) d[j] = fmaf(aff[f0 + j], d[j], bff[f0 + j]);
      }
      float* dd = xs + tid * 8;
#pragma unroll
      for (int j = 0; j < 8; ++j) dd[j] = d[j];
    }
    __syncthreads();

    float accP[8], accQ[8], accR[8];
#pragma unroll
    for (int t = 0; t < 8; ++t) { accP[t] = bP; accQ[t] = bQ; accR[t] = bR; }
    const float* xrow = xs + (nl << 8);
    for (int ci = 0; ci < 32; ++ci) {
      float4 xa = *(const float4*)(xrow + ci * 8);
      float4 xb = *(const float4*)(xrow + ci * 8 + 4);
      float xv[8] = {xa.x, xa.y, xa.z, xa.w, xb.x, xb.y, xb.z, xb.w};
      const u16* wb0 = wl + ci * 102 + c;
      {
        float w0 = b2f(wb0[0]), w1 = b2f(wb0[34]), w2 = b2f(wb0[68]);
        CONV_STEP(accP, w0, w1, w2)
      }
      {
        const u16* wb = wb0 + 3264;
        float w0 = b2f(wb[0]), w1 = b2f(wb[34]), w2 = b2f(wb[68]);
        CONV_STEP(accQ, w0, w1, w2)
      }
      {
        const u16* wb = wb0 + 6528;
        float w0 = b2f(wb[0]), w1 = b2f(wb[34]), w2 = b2f(wb[68]);
        CONV_STEP(accR, w0, w1, w2)
      }
    }
    float hv[8];
#pragma unroll
    for (int t = 0; t < 8; ++t) {
      float q = 1.0f / (1.0f + __expf(-accQ[t]));
      float h = fmaxf(accP[t] * q + accR[t], 0.0f);
      hv[t] = h; gsum += h; gsq += h * h;
    }
    uint4 o;
    o.x = pack2(hv[0], hv[1]); o.y = pack2(hv[2], hv[3]);
    o.z = pack2(hv[4], hv[5]); o.w = pack2(hv[6], hv[7]);
    *(uint4*)(out + base + tid * 8) = o;
  }

  // one block-level stats reduction at the end
  float o1 = gsum + __shfl_down(gsum, 32);
  float o2 = gsq + __shfl_down(gsq, 32);
  int wave = tid >> 6, lane = tid & 63;
  if (lane < 32) { red1[wave * 32 + lane] = o1; red2[wave * 32 + lane] = o2; }
  __syncthreads();
  if (tid < 32) {
    float a = red1[tid] + red1[32 + tid] + red1[64 + tid] + red1[96 + tid];
    float b = red2[tid] + red2[32 + tid] + red2[64 + tid] + red2[96 + tid];
    atomicAdd(s1 + tid, a);
    atomicAdd(s2 + tid, b);
  }
}

// ---------------------------------------------------------------- bn finalize
__global__ void k_bnfin(const float* __restrict__ s1, const float* __restrict__ s2,
                        const float* __restrict__ g, const float* __restrict__ b,
                        float cntInv, int nf, int expand,
                        float* __restrict__ A, float* __restrict__ B)
{
  int f = threadIdx.x;
  if (f < nf) {
    int c = expand ? (f >> 3) : f;
    float m = s1[c] * cntInv;
    float var = s2[c] * cntInv - m * m;
    float a = g[c] / sqrtf(var + EPSF);
    A[f] = a;
    B[f] = b[c] - m * a;
  }
}

// ---------------------------------------------------------------- W fold: WT[j][k]=aff[k]*W[k][j]
__global__ __launch_bounds__(256) void k_wfold(
    const float* __restrict__ W, const float* __restrict__ aff,
    u16* __restrict__ WT)
{
  __shared__ float tile[64][68];
  __shared__ float affl[64];
  const int b = blockIdx.x;
  const int kx = (b & 3) * 64, jx = (b >> 2) * 64;
  const int t = threadIdx.x;
  if (t < 64) affl[t] = aff[kx + t];
  {
    int r = t >> 2, c0 = (t & 3) * 16;
#pragma unroll
    for (int i = 0; i < 4; ++i) {
      float4 v = *(const float4*)(W + (long)(kx + r) * 256 + jx + c0 + i * 4);
      tile[r][c0 + i * 4 + 0] = v.x; tile[r][c0 + i * 4 + 1] = v.y;
      tile[r][c0 + i * 4 + 2] = v.z; tile[r][c0 + i * 4 + 3] = v.w;
    }
  }
  __syncthreads();
  {
    int jl = t >> 2, k0 = (t & 3) * 16;
    u16 tmp[16];
#pragma unroll
    for (int kk = 0; kk < 16; ++kk)
      tmp[kk] = f2b(affl[k0 + kk] * tile[k0 + kk][jl]);
    u16* dst = WT + (long)(jx + jl) * 256 + kx + k0;
    *(uint4*)dst = ((uint4*)tmp)[0];
    *(uint4*)(dst + 8) = ((uint4*)tmp)[1];
  }
}

__global__ void k_rowbias(const float* __restrict__ W, const float* __restrict__ bff,
                          float* __restrict__ rb)
{
  int j = threadIdx.x;
  int k0 = blockIdx.x * 32;
  float s = 0.0f;
  for (int kk = 0; kk < 32; ++kk) s += bff[k0 + kk] * W[(long)(k0 + kk) * 256 + j];
  atomicAdd(rb + j, s);
}

// ---------------------------------------------------------------- MFMA GEMM: out = A @ WT^T + rb
__global__ __launch_bounds__(512, 2) void k_gemmm(
    const u16* __restrict__ A, const u16* __restrict__ WT,
    const float* __restrict__ rowbias, u16* __restrict__ Out)
{
  __shared__ u16 At[128 * 64];   // [row][k 64], 16B-chunk XOR-swizzled by row&7
  __shared__ u16 Bt[256 * 64];   // [j][k 64], same swizzle
  const int tid = threadIdx.x, l = tid & 63, w = tid >> 6;
  const long n0 = (long)blockIdx.x * 128;
  const int wr = (w & 1) << 6, wc = (w >> 1) << 6;
  f32x4 acc[4][4];
#pragma unroll
  for (int i = 0; i < 4; ++i)
#pragma unroll
    for (int j = 0; j < 4; ++j) acc[i][j] = (f32x4){0.f, 0.f, 0.f, 0.f};
  float rb[4];
#pragma unroll
  for (int cf = 0; cf < 4; ++cf) rb[cf] = rowbias[wc + (cf << 4) + (l & 15)];

  for (int kt = 0; kt < 4; ++kt) {
    if (kt) __syncthreads();
#pragma unroll
    for (int i = 0; i < 2; ++i) {
      int row = (w << 4) + (i << 3) + (l >> 3);
      int sg = (l & 7) ^ (row & 7);
      long n = n0 + row; if (n >= NN) n = NN - 1;
      gl16(A + n * 256 + kt * 64 + sg * 8, At + ((w << 4) + (i << 3)) * 64);
    }
#pragma unroll
    for (int i = 0; i < 4; ++i) {
      int row = (w << 5) + (i << 3) + (l >> 3);
      int sg = (l & 7) ^ (row & 7);
      gl16(WT + (long)row * 256 + kt * 64 + sg * 8, Bt + ((w << 5) + (i << 3)) * 64);
    }
    __syncthreads();
#pragma unroll
    for (int ks = 0; ks < 2; ++ks) {
      bf16x8 af[4], bf[4];
#pragma unroll
      for (int rf = 0; rf < 4; ++rf) {
        int row = wr + (rf << 4) + (l & 15);
        int slot = ((ks << 2) + (l >> 4)) ^ (row & 7);
        af[rf] = *(const bf16x8*)(At + row * 64 + (slot << 3));
      }
#pragma unroll
      for (int cf = 0; cf < 4; ++cf) {
        int row = wc + (cf << 4) + (l & 15);
        int slot = ((ks << 2) + (l >> 4)) ^ (row & 7);
        bf[cf] = *(const bf16x8*)(Bt + row * 64 + (slot << 3));
      }
#pragma unroll
      for (int rf = 0; rf < 4; ++rf)
#pragma unroll
        for (int cf = 0; cf < 4; ++cf)
          acc[rf][cf] = __builtin_amdgcn_mfma_f32_16x16x32_bf16(
              af[rf], bf[cf], acc[rf][cf], 0, 0, 0);
    }
  }
#pragma unroll
  for (int rf = 0; rf < 4; ++rf)
#pragma unroll
    for (int reg = 0; reg < 4; ++reg) {
      long n = n0 + wr + (rf << 4) + ((l >> 4) << 2) + reg;
      if (n < NN) {
        u16* orow = Out + n * 256 + wc + (l & 15);
#pragma unroll
        for (int cf = 0; cf < 4; ++cf)
          orow[cf << 4] = f2b(acc[rf][cf][reg] + rb[cf]);
      }
    }
}

// ---------------------------------------------------------------- per-feature col stats (bf16 in)
__global__ void k_colstats(const u16* __restrict__ x, int rows,
                           float* __restrict__ s1, float* __restrict__ s2)
{
  int f = threadIdx.x;
  float a = 0.0f, b = 0.0f;
  for (int n = blockIdx.x; n < rows; n += gridDim.x) {
    float v = b2f(x[(long)n * 256 + f]);
    a += v; b += v * v;
  }
  atomicAdd(s1 + f, a);
  atomicAdd(s2 + f, b);
}

// ---------------------------------------------------------------- finalize layer
__global__ __launch_bounds__(256) void k_final(
    u16* __restrict__ x, const u16* __restrict__ h2,
    const float* __restrict__ resW, const float* __restrict__ resb,
    const float* __restrict__ A2, const float* __restrict__ B2,
    float* __restrict__ xl, int mode)
{
  __shared__ float xs[2048];
  __shared__ float wr[32 * 33];
  const int tid = threadIdx.x;
  for (int idx = tid; idx < 1024; idx += 256) {
    int co = idx >> 5, ci = idx & 31;
    wr[ci * 33 + co] = resW[idx];
  }
  const long base = (long)blockIdx.x * 2048;
  {
    const uint4 v = *((const uint4*)(x + base) + tid);
    float* d = xs + tid * 8;
    d[0] = b2f((u16)(v.x & 0xFFFF)); d[1] = b2f((u16)(v.x >> 16));
    d[2] = b2f((u16)(v.y & 0xFFFF)); d[3] = b2f((u16)(v.y >> 16));
    d[4] = b2f((u16)(v.z & 0xFFFF)); d[5] = b2f((u16)(v.z >> 16));
    d[6] = b2f((u16)(v.w & 0xFFFF)); d[7] = b2f((u16)(v.w >> 16));
  }
  __syncthreads();
  const int nl = tid >> 5, c = tid & 31;
  float r[8];
  {
    float rb = resb[c];
#pragma unroll
    for (int t = 0; t < 8; ++t) r[t] = rb;
  }
  const float* xrow = xs + (nl << 8);
  for (int ci = 0; ci < 32; ++ci) {
    float w = wr[ci * 33 + c];
    float4 xa = *(const float4*)(xrow + ci * 8);
    float4 xb = *(const float4*)(xrow + ci * 8 + 4);
    r[0] += xa.x * w; r[1] += xa.y * w; r[2] += xa.z * w; r[3] += xa.w * w;
    r[4] += xb.x * w; r[5] += xb.y * w; r[6] += xb.z * w; r[7] += xb.w * w;
  }
  float a2 = A2[c], b2 = B2[c];
  float hv[8];
  {
    const uint4 v = *((const uint4*)(h2 + base) + tid);
    hv[0] = b2f((u16)(v.x & 0xFFFF)); hv[1] = b2f((u16)(v.x >> 16));
    hv[2] = b2f((u16)(v.y & 0xFFFF)); hv[3] = b2f((u16)(v.y >> 16));
    hv[4] = b2f((u16)(v.z & 0xFFFF)); hv[5] = b2f((u16)(v.z >> 16));
    hv[6] = b2f((u16)(v.w & 0xFFFF)); hv[7] = b2f((u16)(v.w >> 16));
  }
  if (mode == 0) {
    uint4 o;
    float ov[8];
#pragma unroll
    for (int t = 0; t < 8; ++t) ov[t] = fmaxf(fmaf(a2, hv[t], b2) + r[t], 0.0f);
    o.x = pack2(ov[0], ov[1]); o.y = pack2(ov[2], ov[3]);
    o.z = pack2(ov[4], ov[5]); o.w = pack2(ov[6], ov[7]);
    *(uint4*)(x + base + tid * 8) = o;
  } else {
    float v = fmaf(a2, hv[7], b2) + r[7];
    int n = blockIdx.x * 8 + nl;
    xl[n * 32 + c] = v;
  }
}

// ---------------------------------------------------------------- pooling (sorted graphs)
__global__ __launch_bounds__(256) void k_pool(
    const float* __restrict__ xl, const int* __restrict__ graphs,
    int* __restrict__ cnt, float* __restrict__ sp, unsigned* __restrict__ mxu)
{
  __shared__ float lsum[64 * 32];
  __shared__ unsigned lmax[64 * 32];
  __shared__ int lcnt[64];
  const int tid = threadIdx.x;
  const int n0 = blockIdx.x << 8;
  const int nend = min(n0 + 256, NN);
  const int gmin = graphs[n0];
  const int gmax = graphs[nend - 1];
  const int span = gmax - gmin + 1;
  for (int i = tid; i < span * 32; i += 256) { lsum[i] = 0.0f; lmax[i] = 0u; }
  for (int i = tid; i < span; i += 256) lcnt[i] = 0;
  __syncthreads();
  const int c = tid & 31;
  const int nbase = n0 + ((tid >> 5) << 5);
  int curg = -1; float s = 0.0f; unsigned m = 0u; int cn = 0;
  for (int i = 0; i < 32; ++i) {
    int n = nbase + i;
    if (n >= nend) break;
    int g = graphs[n];
    float v = xl[(n << 5) + c];
    unsigned u = __float_as_uint(v);
    u = (u & 0x80000000u) ? ~u : (u | 0x80000000u);
    if (g != curg) {
      if (curg >= 0) {
        atomicAdd(&lsum[((curg - gmin) << 5) + c], s);
        atomicMax(&lmax[((curg - gmin) << 5) + c], m);
        if (c == 0) atomicAdd(&lcnt[curg - gmin], cn);
      }
      curg = g; s = v; m = u; cn = 1;
    } else {
      s += v; m = (u > m) ? u : m; cn++;
    }
  }
  if (curg >= 0) {
    atomicAdd(&lsum[((curg - gmin) << 5) + c], s);
    atomicMax(&lmax[((curg - gmin) << 5) + c], m);
    if (c == 0) atomicAdd(&lcnt[curg - gmin], cn);
  }
  __syncthreads();
  for (int i = tid; i < span * 32; i += 256) {
    atomicAdd(sp + (gmin << 5) + i, lsum[i]);
    atomicMax(mxu + (gmin << 5) + i, lmax[i]);
  }
  for (int i = tid; i < span; i += 256)
    if (lcnt[i]) atomicAdd(cnt + gmin + i, lcnt[i]);
}

// ---------------------------------------------------------------- MLP head
__global__ __launch_bounds__(128) void k_head(
    const int* __restrict__ cnt, const float* __restrict__ sp,
    const unsigned* __restrict__ mxu,
    const float* __restrict__ W1, const float* __restrict__ b1,
    const float* __restrict__ W2, const float* __restrict__ b2,
    const float* __restrict__ W3, const float* __restrict__ b3,
    float* __restrict__ out)
{
  __shared__ float xg[96], hh1[128], hh2[64];
  const int g = blockIdx.x, tid = threadIdx.x;
  if (tid < 32) {
    float s = sp[g * 32 + tid];
    int cn = cnt[g];
    float mean = s / fmaxf((float)cn, 1.0f);
    float mx = 0.0f;
    if (cn > 0) {
      unsigned u = mxu[g * 32 + tid];
      unsigned ub = (u & 0x80000000u) ? (u ^ 0x80000000u) : ~u;
      mx = __uint_as_float(ub);
    }
    xg[tid] = mean; xg[32 + tid] = mx; xg[64 + tid] = s;
  }
  __syncthreads();
  {
    float a = b1[tid];
    for (int k = 0; k < 96; ++k) a += xg[k] * W1[k * 128 + tid];
    hh1[tid] = fmaxf(a, 0.0f);
  }
  __syncthreads();
  if (tid < 64) {
    float a = b2[tid];
    for (int k = 0; k < 128; ++k) a += hh1[k] * W2[k * 64 + tid];
    hh2[tid] = fmaxf(a, 0.0f);
  }
  __syncthreads();
  if (tid < 64) {
    float p = hh2[tid] * W3[tid];
    for (int off = 32; off; off >>= 1) p += __shfl_down(p, off);
    if (tid == 0) out[g] = p + b3[0];
  }
}

// ================================================================ launch
extern "C" void kernel_launch(void* const* d_in, const int* in_sizes, int n_in,
                              void* d_out, int out_size, void* d_ws, size_t ws_size,
                              hipStream_t stream)
{
  const float* X       = (const float*)d_in[0];
  const int*   edge    = (const int*)d_in[1];
  const int*   graphs  = (const int*)d_in[2];
  const float* W_in    = (const float*)d_in[3];
  const float* b_in    = (const float*)d_in[4];
  const float* res_W   = (const float*)d_in[5];
  const float* res_b   = (const float*)d_in[6];
  const float* g1_W    = (const float*)d_in[7];
  const float* g1_b    = (const float*)d_in[8];
  const float* bn0_g   = (const float*)d_in[9];
  const float* bn0_b   = (const float*)d_in[10];
  const float* gcn_W   = (const float*)d_in[11];
  // d_in[12] = gcn_b: cancels in bn1 (per-feature shift removed by mean over axis 0)
  const float* bn1_g   = (const float*)d_in[13];
  const float* bn1_b   = (const float*)d_in[14];
  const float* g2_W    = (const float*)d_in[15];
  const float* g2_b    = (const float*)d_in[16];
  const float* bn2_g   = (const float*)d_in[17];
  const float* bn2_b   = (const float*)d_in[18];
  const float* out_W1  = (const float*)d_in[19];
  const float* out_b1  = (const float*)d_in[20];
  const float* out_W2  = (const float*)d_in[21];
  const float* out_b2  = (const float*)d_in[22];
  const float* out_W3  = (const float*)d_in[23];
  const float* out_b3  = (const float*)d_in[24];
  float* outp = (float*)d_out;

  const int* srcp = edge;
  const int* dstp = edge + EE;

  // ---- workspace layout (~113 MB) ----
  const long BIGE = (long)NN * 256;              // 12.8M elems
  u16*   P0   = (u16*)d_ws;                      // x bf16
  u16*   P1   = P0 + BIGE;                       // h1 / h2 bf16
  u16*   P2   = P1 + BIGE;                       // gather out bf16
  u16*   P3   = P2 + BIGE;                       // gemm out bf16
  u16*   WT   = P3 + BIGE;                       // 65536 u16
  float* xl   = (float*)(WT + 65536);            // N*32
  float* dinv = xl + (long)NN * 32;              // N
  int*   rowptr = (int*)(dinv + NN);             // N+1
  int*   cursor = rowptr + NN + 1;               // N
  int*   eidx   = cursor + NN;                   // E
  float* enrm   = (float*)(eidx + EE);           // E
  int*   bsum   = (int*)(enrm + EE);             // NB
  int*   boff   = bsum + NB;                     // NB
  int*   degi = boff + NB;                       // N      <- zero region start
  float* stats = (float*)(degi + NN);            // 1280
  int*   cnt  = (int*)(stats + 1280);            // 64
  float* sp   = (float*)(cnt + 64);              // 2048
  unsigned* mxu = (unsigned*)(sp + 2048);        // 2048
  float* rbias = (float*)(mxu + 2048);           // 512    <- zero region end
  float* AFF  = rbias + 512;                     // 256
  float* BFF  = AFF + 256;
  float* A2v  = BFF + 256;
  float* B2v  = A2v + 32;

  const size_t zero_bytes = (size_t)(NN + 1280 + 64 + 2048 + 2048 + 512) * 4;
  hipMemsetAsync(degi, 0, zero_bytes, stream);

  k_convin<<<NN / 8, 256, 0, stream>>>(X, P0, W_in, b_in);
  k_deg<<<(EE + 255) / 256, 256, 0, stream>>>(dstp, degi);
  k_dinv<<<(NN + 255) / 256, 256, 0, stream>>>(degi, dinv);
  k_psum<<<NB, 256, 0, stream>>>(degi, bsum);
  k_bscan<<<1, 256, 0, stream>>>(bsum, boff);
  k_scan2<<<NB, 256, 0, stream>>>(degi, boff, rowptr, cursor);
  k_fill<<<(EE + 255) / 256, 256, 0, stream>>>(srcp, dstp, dinv, cursor, eidx, enrm);

  for (int l = 0; l < 2; ++l) {
    const float* g1Wl = g1_W + l * 9216;
    const float* g1bl = g1_b + l * 96;
    const float* g2Wl = g2_W + l * 9216;
    const float* g2bl = g2_b + l * 96;
    const float* gWl  = gcn_W + l * 65536;
    float* st = stats + l * 640;
    float* rbl = rbias + l * 256;

    // gated conv 1 (VALU, bf16 weights, tile-strided) + bn0 stats
    k_gatedv<0><<<NGATED, 256, 0, stream>>>(P0, P1, g1Wl, g1bl, nullptr, nullptr,
                                            st + 0, st + 32);
    k_bnfin<<<1, 256, 0, stream>>>(st + 0, st + 32, bn0_g + l * 32, bn0_b + l * 32,
                                   1.0f / 400000.0f, 256, 1, AFF, BFF);
    // fold bn0 into W (transposed bf16) + row bias
    k_wfold<<<16, 256, 0, stream>>>(gWl, AFF, WT);
    k_rowbias<<<8, 256, 0, stream>>>(gWl, BFF, rbl);
    // MFMA GEMM: P3 = P1 @ Wfold + rb
    k_gemmm<<<(NN + 127) / 128, 512, 0, stream>>>(P1, WT, rbl, P3);
    // GCN aggregation: CSR gather (self-loop included)
    k_gather<<<(NN + 3) / 4, 256, 0, stream>>>(P3, P2, rowptr, eidx, enrm, dinv);
    // bn1 stats + fold
    k_colstats<<<512, 256, 0, stream>>>(P2, NN, st + 64, st + 320);
    k_bnfin<<<1, 256, 0, stream>>>(st + 64, st + 320, bn1_g + l * 256, bn1_b + l * 256,
                                   1.0f / (float)NN, 256, 0, AFF, BFF);
    // gated conv 2 (VALU, bn1 fold on input) + bn2 stats
    k_gatedv<1><<<NGATED, 256, 0, stream>>>(P2, P1, g2Wl, g2bl, AFF, BFF,
                                            st + 576, st + 608);
    k_bnfin<<<1, 256, 0, stream>>>(st + 576, st + 608, bn2_g + l * 32, bn2_b + l * 32,
                                   1.0f / 400000.0f, 32, 0, A2v, B2v);
    // finalize: bn2 + residual(x) + (relu in-place | t=7 slice)
    k_final<<<NN / 8, 256, 0, stream>>>(P0, P1, res_W + l * 1024, res_b + l * 32,
                                        A2v, B2v, xl, (l == 0) ? 0 : 1);
  }

  k_pool<<<(NN + 255) / 256, 256, 0, stream>>>(xl, graphs, cnt, sp, mxu);
  k_head<<<64, 128, 0, stream>>>(cnt, sp, mxu, out_W1, out_b1, out_W2, out_b2,
                                 out_W3, out_b3, outp);

  (void)in_sizes; (void)n_in; (void)out_size; (void)ws_size;
}

// Round 9
// 841.358 us; speedup vs baseline: 5.4865x; 1.1727x over previous
//
#include <hip/hip_runtime.h>
#include <hip/hip_bf16.h>

#define NN 50000
#define EE 400000
#define EPSF 1e-5f
#define NB 196   // (NN+255)/256
#define NGATED 1280   // 5 blocks/CU x 256 CU

typedef unsigned short u16;
typedef __attribute__((ext_vector_type(8))) short bf16x8;
typedef __attribute__((ext_vector_type(4))) float f32x4;
typedef __attribute__((ext_vector_type(2))) float f32x2;

__device__ __forceinline__ float b2f(u16 u) { return __uint_as_float(((unsigned)u) << 16); }
__device__ __forceinline__ u16 f2b(float f) {
  unsigned x = __float_as_uint(f);
  unsigned r = x + 0x7FFFu + ((x >> 16) & 1u);   // RNE
  return (u16)(r >> 16);
}
__device__ __forceinline__ unsigned pack2(float lo, float hi) {
  return (unsigned)f2b(lo) | ((unsigned)f2b(hi) << 16);
}
__device__ __forceinline__ f32x2 mk2(float a, float b) { f32x2 r; r.x = a; r.y = b; return r; }
__device__ __forceinline__ void gl16(const void* g, void* l) {
  __builtin_amdgcn_global_load_lds(
      (const __attribute__((address_space(1))) void*)g,
      (__attribute__((address_space(3))) void*)l, 16, 0, 0);
}

// ---------------------------------------------------------------- conv_in
__global__ __launch_bounds__(256) void k_convin(
    const float* __restrict__ X, u16* __restrict__ out,
    const float* __restrict__ Wi, const float* __restrict__ bi)
{
  __shared__ float xs[1024];
  __shared__ float wi[16 * 33];
  const int tid = threadIdx.x;
  for (int idx = tid; idx < 512; idx += 256) {
    int co = idx >> 4, ci = idx & 15;
    wi[ci * 33 + co] = Wi[idx];
  }
  const long xbase = (long)blockIdx.x * 1024;
  ((float4*)xs)[tid] = ((const float4*)(X + xbase))[tid];
  __syncthreads();
  const int nl = tid >> 5, c = tid & 31;
  float acc[8];
  {
    float bc = bi[c];
#pragma unroll
    for (int t = 0; t < 8; ++t) acc[t] = bc;
  }
  const float* xrow = xs + (nl << 7);
  for (int ci = 0; ci < 16; ++ci) {
    float w = wi[ci * 33 + c];
    float4 xa = *(const float4*)(xrow + ci * 8);
    float4 xb = *(const float4*)(xrow + ci * 8 + 4);
    acc[0] += xa.x * w; acc[1] += xa.y * w; acc[2] += xa.z * w; acc[3] += xa.w * w;
    acc[4] += xb.x * w; acc[5] += xb.y * w; acc[6] += xb.z * w; acc[7] += xb.w * w;
  }
  uint4 o;
  o.x = pack2(acc[0], acc[1]); o.y = pack2(acc[2], acc[3]);
  o.z = pack2(acc[4], acc[5]); o.w = pack2(acc[6], acc[7]);
  *(uint4*)(out + (long)blockIdx.x * 2048 + tid * 8) = o;
}

// ---------------------------------------------------------------- degree / dinv
__global__ void k_deg(const int* __restrict__ dst, int* __restrict__ degi)
{
  int e = blockIdx.x * 256 + threadIdx.x;
  if (e < EE) atomicAdd(degi + dst[e], 1);
}
__global__ void k_dinv(const int* __restrict__ degi, float* __restrict__ dinv)
{
  int n = blockIdx.x * 256 + threadIdx.x;
  if (n < NN) dinv[n] = rsqrtf((float)degi[n] + 1.0f);
}

// ---------------------------------------------------------------- CSR build
__global__ __launch_bounds__(256) void k_psum(const int* __restrict__ degi,
                                              int* __restrict__ bsum)
{
  __shared__ int red[4];
  const int tid = threadIdx.x;
  int i = blockIdx.x * 256 + tid;
  int v = (i < NN) ? degi[i] : 0;
#pragma unroll
  for (int d = 32; d >= 1; d >>= 1) v += __shfl_down(v, d);
  if ((tid & 63) == 0) red[tid >> 6] = v;
  __syncthreads();
  if (tid == 0) bsum[blockIdx.x] = red[0] + red[1] + red[2] + red[3];
}

__global__ __launch_bounds__(256) void k_bscan(const int* __restrict__ bsum,
                                               int* __restrict__ boff)
{
  __shared__ int wsum[4];
  const int tid = threadIdx.x, lane = tid & 63, wv = tid >> 6;
  int v = (tid < NB) ? bsum[tid] : 0;
  int s = v;
#pragma unroll
  for (int d = 1; d < 64; d <<= 1) { int t = __shfl_up(s, d); if (lane >= d) s += t; }
  if (lane == 63) wsum[wv] = s;
  __syncthreads();
  int wo = 0;
  for (int w = 0; w < wv; ++w) wo += wsum[w];
  if (tid < NB) boff[tid] = wo + s - v;
}

__global__ __launch_bounds__(256) void k_scan2(const int* __restrict__ degi,
                                               const int* __restrict__ boff,
                                               int* __restrict__ rowptr,
                                               int* __restrict__ cursor)
{
  __shared__ int wsum[4];
  const int tid = threadIdx.x, lane = tid & 63, wv = tid >> 6;
  int i = blockIdx.x * 256 + tid;
  int v = (i < NN) ? degi[i] : 0;
  int s = v;
#pragma unroll
  for (int d = 1; d < 64; d <<= 1) { int t = __shfl_up(s, d); if (lane >= d) s += t; }
  if (lane == 63) wsum[wv] = s;
  __syncthreads();
  int wo = 0;
  for (int w = 0; w < wv; ++w) wo += wsum[w];
  int excl = boff[blockIdx.x] + wo + (s - v);
  if (i < NN) { rowptr[i] = excl; cursor[i] = excl; }
  if (i == NN) rowptr[NN] = excl;
}

__global__ void k_fill(const int* __restrict__ src, const int* __restrict__ dst,
                       const float* __restrict__ dinv,
                       int* __restrict__ cursor,
                       int* __restrict__ eidx, float* __restrict__ enrm)
{
  int e = blockIdx.x * 256 + threadIdx.x;
  if (e < EE) {
    int s = src[e], d = dst[e];
    int p = atomicAdd(cursor + d, 1);
    eidx[p] = s;
    enrm[p] = dinv[s] * dinv[d];
  }
}

// ---------------------------------------------------------------- GCN gather (bf16 in, bf16 out)
__global__ __launch_bounds__(256) void k_gather(
    const u16* __restrict__ hw, u16* __restrict__ out,
    const int* __restrict__ rowptr, const int* __restrict__ eidx,
    const float* __restrict__ enrm, const float* __restrict__ dinv)
{
  const int wid = (blockIdx.x << 2) + (threadIdx.x >> 6);
  if (wid >= NN) return;
  const int lane = threadIdx.x & 63;
  const int c0 = lane << 2;
  float a0, a1, a2, a3;
  {
    float d2 = dinv[wid]; d2 *= d2;
    uint2 v = *(const uint2*)(hw + (long)wid * 256 + c0);
    a0 = d2 * b2f((u16)(v.x & 0xFFFF)); a1 = d2 * b2f((u16)(v.x >> 16));
    a2 = d2 * b2f((u16)(v.y & 0xFFFF)); a3 = d2 * b2f((u16)(v.y >> 16));
  }
  int p = rowptr[wid];
  const int end = rowptr[wid + 1];
  for (; p + 1 < end; p += 2) {
    int s0 = eidx[p], s1 = eidx[p + 1];
    float n0 = enrm[p], n1 = enrm[p + 1];
    uint2 v0 = *(const uint2*)(hw + (long)s0 * 256 + c0);
    uint2 v1 = *(const uint2*)(hw + (long)s1 * 256 + c0);
    a0 += n0 * b2f((u16)(v0.x & 0xFFFF)) + n1 * b2f((u16)(v1.x & 0xFFFF));
    a1 += n0 * b2f((u16)(v0.x >> 16))    + n1 * b2f((u16)(v1.x >> 16));
    a2 += n0 * b2f((u16)(v0.y & 0xFFFF)) + n1 * b2f((u16)(v1.y & 0xFFFF));
    a3 += n0 * b2f((u16)(v0.y >> 16))    + n1 * b2f((u16)(v1.y >> 16));
  }
  if (p < end) {
    int s0 = eidx[p];
    float n0 = enrm[p];
    uint2 v0 = *(const uint2*)(hw + (long)s0 * 256 + c0);
    a0 += n0 * b2f((u16)(v0.x & 0xFFFF));
    a1 += n0 * b2f((u16)(v0.x >> 16));
    a2 += n0 * b2f((u16)(v0.y & 0xFFFF));
    a3 += n0 * b2f((u16)(v0.y >> 16));
  }
  uint2 o; o.x = pack2(a0, a1); o.y = pack2(a2, a3);
  *(uint2*)(out + (long)wid * 256 + c0) = o;
}

// ---------------------------------------------------------------- gated conv (packed-math VALU)
// out(bf16) = relu(P * sigmoid(Q) + R); k=3 pad=1 over t; per-channel stats.
// t-accumulators paired into f32x2 -> v_pk_fma_f32; weights LDS as (w0|w1) u32 + w2 u16.
template<int FOLD>
__global__ __launch_bounds__(256) void k_gatedv(
    const u16* __restrict__ in, u16* __restrict__ out,
    const float* __restrict__ Wg,   // (3,32,32,3)
    const float* __restrict__ bg,   // (3,32)
    const float* __restrict__ aff, const float* __restrict__ bff, // per-f (256) or null
    float* __restrict__ s1, float* __restrict__ s2)               // [32]
{
  __shared__ float xs[2048];            // 8 KB
  __shared__ unsigned wlA[3072];        // (w0|w1<<16) [conv][ci][co], 12 KB
  __shared__ u16 wlB[3072];             // w2 bf16 [conv][ci][co], 6 KB
  __shared__ float red1[128], red2[128];
  const int tid = threadIdx.x;

  // stage weights once per block
  for (int idx = tid; idx < 3072; idx += 256) {
    int conv = idx >> 10;
    int r = idx & 1023;
    int co = r >> 5, ci = r & 31;
    const float* wsrc = Wg + (((conv << 5) + co) * 32 + ci) * 3;
    float w0 = wsrc[0], w1 = wsrc[1], w2 = wsrc[2];
    int di = (conv << 10) + (ci << 5) + co;
    wlA[di] = pack2(w0, w1);
    wlB[di] = f2b(w2);
  }

  const int nl = tid >> 5, c = tid & 31;
  const float bP = bg[c], bQ = bg[32 + c], bR = bg[64 + c];
  float gsum = 0.0f, gsq = 0.0f;

  for (int tile = blockIdx.x; tile < NN / 8; tile += gridDim.x) {
    __syncthreads();                    // xs free from previous tile (1st iter: weights done)
    const long base = (long)tile * 2048;
    {
      const uint4 v = *((const uint4*)(in + base) + tid);
      float d[8];
      d[0] = b2f((u16)(v.x & 0xFFFF)); d[1] = b2f((u16)(v.x >> 16));
      d[2] = b2f((u16)(v.y & 0xFFFF)); d[3] = b2f((u16)(v.y >> 16));
      d[4] = b2f((u16)(v.z & 0xFFFF)); d[5] = b2f((u16)(v.z >> 16));
      d[6] = b2f((u16)(v.w & 0xFFFF)); d[7] = b2f((u16)(v.w >> 16));
      if (FOLD) {
        const int f0 = (tid & 31) << 3;
#pragma unroll
        for (int j = 0; j < 8; ++j) d[j] = fmaf(aff[f0 + j], d[j], bff[f0 + j]);
      }
      float* dd = xs + tid * 8;
#pragma unroll
      for (int j = 0; j < 8; ++j) dd[j] = d[j];
    }
    __syncthreads();

    f32x2 aP[4], aQ[4], aR[4];
#pragma unroll
    for (int j = 0; j < 4; ++j) {
      aP[j] = mk2(bP, bP); aQ[j] = mk2(bQ, bQ); aR[j] = mk2(bR, bR);
    }
    const float* xrow = xs + (nl << 8);
    for (int ci = 0; ci < 32; ++ci) {
      float4 xa = *(const float4*)(xrow + ci * 8);
      float4 xb = *(const float4*)(xrow + ci * 8 + 4);
      f32x2 p0 = mk2(xa.x, xa.y), p1 = mk2(xa.z, xa.w);
      f32x2 p2 = mk2(xb.x, xb.y), p3 = mk2(xb.z, xb.w);
      f32x2 A0  = mk2(0.0f, xa.x);
      f32x2 s01 = mk2(xa.y, xa.z);
      f32x2 s23 = mk2(xa.w, xb.x);
      f32x2 s45 = mk2(xb.y, xb.z);
      f32x2 c3  = mk2(xb.w, 0.0f);
      const int wi = (ci << 5) + c;
#define CONV3(ACC, OFF)                                                        \
      {                                                                        \
        unsigned wA = wlA[wi + OFF];                                           \
        float w0 = __uint_as_float(wA << 16);                                  \
        float w1 = __uint_as_float(wA & 0xFFFF0000u);                          \
        float w2 = b2f(wlB[wi + OFF]);                                         \
        f32x2 W0 = mk2(w0, w0), W1 = mk2(w1, w1), W2 = mk2(w2, w2);            \
        ACC[0] += A0  * W0 + p0 * W1 + s01 * W2;                               \
        ACC[1] += s01 * W0 + p1 * W1 + s23 * W2;                               \
        ACC[2] += s23 * W0 + p2 * W1 + s45 * W2;                               \
        ACC[3] += s45 * W0 + p3 * W1 + c3  * W2;                               \
      }
      CONV3(aP, 0)
      CONV3(aQ, 1024)
      CONV3(aR, 2048)
#undef CONV3
    }
    float hv[8];
#pragma unroll
    for (int j = 0; j < 4; ++j) {
#pragma unroll
      for (int h2 = 0; h2 < 2; ++h2) {
        float pp = h2 ? aP[j].y : aP[j].x;
        float qq = h2 ? aQ[j].y : aQ[j].x;
        float rr = h2 ? aR[j].y : aR[j].x;
        float q = __builtin_amdgcn_rcpf(1.0f + __expf(-qq));
        float h = fmaxf(fmaf(pp, q, rr), 0.0f);
        hv[j * 2 + h2] = h; gsum += h; gsq += h * h;
      }
    }
    uint4 o;
    o.x = pack2(hv[0], hv[1]); o.y = pack2(hv[2], hv[3]);
    o.z = pack2(hv[4], hv[5]); o.w = pack2(hv[6], hv[7]);
    *(uint4*)(out + base + tid * 8) = o;
  }

  // one block-level stats reduction at the end
  float o1 = gsum + __shfl_down(gsum, 32);
  float o2 = gsq + __shfl_down(gsq, 32);
  int wave = tid >> 6, lane = tid & 63;
  if (lane < 32) { red1[wave * 32 + lane] = o1; red2[wave * 32 + lane] = o2; }
  __syncthreads();
  if (tid < 32) {
    float a = red1[tid] + red1[32 + tid] + red1[64 + tid] + red1[96 + tid];
    float b = red2[tid] + red2[32 + tid] + red2[64 + tid] + red2[96 + tid];
    atomicAdd(s1 + tid, a);
    atomicAdd(s2 + tid, b);
  }
}

// ---------------------------------------------------------------- bn finalize
__global__ void k_bnfin(const float* __restrict__ s1, const float* __restrict__ s2,
                        const float* __restrict__ g, const float* __restrict__ b,
                        float cntInv, int nf, int expand,
                        float* __restrict__ A, float* __restrict__ B)
{
  int f = threadIdx.x;
  if (f < nf) {
    int c = expand ? (f >> 3) : f;
    float m = s1[c] * cntInv;
    float var = s2[c] * cntInv - m * m;
    float a = g[c] / sqrtf(var + EPSF);
    A[f] = a;
    B[f] = b[c] - m * a;
  }
}

// ---------------------------------------------------------------- W fold: WT[j][k]=aff[k]*W[k][j]
__global__ __launch_bounds__(256) void k_wfold(
    const float* __restrict__ W, const float* __restrict__ aff,
    u16* __restrict__ WT)
{
  __shared__ float tile[64][68];
  __shared__ float affl[64];
  const int b = blockIdx.x;
  const int kx = (b & 3) * 64, jx = (b >> 2) * 64;
  const int t = threadIdx.x;
  if (t < 64) affl[t] = aff[kx + t];
  {
    int r = t >> 2, c0 = (t & 3) * 16;
#pragma unroll
    for (int i = 0; i < 4; ++i) {
      float4 v = *(const float4*)(W + (long)(kx + r) * 256 + jx + c0 + i * 4);
      tile[r][c0 + i * 4 + 0] = v.x; tile[r][c0 + i * 4 + 1] = v.y;
      tile[r][c0 + i * 4 + 2] = v.z; tile[r][c0 + i * 4 + 3] = v.w;
    }
  }
  __syncthreads();
  {
    int jl = t >> 2, k0 = (t & 3) * 16;
    u16 tmp[16];
#pragma unroll
    for (int kk = 0; kk < 16; ++kk)
      tmp[kk] = f2b(affl[k0 + kk] * tile[k0 + kk][jl]);
    u16* dst = WT + (long)(jx + jl) * 256 + kx + k0;
    *(uint4*)dst = ((uint4*)tmp)[0];
    *(uint4*)(dst + 8) = ((uint4*)tmp)[1];
  }
}

__global__ void k_rowbias(const float* __restrict__ W, const float* __restrict__ bff,
                          float* __restrict__ rb)
{
  int j = threadIdx.x;
  int k0 = blockIdx.x * 32;
  float s = 0.0f;
  for (int kk = 0; kk < 32; ++kk) s += bff[k0 + kk] * W[(long)(k0 + kk) * 256 + j];
  atomicAdd(rb + j, s);
}

// ---------------------------------------------------------------- MFMA GEMM: out = A @ WT^T + rb
__global__ __launch_bounds__(512, 2) void k_gemmm(
    const u16* __restrict__ A, const u16* __restrict__ WT,
    const float* __restrict__ rowbias, u16* __restrict__ Out)
{
  __shared__ u16 At[128 * 64];   // [row][k 64], 16B-chunk XOR-swizzled by row&7
  __shared__ u16 Bt[256 * 64];   // [j][k 64], same swizzle
  const int tid = threadIdx.x, l = tid & 63, w = tid >> 6;
  const long n0 = (long)blockIdx.x * 128;
  const int wr = (w & 1) << 6, wc = (w >> 1) << 6;
  f32x4 acc[4][4];
#pragma unroll
  for (int i = 0; i < 4; ++i)
#pragma unroll
    for (int j = 0; j < 4; ++j) acc[i][j] = (f32x4){0.f, 0.f, 0.f, 0.f};
  float rb[4];
#pragma unroll
  for (int cf = 0; cf < 4; ++cf) rb[cf] = rowbias[wc + (cf << 4) + (l & 15)];

  for (int kt = 0; kt < 4; ++kt) {
    if (kt) __syncthreads();
#pragma unroll
    for (int i = 0; i < 2; ++i) {
      int row = (w << 4) + (i << 3) + (l >> 3);
      int sg = (l & 7) ^ (row & 7);
      long n = n0 + row; if (n >= NN) n = NN - 1;
      gl16(A + n * 256 + kt * 64 + sg * 8, At + ((w << 4) + (i << 3)) * 64);
    }
#pragma unroll
    for (int i = 0; i < 4; ++i) {
      int row = (w << 5) + (i << 3) + (l >> 3);
      int sg = (l & 7) ^ (row & 7);
      gl16(WT + (long)row * 256 + kt * 64 + sg * 8, Bt + ((w << 5) + (i << 3)) * 64);
    }
    __syncthreads();
#pragma unroll
    for (int ks = 0; ks < 2; ++ks) {
      bf16x8 af[4], bf[4];
#pragma unroll
      for (int rf = 0; rf < 4; ++rf) {
        int row = wr + (rf << 4) + (l & 15);
        int slot = ((ks << 2) + (l >> 4)) ^ (row & 7);
        af[rf] = *(const bf16x8*)(At + row * 64 + (slot << 3));
      }
#pragma unroll
      for (int cf = 0; cf < 4; ++cf) {
        int row = wc + (cf << 4) + (l & 15);
        int slot = ((ks << 2) + (l >> 4)) ^ (row & 7);
        bf[cf] = *(const bf16x8*)(Bt + row * 64 + (slot << 3));
      }
#pragma unroll
      for (int rf = 0; rf < 4; ++rf)
#pragma unroll
        for (int cf = 0; cf < 4; ++cf)
          acc[rf][cf] = __builtin_amdgcn_mfma_f32_16x16x32_bf16(
              af[rf], bf[cf], acc[rf][cf], 0, 0, 0);
    }
  }
#pragma unroll
  for (int rf = 0; rf < 4; ++rf)
#pragma unroll
    for (int reg = 0; reg < 4; ++reg) {
      long n = n0 + wr + (rf << 4) + ((l >> 4) << 2) + reg;
      if (n < NN) {
        u16* orow = Out + n * 256 + wc + (l & 15);
#pragma unroll
        for (int cf = 0; cf < 4; ++cf)
          orow[cf << 4] = f2b(acc[rf][cf][reg] + rb[cf]);
      }
    }
}

// ---------------------------------------------------------------- per-feature col stats (bf16 in)
__global__ void k_colstats(const u16* __restrict__ x, int rows,
                           float* __restrict__ s1, float* __restrict__ s2)
{
  int f = threadIdx.x;
  float a = 0.0f, b = 0.0f;
  for (int n = blockIdx.x; n < rows; n += gridDim.x) {
    float v = b2f(x[(long)n * 256 + f]);
    a += v; b += v * v;
  }
  atomicAdd(s1 + f, a);
  atomicAdd(s2 + f, b);
}

// ---------------------------------------------------------------- finalize layer
__global__ __launch_bounds__(256) void k_final(
    u16* __restrict__ x, const u16* __restrict__ h2,
    const float* __restrict__ resW, const float* __restrict__ resb,
    const float* __restrict__ A2, const float* __restrict__ B2,
    float* __restrict__ xl, int mode)
{
  __shared__ float xs[2048];
  __shared__ float wr[32 * 33];
  const int tid = threadIdx.x;
  for (int idx = tid; idx < 1024; idx += 256) {
    int co = idx >> 5, ci = idx & 31;
    wr[ci * 33 + co] = resW[idx];
  }
  const long base = (long)blockIdx.x * 2048;
  {
    const uint4 v = *((const uint4*)(x + base) + tid);
    float* d = xs + tid * 8;
    d[0] = b2f((u16)(v.x & 0xFFFF)); d[1] = b2f((u16)(v.x >> 16));
    d[2] = b2f((u16)(v.y & 0xFFFF)); d[3] = b2f((u16)(v.y >> 16));
    d[4] = b2f((u16)(v.z & 0xFFFF)); d[5] = b2f((u16)(v.z >> 16));
    d[6] = b2f((u16)(v.w & 0xFFFF)); d[7] = b2f((u16)(v.w >> 16));
  }
  __syncthreads();
  const int nl = tid >> 5, c = tid & 31;
  float r[8];
  {
    float rb = resb[c];
#pragma unroll
    for (int t = 0; t < 8; ++t) r[t] = rb;
  }
  const float* xrow = xs + (nl << 8);
  for (int ci = 0; ci < 32; ++ci) {
    float w = wr[ci * 33 + c];
    float4 xa = *(const float4*)(xrow + ci * 8);
    float4 xb = *(const float4*)(xrow + ci * 8 + 4);
    r[0] += xa.x * w; r[1] += xa.y * w; r[2] += xa.z * w; r[3] += xa.w * w;
    r[4] += xb.x * w; r[5] += xb.y * w; r[6] += xb.z * w; r[7] += xb.w * w;
  }
  float a2 = A2[c], b2 = B2[c];
  float hv[8];
  {
    const uint4 v = *((const uint4*)(h2 + base) + tid);
    hv[0] = b2f((u16)(v.x & 0xFFFF)); hv[1] = b2f((u16)(v.x >> 16));
    hv[2] = b2f((u16)(v.y & 0xFFFF)); hv[3] = b2f((u16)(v.y >> 16));
    hv[4] = b2f((u16)(v.z & 0xFFFF)); hv[5] = b2f((u16)(v.z >> 16));
    hv[6] = b2f((u16)(v.w & 0xFFFF)); hv[7] = b2f((u16)(v.w >> 16));
  }
  if (mode == 0) {
    uint4 o;
    float ov[8];
#pragma unroll
    for (int t = 0; t < 8; ++t) ov[t] = fmaxf(fmaf(a2, hv[t], b2) + r[t], 0.0f);
    o.x = pack2(ov[0], ov[1]); o.y = pack2(ov[2], ov[3]);
    o.z = pack2(ov[4], ov[5]); o.w = pack2(ov[6], ov[7]);
    *(uint4*)(x + base + tid * 8) = o;
  } else {
    float v = fmaf(a2, hv[7], b2) + r[7];
    int n = blockIdx.x * 8 + nl;
    xl[n * 32 + c] = v;
  }
}

// ---------------------------------------------------------------- pooling (sorted graphs)
__global__ __launch_bounds__(256) void k_pool(
    const float* __restrict__ xl, const int* __restrict__ graphs,
    int* __restrict__ cnt, float* __restrict__ sp, unsigned* __restrict__ mxu)
{
  __shared__ float lsum[64 * 32];
  __shared__ unsigned lmax[64 * 32];
  __shared__ int lcnt[64];
  const int tid = threadIdx.x;
  const int n0 = blockIdx.x << 8;
  const int nend = min(n0 + 256, NN);
  const int gmin = graphs[n0];
  const int gmax = graphs[nend - 1];
  const int span = gmax - gmin + 1;
  for (int i = tid; i < span * 32; i += 256) { lsum[i] = 0.0f; lmax[i] = 0u; }
  for (int i = tid; i < span; i += 256) lcnt[i] = 0;
  __syncthreads();
  const int c = tid & 31;
  const int nbase = n0 + ((tid >> 5) << 5);
  int curg = -1; float s = 0.0f; unsigned m = 0u; int cn = 0;
  for (int i = 0; i < 32; ++i) {
    int n = nbase + i;
    if (n >= nend) break;
    int g = graphs[n];
    float v = xl[(n << 5) + c];
    unsigned u = __float_as_uint(v);
    u = (u & 0x80000000u) ? ~u : (u | 0x80000000u);
    if (g != curg) {
      if (curg >= 0) {
        atomicAdd(&lsum[((curg - gmin) << 5) + c], s);
        atomicMax(&lmax[((curg - gmin) << 5) + c], m);
        if (c == 0) atomicAdd(&lcnt[curg - gmin], cn);
      }
      curg = g; s = v; m = u; cn = 1;
    } else {
      s += v; m = (u > m) ? u : m; cn++;
    }
  }
  if (curg >= 0) {
    atomicAdd(&lsum[((curg - gmin) << 5) + c], s);
    atomicMax(&lmax[((curg - gmin) << 5) + c], m);
    if (c == 0) atomicAdd(&lcnt[curg - gmin], cn);
  }
  __syncthreads();
  for (int i = tid; i < span * 32; i += 256) {
    atomicAdd(sp + (gmin << 5) + i, lsum[i]);
    atomicMax(mxu + (gmin << 5) + i, lmax[i]);
  }
  for (int i = tid; i < span; i += 256)
    if (lcnt[i]) atomicAdd(cnt + gmin + i, lcnt[i]);
}

// ---------------------------------------------------------------- MLP head
__global__ __launch_bounds__(128) void k_head(
    const int* __restrict__ cnt, const float* __restrict__ sp,
    const unsigned* __restrict__ mxu,
    const float* __restrict__ W1, const float* __restrict__ b1,
    const float* __restrict__ W2, const float* __restrict__ b2,
    const float* __restrict__ W3, const float* __restrict__ b3,
    float* __restrict__ out)
{
  __shared__ float xg[96], hh1[128], hh2[64];
  const int g = blockIdx.x, tid = threadIdx.x;
  if (tid < 32) {
    float s = sp[g * 32 + tid];
    int cn = cnt[g];
    float mean = s / fmaxf((float)cn, 1.0f);
    float mx = 0.0f;
    if (cn > 0) {
      unsigned u = mxu[g * 32 + tid];
      unsigned ub = (u & 0x80000000u) ? (u ^ 0x80000000u) : ~u;
      mx = __uint_as_float(ub);
    }
    xg[tid] = mean; xg[32 + tid] = mx; xg[64 + tid] = s;
  }
  __syncthreads();
  {
    float a = b1[tid];
    for (int k = 0; k < 96; ++k) a += xg[k] * W1[k * 128 + tid];
    hh1[tid] = fmaxf(a, 0.0f);
  }
  __syncthreads();
  if (tid < 64) {
    float a = b2[tid];
    for (int k = 0; k < 128; ++k) a += hh1[k] * W2[k * 64 + tid];
    hh2[tid] = fmaxf(a, 0.0f);
  }
  __syncthreads();
  if (tid < 64) {
    float p = hh2[tid] * W3[tid];
    for (int off = 32; off; off >>= 1) p += __shfl_down(p, off);
    if (tid == 0) out[g] = p + b3[0];
  }
}

// ================================================================ launch
extern "C" void kernel_launch(void* const* d_in, const int* in_sizes, int n_in,
                              void* d_out, int out_size, void* d_ws, size_t ws_size,
                              hipStream_t stream)
{
  const float* X       = (const float*)d_in[0];
  const int*   edge    = (const int*)d_in[1];
  const int*   graphs  = (const int*)d_in[2];
  const float* W_in    = (const float*)d_in[3];
  const float* b_in    = (const float*)d_in[4];
  const float* res_W   = (const float*)d_in[5];
  const float* res_b   = (const float*)d_in[6];
  const float* g1_W    = (const float*)d_in[7];
  const float* g1_b    = (const float*)d_in[8];
  const float* bn0_g   = (const float*)d_in[9];
  const float* bn0_b   = (const float*)d_in[10];
  const float* gcn_W   = (const float*)d_in[11];
  // d_in[12] = gcn_b: cancels in bn1 (per-feature shift removed by mean over axis 0)
  const float* bn1_g   = (const float*)d_in[13];
  const float* bn1_b   = (const float*)d_in[14];
  const float* g2_W    = (const float*)d_in[15];
  const float* g2_b    = (const float*)d_in[16];
  const float* bn2_g   = (const float*)d_in[17];
  const float* bn2_b   = (const float*)d_in[18];
  const float* out_W1  = (const float*)d_in[19];
  const float* out_b1  = (const float*)d_in[20];
  const float* out_W2  = (const float*)d_in[21];
  const float* out_b2  = (const float*)d_in[22];
  const float* out_W3  = (const float*)d_in[23];
  const float* out_b3  = (const float*)d_in[24];
  float* outp = (float*)d_out;

  const int* srcp = edge;
  const int* dstp = edge + EE;

  // ---- workspace layout (~113 MB) ----
  const long BIGE = (long)NN * 256;              // 12.8M elems
  u16*   P0   = (u16*)d_ws;                      // x bf16
  u16*   P1   = P0 + BIGE;                       // h1 / h2 bf16
  u16*   P2   = P1 + BIGE;                       // gather out bf16
  u16*   P3   = P2 + BIGE;                       // gemm out bf16
  u16*   WT   = P3 + BIGE;                       // 65536 u16
  float* xl   = (float*)(WT + 65536);            // N*32
  float* dinv = xl + (long)NN * 32;              // N
  int*   rowptr = (int*)(dinv + NN);             // N+1
  int*   cursor = rowptr + NN + 1;               // N
  int*   eidx   = cursor + NN;                   // E
  float* enrm   = (float*)(eidx + EE);           // E
  int*   bsum   = (int*)(enrm + EE);             // NB
  int*   boff   = bsum + NB;                     // NB
  int*   degi = boff + NB;                       // N      <- zero region start
  float* stats = (float*)(degi + NN);            // 1280
  int*   cnt  = (int*)(stats + 1280);            // 64
  float* sp   = (float*)(cnt + 64);              // 2048
  unsigned* mxu = (unsigned*)(sp + 2048);        // 2048
  float* rbias = (float*)(mxu + 2048);           // 512    <- zero region end
  float* AFF  = rbias + 512;                     // 256
  float* BFF  = AFF + 256;
  float* A2v  = BFF + 256;
  float* B2v  = A2v + 32;

  const size_t zero_bytes = (size_t)(NN + 1280 + 64 + 2048 + 2048 + 512) * 4;
  hipMemsetAsync(degi, 0, zero_bytes, stream);

  k_convin<<<NN / 8, 256, 0, stream>>>(X, P0, W_in, b_in);
  k_deg<<<(EE + 255) / 256, 256, 0, stream>>>(dstp, degi);
  k_dinv<<<(NN + 255) / 256, 256, 0, stream>>>(degi, dinv);
  k_psum<<<NB, 256, 0, stream>>>(degi, bsum);
  k_bscan<<<1, 256, 0, stream>>>(bsum, boff);
  k_scan2<<<NB, 256, 0, stream>>>(degi, boff, rowptr, cursor);
  k_fill<<<(EE + 255) / 256, 256, 0, stream>>>(srcp, dstp, dinv, cursor, eidx, enrm);

  for (int l = 0; l < 2; ++l) {
    const float* g1Wl = g1_W + l * 9216;
    const float* g1bl = g1_b + l * 96;
    const float* g2Wl = g2_W + l * 9216;
    const float* g2bl = g2_b + l * 96;
    const float* gWl  = gcn_W + l * 65536;
    float* st = stats + l * 640;
    float* rbl = rbias + l * 256;

    // gated conv 1 (packed VALU, bf16 weights) + bn0 stats
    k_gatedv<0><<<NGATED, 256, 0, stream>>>(P0, P1, g1Wl, g1bl, nullptr, nullptr,
                                            st + 0, st + 32);
    k_bnfin<<<1, 256, 0, stream>>>(st + 0, st + 32, bn0_g + l * 32, bn0_b + l * 32,
                                   1.0f / 400000.0f, 256, 1, AFF, BFF);
    // fold bn0 into W (transposed bf16) + row bias
    k_wfold<<<16, 256, 0, stream>>>(gWl, AFF, WT);
    k_rowbias<<<8, 256, 0, stream>>>(gWl, BFF, rbl);
    // MFMA GEMM: P3 = P1 @ Wfold + rb
    k_gemmm<<<(NN + 127) / 128, 512, 0, stream>>>(P1, WT, rbl, P3);
    // GCN aggregation: CSR gather (self-loop included)
    k_gather<<<(NN + 3) / 4, 256, 0, stream>>>(P3, P2, rowptr, eidx, enrm, dinv);
    // bn1 stats + fold
    k_colstats<<<512, 256, 0, stream>>>(P2, NN, st + 64, st + 320);
    k_bnfin<<<1, 256, 0, stream>>>(st + 64, st + 320, bn1_g + l * 256, bn1_b + l * 256,
                                   1.0f / (float)NN, 256, 0, AFF, BFF);
    // gated conv 2 (packed VALU, bn1 fold on input) + bn2 stats
    k_gatedv<1><<<NGATED, 256, 0, stream>>>(P2, P1, g2Wl, g2bl, AFF, BFF,
                                            st + 576, st + 608);
    k_bnfin<<<1, 256, 0, stream>>>(st + 576, st + 608, bn2_g + l * 32, bn2_b + l * 32,
                                   1.0f / 400000.0f, 32, 0, A2v, B2v);
    // finalize: bn2 + residual(x) + (relu in-place | t=7 slice)
    k_final<<<NN / 8, 256, 0, stream>>>(P0, P1, res_W + l * 1024, res_b + l * 32,
                                        A2v, B2v, xl, (l == 0) ? 0 : 1);
  }

  k_pool<<<(NN + 255) / 256, 256, 0, stream>>>(xl, graphs, cnt, sp, mxu);
  k_head<<<64, 128, 0, stream>>>(cnt, sp, mxu, out_W1, out_b1, out_W2, out_b2,
                                 out_W3, out_b3, outp);

  (void)in_sizes; (void)n_in; (void)out_size; (void)ws_size;
}

// Round 10
// 834.040 us; speedup vs baseline: 5.5347x; 1.0088x over previous
//
#include <hip/hip_runtime.h>
#include <hip/hip_bf16.h>

#define NN 50000
#define EE 400000
#define EPSF 1e-5f
#define NB 196   // (NN+255)/256
#define NGATED 1280   // 5 blocks/CU x 256 CU

typedef unsigned short u16;
typedef __attribute__((ext_vector_type(8))) short bf16x8;
typedef __attribute__((ext_vector_type(4))) float f32x4;
typedef __attribute__((ext_vector_type(2))) float f32x2;

__device__ __forceinline__ float b2f(u16 u) { return __uint_as_float(((unsigned)u) << 16); }
__device__ __forceinline__ u16 f2b(float f) {
  unsigned x = __float_as_uint(f);
  unsigned r = x + 0x7FFFu + ((x >> 16) & 1u);   // RNE
  return (u16)(r >> 16);
}
__device__ __forceinline__ unsigned pack2(float lo, float hi) {
  return (unsigned)f2b(lo) | ((unsigned)f2b(hi) << 16);
}
__device__ __forceinline__ f32x2 mk2(float a, float b) { f32x2 r; r.x = a; r.y = b; return r; }
__device__ __forceinline__ void gl16(const void* g, void* l) {
  __builtin_amdgcn_global_load_lds(
      (const __attribute__((address_space(1))) void*)g,
      (__attribute__((address_space(3))) void*)l, 16, 0, 0);
}

// ---------------------------------------------------------------- conv_in
__global__ __launch_bounds__(256) void k_convin(
    const float* __restrict__ X, u16* __restrict__ out,
    const float* __restrict__ Wi, const float* __restrict__ bi)
{
  __shared__ float xs[1024];
  __shared__ float wi[16 * 33];
  const int tid = threadIdx.x;
  for (int idx = tid; idx < 512; idx += 256) {
    int co = idx >> 4, ci = idx & 15;
    wi[ci * 33 + co] = Wi[idx];
  }
  const long xbase = (long)blockIdx.x * 1024;
  ((float4*)xs)[tid] = ((const float4*)(X + xbase))[tid];
  __syncthreads();
  const int nl = tid >> 5, c = tid & 31;
  float acc[8];
  {
    float bc = bi[c];
#pragma unroll
    for (int t = 0; t < 8; ++t) acc[t] = bc;
  }
  const float* xrow = xs + (nl << 7);
  for (int ci = 0; ci < 16; ++ci) {
    float w = wi[ci * 33 + c];
    float4 xa = *(const float4*)(xrow + ci * 8);
    float4 xb = *(const float4*)(xrow + ci * 8 + 4);
    acc[0] += xa.x * w; acc[1] += xa.y * w; acc[2] += xa.z * w; acc[3] += xa.w * w;
    acc[4] += xb.x * w; acc[5] += xb.y * w; acc[6] += xb.z * w; acc[7] += xb.w * w;
  }
  uint4 o;
  o.x = pack2(acc[0], acc[1]); o.y = pack2(acc[2], acc[3]);
  o.z = pack2(acc[4], acc[5]); o.w = pack2(acc[6], acc[7]);
  *(uint4*)(out + (long)blockIdx.x * 2048 + tid * 8) = o;
}

// ---------------------------------------------------------------- degree / dinv
__global__ void k_deg(const int* __restrict__ dst, int* __restrict__ degi)
{
  int e = blockIdx.x * 256 + threadIdx.x;
  if (e < EE) atomicAdd(degi + dst[e], 1);
}
__global__ void k_dinv(const int* __restrict__ degi, float* __restrict__ dinv)
{
  int n = blockIdx.x * 256 + threadIdx.x;
  if (n < NN) dinv[n] = rsqrtf((float)degi[n] + 1.0f);
}

// ---------------------------------------------------------------- CSR build
__global__ __launch_bounds__(256) void k_psum(const int* __restrict__ degi,
                                              int* __restrict__ bsum)
{
  __shared__ int red[4];
  const int tid = threadIdx.x;
  int i = blockIdx.x * 256 + tid;
  int v = (i < NN) ? degi[i] : 0;
#pragma unroll
  for (int d = 32; d >= 1; d >>= 1) v += __shfl_down(v, d);
  if ((tid & 63) == 0) red[tid >> 6] = v;
  __syncthreads();
  if (tid == 0) bsum[blockIdx.x] = red[0] + red[1] + red[2] + red[3];
}

__global__ __launch_bounds__(256) void k_bscan(const int* __restrict__ bsum,
                                               int* __restrict__ boff)
{
  __shared__ int wsum[4];
  const int tid = threadIdx.x, lane = tid & 63, wv = tid >> 6;
  int v = (tid < NB) ? bsum[tid] : 0;
  int s = v;
#pragma unroll
  for (int d = 1; d < 64; d <<= 1) { int t = __shfl_up(s, d); if (lane >= d) s += t; }
  if (lane == 63) wsum[wv] = s;
  __syncthreads();
  int wo = 0;
  for (int w = 0; w < wv; ++w) wo += wsum[w];
  if (tid < NB) boff[tid] = wo + s - v;
}

__global__ __launch_bounds__(256) void k_scan2(const int* __restrict__ degi,
                                               const int* __restrict__ boff,
                                               int* __restrict__ rowptr,
                                               int* __restrict__ cursor)
{
  __shared__ int wsum[4];
  const int tid = threadIdx.x, lane = tid & 63, wv = tid >> 6;
  int i = blockIdx.x * 256 + tid;
  int v = (i < NN) ? degi[i] : 0;
  int s = v;
#pragma unroll
  for (int d = 1; d < 64; d <<= 1) { int t = __shfl_up(s, d); if (lane >= d) s += t; }
  if (lane == 63) wsum[wv] = s;
  __syncthreads();
  int wo = 0;
  for (int w = 0; w < wv; ++w) wo += wsum[w];
  int excl = boff[blockIdx.x] + wo + (s - v);
  if (i < NN) { rowptr[i] = excl; cursor[i] = excl; }
  if (i == NN) rowptr[NN] = excl;
}

__global__ void k_fill(const int* __restrict__ src, const int* __restrict__ dst,
                       const float* __restrict__ dinv,
                       int* __restrict__ cursor,
                       int* __restrict__ eidx, float* __restrict__ enrm)
{
  int e = blockIdx.x * 256 + threadIdx.x;
  if (e < EE) {
    int s = src[e], d = dst[e];
    int p = atomicAdd(cursor + d, 1);
    eidx[p] = s;
    enrm[p] = dinv[s] * dinv[d];
  }
}

// ---------------------------------------------------------------- GCN gather (bf16 in, bf16 out)
__global__ __launch_bounds__(256) void k_gather(
    const u16* __restrict__ hw, u16* __restrict__ out,
    const int* __restrict__ rowptr, const int* __restrict__ eidx,
    const float* __restrict__ enrm, const float* __restrict__ dinv)
{
  const int wid = (blockIdx.x << 2) + (threadIdx.x >> 6);
  if (wid >= NN) return;
  const int lane = threadIdx.x & 63;
  const int c0 = lane << 2;
  float a0, a1, a2, a3;
  {
    float d2 = dinv[wid]; d2 *= d2;
    uint2 v = *(const uint2*)(hw + (long)wid * 256 + c0);
    a0 = d2 * b2f((u16)(v.x & 0xFFFF)); a1 = d2 * b2f((u16)(v.x >> 16));
    a2 = d2 * b2f((u16)(v.y & 0xFFFF)); a3 = d2 * b2f((u16)(v.y >> 16));
  }
  int p = rowptr[wid];
  const int end = rowptr[wid + 1];
  for (; p + 1 < end; p += 2) {
    int s0 = eidx[p], s1 = eidx[p + 1];
    float n0 = enrm[p], n1 = enrm[p + 1];
    uint2 v0 = *(const uint2*)(hw + (long)s0 * 256 + c0);
    uint2 v1 = *(const uint2*)(hw + (long)s1 * 256 + c0);
    a0 += n0 * b2f((u16)(v0.x & 0xFFFF)) + n1 * b2f((u16)(v1.x & 0xFFFF));
    a1 += n0 * b2f((u16)(v0.x >> 16))    + n1 * b2f((u16)(v1.x >> 16));
    a2 += n0 * b2f((u16)(v0.y & 0xFFFF)) + n1 * b2f((u16)(v1.y & 0xFFFF));
    a3 += n0 * b2f((u16)(v0.y >> 16))    + n1 * b2f((u16)(v1.y >> 16));
  }
  if (p < end) {
    int s0 = eidx[p];
    float n0 = enrm[p];
    uint2 v0 = *(const uint2*)(hw + (long)s0 * 256 + c0);
    a0 += n0 * b2f((u16)(v0.x & 0xFFFF));
    a1 += n0 * b2f((u16)(v0.x >> 16));
    a2 += n0 * b2f((u16)(v0.y & 0xFFFF));
    a3 += n0 * b2f((u16)(v0.y >> 16));
  }
  uint2 o; o.x = pack2(a0, a1); o.y = pack2(a2, a3);
  *(uint2*)(out + (long)wid * 256 + c0) = o;
}

// ---------------------------------------------------------------- gated conv (packed-math VALU, swizzled xs)
// out(bf16) = relu(P * sigmoid(Q) + R); k=3 pad=1 over t; per-channel stats.
// 16B-slot swizzle: phys = (2ci+h) ^ (ci>>2) -- bijective, spreads write banks;
// reads remain same-address broadcasts. FOLD: bn coefficients computed inline from stats.
template<int FOLD>
__global__ __launch_bounds__(256) void k_gatedv(
    const u16* __restrict__ in, u16* __restrict__ out,
    const float* __restrict__ Wg,   // (3,32,32,3)
    const float* __restrict__ bg,   // (3,32)
    const float* __restrict__ s1in, const float* __restrict__ s2in,  // raw stats (256) or null
    const float* __restrict__ gin, const float* __restrict__ bin,    // bn gamma/beta (256) or null
    float cntInv,
    float* __restrict__ s1, float* __restrict__ s2)                  // [32] out stats
{
  __shared__ float xs[2048];            // 8 KB (swizzled 16B slots)
  __shared__ unsigned wlA[3072];        // (w0|w1<<16) [conv][ci][co], 12 KB
  __shared__ u16 wlB[3072];             // w2 bf16 [conv][ci][co], 6 KB
  __shared__ float red1[128], red2[128];
  const int tid = threadIdx.x;

  // stage weights once per block
  for (int idx = tid; idx < 3072; idx += 256) {
    int conv = idx >> 10;
    int r = idx & 1023;
    int co = r >> 5, ci = r & 31;
    const float* wsrc = Wg + (((conv << 5) + co) * 32 + ci) * 3;
    float w0 = wsrc[0], w1 = wsrc[1], w2 = wsrc[2];
    int di = (conv << 10) + (ci << 5) + co;
    wlA[di] = pack2(w0, w1);
    wlB[di] = f2b(w2);
  }

  const int nl = tid >> 5, c = tid & 31;
  const float bP = bg[c], bQ = bg[32 + c], bR = bg[64 + c];
  float affr[8], bffr[8];
  if (FOLD) {
    const int f0 = c << 3;
#pragma unroll
    for (int j = 0; j < 8; ++j) {
      float m = s1in[f0 + j] * cntInv;
      float var = s2in[f0 + j] * cntInv - m * m;
      float A = gin[f0 + j] / sqrtf(var + EPSF);
      affr[j] = A;
      bffr[j] = bin[f0 + j] - m * A;
    }
  }
  float gsum = 0.0f, gsq = 0.0f;
  const int swa = c >> 2;               // 0..7 swizzle key

  for (int tile = blockIdx.x; tile < NN / 8; tile += gridDim.x) {
    __syncthreads();                    // xs free from previous tile (1st iter: weights done)
    const long base = (long)tile * 2048;
    {
      const uint4 v = *((const uint4*)(in + base) + tid);
      float d[8];
      d[0] = b2f((u16)(v.x & 0xFFFF)); d[1] = b2f((u16)(v.x >> 16));
      d[2] = b2f((u16)(v.y & 0xFFFF)); d[3] = b2f((u16)(v.y >> 16));
      d[4] = b2f((u16)(v.z & 0xFFFF)); d[5] = b2f((u16)(v.z >> 16));
      d[6] = b2f((u16)(v.w & 0xFFFF)); d[7] = b2f((u16)(v.w >> 16));
      if (FOLD) {
#pragma unroll
        for (int j = 0; j < 8; ++j) d[j] = fmaf(affr[j], d[j], bffr[j]);
      }
      float4* xw = (float4*)xs + (nl << 6);
      xw[(2 * c) ^ swa]     = make_float4(d[0], d[1], d[2], d[3]);
      xw[(2 * c + 1) ^ swa] = make_float4(d[4], d[5], d[6], d[7]);
    }
    __syncthreads();

    f32x2 aP[4], aQ[4], aR[4];
#pragma unroll
    for (int j = 0; j < 4; ++j) {
      aP[j] = mk2(bP, bP); aQ[j] = mk2(bQ, bQ); aR[j] = mk2(bR, bR);
    }
    const float4* xrow = (const float4*)xs + (nl << 6);
    for (int ci = 0; ci < 32; ++ci) {
      const int a = ci >> 2;
      float4 xa = xrow[(2 * ci) ^ a];
      float4 xb = xrow[(2 * ci + 1) ^ a];
      f32x2 p0 = mk2(xa.x, xa.y), p1 = mk2(xa.z, xa.w);
      f32x2 p2 = mk2(xb.x, xb.y), p3 = mk2(xb.z, xb.w);
      f32x2 A0  = mk2(0.0f, xa.x);
      f32x2 s01 = mk2(xa.y, xa.z);
      f32x2 s23 = mk2(xa.w, xb.x);
      f32x2 s45 = mk2(xb.y, xb.z);
      f32x2 c3  = mk2(xb.w, 0.0f);
      const int wi = (ci << 5) + c;
#define CONV3(ACC, OFF)                                                        \
      {                                                                        \
        unsigned wA = wlA[wi + OFF];                                           \
        float w0 = __uint_as_float(wA << 16);                                  \
        float w1 = __uint_as_float(wA & 0xFFFF0000u);                          \
        float w2 = b2f(wlB[wi + OFF]);                                         \
        f32x2 W0 = mk2(w0, w0), W1 = mk2(w1, w1), W2 = mk2(w2, w2);            \
        ACC[0] += A0  * W0 + p0 * W1 + s01 * W2;                               \
        ACC[1] += s01 * W0 + p1 * W1 + s23 * W2;                               \
        ACC[2] += s23 * W0 + p2 * W1 + s45 * W2;                               \
        ACC[3] += s45 * W0 + p3 * W1 + c3  * W2;                               \
      }
      CONV3(aP, 0)
      CONV3(aQ, 1024)
      CONV3(aR, 2048)
#undef CONV3
    }
    float hv[8];
#pragma unroll
    for (int j = 0; j < 4; ++j) {
#pragma unroll
      for (int h2 = 0; h2 < 2; ++h2) {
        float pp = h2 ? aP[j].y : aP[j].x;
        float qq = h2 ? aQ[j].y : aQ[j].x;
        float rr = h2 ? aR[j].y : aR[j].x;
        float q = __builtin_amdgcn_rcpf(1.0f + __expf(-qq));
        float h = fmaxf(fmaf(pp, q, rr), 0.0f);
        hv[j * 2 + h2] = h; gsum += h; gsq += h * h;
      }
    }
    uint4 o;
    o.x = pack2(hv[0], hv[1]); o.y = pack2(hv[2], hv[3]);
    o.z = pack2(hv[4], hv[5]); o.w = pack2(hv[6], hv[7]);
    *(uint4*)(out + base + tid * 8) = o;
  }

  // one block-level stats reduction at the end
  float o1 = gsum + __shfl_down(gsum, 32);
  float o2 = gsq + __shfl_down(gsq, 32);
  int wave = tid >> 6, lane = tid & 63;
  if (lane < 32) { red1[wave * 32 + lane] = o1; red2[wave * 32 + lane] = o2; }
  __syncthreads();
  if (tid < 32) {
    float a = red1[tid] + red1[32 + tid] + red1[64 + tid] + red1[96 + tid];
    float b = red2[tid] + red2[32 + tid] + red2[64 + tid] + red2[96 + tid];
    atomicAdd(s1 + tid, a);
    atomicAdd(s2 + tid, b);
  }
}

// ---------------------------------------------------------------- W prep: fold bn0 into W (blocks 0..15)
// and compute row bias (blocks 16..23). bn0 finalize inlined from raw stats.
__global__ __launch_bounds__(256) void k_wprep(
    const float* __restrict__ W, const float* __restrict__ st1, const float* __restrict__ st2,
    const float* __restrict__ g0, const float* __restrict__ b0,
    u16* __restrict__ WT, float* __restrict__ rb)
{
  __shared__ float tile[64][68];
  __shared__ float affl[64];
  const int b = blockIdx.x;
  const int t = threadIdx.x;
  const float ci400 = 1.0f / 400000.0f;
  if (b < 16) {
    const int kx = (b & 3) * 64, jx = (b >> 2) * 64;
    if (t < 64) {
      int cch = (kx + t) >> 3;
      float m = st1[cch] * ci400;
      float var = st2[cch] * ci400 - m * m;
      affl[t] = g0[cch] / sqrtf(var + EPSF);
    }
    {
      int r = t >> 2, c0 = (t & 3) * 16;
#pragma unroll
      for (int i = 0; i < 4; ++i) {
        float4 v = *(const float4*)(W + (long)(kx + r) * 256 + jx + c0 + i * 4);
        tile[r][c0 + i * 4 + 0] = v.x; tile[r][c0 + i * 4 + 1] = v.y;
        tile[r][c0 + i * 4 + 2] = v.z; tile[r][c0 + i * 4 + 3] = v.w;
      }
    }
    __syncthreads();
    {
      int jl = t >> 2, k0 = (t & 3) * 16;
      u16 tmp[16];
#pragma unroll
      for (int kk = 0; kk < 16; ++kk)
        tmp[kk] = f2b(affl[k0 + kk] * tile[k0 + kk][jl]);
      u16* dst = WT + (long)(jx + jl) * 256 + kx + k0;
      *(uint4*)dst = ((uint4*)tmp)[0];
      *(uint4*)(dst + 8) = ((uint4*)tmp)[1];
    }
  } else {
    const int k0 = (b - 16) * 32;
    if (t < 32) {
      int cch = (k0 + t) >> 3;
      float m = st1[cch] * ci400;
      float var = st2[cch] * ci400 - m * m;
      float A = g0[cch] / sqrtf(var + EPSF);
      affl[t] = b0[cch] - m * A;   // bff
    }
    __syncthreads();
    float s = 0.0f;
    for (int kk = 0; kk < 32; ++kk) s += affl[kk] * W[(long)(k0 + kk) * 256 + t];
    atomicAdd(rb + t, s);
  }
}

// ---------------------------------------------------------------- MFMA GEMM: out = A @ WT^T + rb
__global__ __launch_bounds__(512, 2) void k_gemmm(
    const u16* __restrict__ A, const u16* __restrict__ WT,
    const float* __restrict__ rowbias, u16* __restrict__ Out)
{
  __shared__ u16 At[128 * 64];   // [row][k 64], 16B-chunk XOR-swizzled by row&7
  __shared__ u16 Bt[256 * 64];   // [j][k 64], same swizzle
  const int tid = threadIdx.x, l = tid & 63, w = tid >> 6;
  const long n0 = (long)blockIdx.x * 128;
  const int wr = (w & 1) << 6, wc = (w >> 1) << 6;
  f32x4 acc[4][4];
#pragma unroll
  for (int i = 0; i < 4; ++i)
#pragma unroll
    for (int j = 0; j < 4; ++j) acc[i][j] = (f32x4){0.f, 0.f, 0.f, 0.f};
  float rb[4];
#pragma unroll
  for (int cf = 0; cf < 4; ++cf) rb[cf] = rowbias[wc + (cf << 4) + (l & 15)];

  for (int kt = 0; kt < 4; ++kt) {
    if (kt) __syncthreads();
#pragma unroll
    for (int i = 0; i < 2; ++i) {
      int row = (w << 4) + (i << 3) + (l >> 3);
      int sg = (l & 7) ^ (row & 7);
      long n = n0 + row; if (n >= NN) n = NN - 1;
      gl16(A + n * 256 + kt * 64 + sg * 8, At + ((w << 4) + (i << 3)) * 64);
    }
#pragma unroll
    for (int i = 0; i < 4; ++i) {
      int row = (w << 5) + (i << 3) + (l >> 3);
      int sg = (l & 7) ^ (row & 7);
      gl16(WT + (long)row * 256 + kt * 64 + sg * 8, Bt + ((w << 5) + (i << 3)) * 64);
    }
    __syncthreads();
#pragma unroll
    for (int ks = 0; ks < 2; ++ks) {
      bf16x8 af[4], bf[4];
#pragma unroll
      for (int rf = 0; rf < 4; ++rf) {
        int row = wr + (rf << 4) + (l & 15);
        int slot = ((ks << 2) + (l >> 4)) ^ (row & 7);
        af[rf] = *(const bf16x8*)(At + row * 64 + (slot << 3));
      }
#pragma unroll
      for (int cf = 0; cf < 4; ++cf) {
        int row = wc + (cf << 4) + (l & 15);
        int slot = ((ks << 2) + (l >> 4)) ^ (row & 7);
        bf[cf] = *(const bf16x8*)(Bt + row * 64 + (slot << 3));
      }
#pragma unroll
      for (int rf = 0; rf < 4; ++rf)
#pragma unroll
        for (int cf = 0; cf < 4; ++cf)
          acc[rf][cf] = __builtin_amdgcn_mfma_f32_16x16x32_bf16(
              af[rf], bf[cf], acc[rf][cf], 0, 0, 0);
    }
  }
#pragma unroll
  for (int rf = 0; rf < 4; ++rf)
#pragma unroll
    for (int reg = 0; reg < 4; ++reg) {
      long n = n0 + wr + (rf << 4) + ((l >> 4) << 2) + reg;
      if (n < NN) {
        u16* orow = Out + n * 256 + wc + (l & 15);
#pragma unroll
        for (int cf = 0; cf < 4; ++cf)
          orow[cf << 4] = f2b(acc[rf][cf][reg] + rb[cf]);
      }
    }
}

// ---------------------------------------------------------------- per-feature col stats (bf16 in)
__global__ void k_colstats(const u16* __restrict__ x, int rows,
                           float* __restrict__ s1, float* __restrict__ s2)
{
  int f = threadIdx.x;
  float a = 0.0f, b = 0.0f;
  for (int n = blockIdx.x; n < rows; n += gridDim.x) {
    float v = b2f(x[(long)n * 256 + f]);
    a += v; b += v * v;
  }
  atomicAdd(s1 + f, a);
  atomicAdd(s2 + f, b);
}

// ---------------------------------------------------------------- finalize layer (bn2 finalize inlined)
__global__ __launch_bounds__(256) void k_final(
    u16* __restrict__ x, const u16* __restrict__ h2,
    const float* __restrict__ resW, const float* __restrict__ resb,
    const float* __restrict__ st1, const float* __restrict__ st2,
    const float* __restrict__ g2, const float* __restrict__ b2g,
    float* __restrict__ xl, int mode)
{
  __shared__ float xs[2048];
  __shared__ float wr[32 * 33];
  __shared__ float a2l[32], b2l[32];
  const int tid = threadIdx.x;
  for (int idx = tid; idx < 1024; idx += 256) {
    int co = idx >> 5, ci = idx & 31;
    wr[ci * 33 + co] = resW[idx];
  }
  if (tid < 32) {
    const float ci400 = 1.0f / 400000.0f;
    float m = st1[tid] * ci400;
    float var = st2[tid] * ci400 - m * m;
    float A = g2[tid] / sqrtf(var + EPSF);
    a2l[tid] = A;
    b2l[tid] = b2g[tid] - m * A;
  }
  const long base = (long)blockIdx.x * 2048;
  {
    const uint4 v = *((const uint4*)(x + base) + tid);
    float* d = xs + tid * 8;
    d[0] = b2f((u16)(v.x & 0xFFFF)); d[1] = b2f((u16)(v.x >> 16));
    d[2] = b2f((u16)(v.y & 0xFFFF)); d[3] = b2f((u16)(v.y >> 16));
    d[4] = b2f((u16)(v.z & 0xFFFF)); d[5] = b2f((u16)(v.z >> 16));
    d[6] = b2f((u16)(v.w & 0xFFFF)); d[7] = b2f((u16)(v.w >> 16));
  }
  __syncthreads();
  const int nl = tid >> 5, c = tid & 31;
  float r[8];
  {
    float rb = resb[c];
#pragma unroll
    for (int t = 0; t < 8; ++t) r[t] = rb;
  }
  const float* xrow = xs + (nl << 8);
  for (int ci = 0; ci < 32; ++ci) {
    float w = wr[ci * 33 + c];
    float4 xa = *(const float4*)(xrow + ci * 8);
    float4 xb = *(const float4*)(xrow + ci * 8 + 4);
    r[0] += xa.x * w; r[1] += xa.y * w; r[2] += xa.z * w; r[3] += xa.w * w;
    r[4] += xb.x * w; r[5] += xb.y * w; r[6] += xb.z * w; r[7] += xb.w * w;
  }
  float a2 = a2l[c], b2 = b2l[c];
  float hv[8];
  {
    const uint4 v = *((const uint4*)(h2 + base) + tid);
    hv[0] = b2f((u16)(v.x & 0xFFFF)); hv[1] = b2f((u16)(v.x >> 16));
    hv[2] = b2f((u16)(v.y & 0xFFFF)); hv[3] = b2f((u16)(v.y >> 16));
    hv[4] = b2f((u16)(v.z & 0xFFFF)); hv[5] = b2f((u16)(v.z >> 16));
    hv[6] = b2f((u16)(v.w & 0xFFFF)); hv[7] = b2f((u16)(v.w >> 16));
  }
  if (mode == 0) {
    uint4 o;
    float ov[8];
#pragma unroll
    for (int t = 0; t < 8; ++t) ov[t] = fmaxf(fmaf(a2, hv[t], b2) + r[t], 0.0f);
    o.x = pack2(ov[0], ov[1]); o.y = pack2(ov[2], ov[3]);
    o.z = pack2(ov[4], ov[5]); o.w = pack2(ov[6], ov[7]);
    *(uint4*)(x + base + tid * 8) = o;
  } else {
    float v = fmaf(a2, hv[7], b2) + r[7];
    int n = blockIdx.x * 8 + nl;
    xl[n * 32 + c] = v;
  }
}

// ---------------------------------------------------------------- pooling (sorted graphs)
__global__ __launch_bounds__(256) void k_pool(
    const float* __restrict__ xl, const int* __restrict__ graphs,
    int* __restrict__ cnt, float* __restrict__ sp, unsigned* __restrict__ mxu)
{
  __shared__ float lsum[64 * 32];
  __shared__ unsigned lmax[64 * 32];
  __shared__ int lcnt[64];
  const int tid = threadIdx.x;
  const int n0 = blockIdx.x << 8;
  const int nend = min(n0 + 256, NN);
  const int gmin = graphs[n0];
  const int gmax = graphs[nend - 1];
  const int span = gmax - gmin + 1;
  for (int i = tid; i < span * 32; i += 256) { lsum[i] = 0.0f; lmax[i] = 0u; }
  for (int i = tid; i < span; i += 256) lcnt[i] = 0;
  __syncthreads();
  const int c = tid & 31;
  const int nbase = n0 + ((tid >> 5) << 5);
  int curg = -1; float s = 0.0f; unsigned m = 0u; int cn = 0;
  for (int i = 0; i < 32; ++i) {
    int n = nbase + i;
    if (n >= nend) break;
    int g = graphs[n];
    float v = xl[(n << 5) + c];
    unsigned u = __float_as_uint(v);
    u = (u & 0x80000000u) ? ~u : (u | 0x80000000u);
    if (g != curg) {
      if (curg >= 0) {
        atomicAdd(&lsum[((curg - gmin) << 5) + c], s);
        atomicMax(&lmax[((curg - gmin) << 5) + c], m);
        if (c == 0) atomicAdd(&lcnt[curg - gmin], cn);
      }
      curg = g; s = v; m = u; cn = 1;
    } else {
      s += v; m = (u > m) ? u : m; cn++;
    }
  }
  if (curg >= 0) {
    atomicAdd(&lsum[((curg - gmin) << 5) + c], s);
    atomicMax(&lmax[((curg - gmin) << 5) + c], m);
    if (c == 0) atomicAdd(&lcnt[curg - gmin], cn);
  }
  __syncthreads();
  for (int i = tid; i < span * 32; i += 256) {
    atomicAdd(sp + (gmin << 5) + i, lsum[i]);
    atomicMax(mxu + (gmin << 5) + i, lmax[i]);
  }
  for (int i = tid; i < span; i += 256)
    if (lcnt[i]) atomicAdd(cnt + gmin + i, lcnt[i]);
}

// ---------------------------------------------------------------- MLP head
__global__ __launch_bounds__(128) void k_head(
    const int* __restrict__ cnt, const float* __restrict__ sp,
    const unsigned* __restrict__ mxu,
    const float* __restrict__ W1, const float* __restrict__ b1,
    const float* __restrict__ W2, const float* __restrict__ b2,
    const float* __restrict__ W3, const float* __restrict__ b3,
    float* __restrict__ out)
{
  __shared__ float xg[96], hh1[128], hh2[64];
  const int g = blockIdx.x, tid = threadIdx.x;
  if (tid < 32) {
    float s = sp[g * 32 + tid];
    int cn = cnt[g];
    float mean = s / fmaxf((float)cn, 1.0f);
    float mx = 0.0f;
    if (cn > 0) {
      unsigned u = mxu[g * 32 + tid];
      unsigned ub = (u & 0x80000000u) ? (u ^ 0x80000000u) : ~u;
      mx = __uint_as_float(ub);
    }
    xg[tid] = mean; xg[32 + tid] = mx; xg[64 + tid] = s;
  }
  __syncthreads();
  {
    float a = b1[tid];
    for (int k = 0; k < 96; ++k) a += xg[k] * W1[k * 128 + tid];
    hh1[tid] = fmaxf(a, 0.0f);
  }
  __syncthreads();
  if (tid < 64) {
    float a = b2[tid];
    for (int k = 0; k < 128; ++k) a += hh1[k] * W2[k * 64 + tid];
    hh2[tid] = fmaxf(a, 0.0f);
  }
  __syncthreads();
  if (tid < 64) {
    float p = hh2[tid] * W3[tid];
    for (int off = 32; off; off >>= 1) p += __shfl_down(p, off);
    if (tid == 0) out[g] = p + b3[0];
  }
}

// ================================================================ launch
extern "C" void kernel_launch(void* const* d_in, const int* in_sizes, int n_in,
                              void* d_out, int out_size, void* d_ws, size_t ws_size,
                              hipStream_t stream)
{
  const float* X       = (const float*)d_in[0];
  const int*   edge    = (const int*)d_in[1];
  const int*   graphs  = (const int*)d_in[2];
  const float* W_in    = (const float*)d_in[3];
  const float* b_in    = (const float*)d_in[4];
  const float* res_W   = (const float*)d_in[5];
  const float* res_b   = (const float*)d_in[6];
  const float* g1_W    = (const float*)d_in[7];
  const float* g1_b    = (const float*)d_in[8];
  const float* bn0_g   = (const float*)d_in[9];
  const float* bn0_b   = (const float*)d_in[10];
  const float* gcn_W   = (const float*)d_in[11];
  // d_in[12] = gcn_b: cancels in bn1 (per-feature shift removed by mean over axis 0)
  const float* bn1_g   = (const float*)d_in[13];
  const float* bn1_b   = (const float*)d_in[14];
  const float* g2_W    = (const float*)d_in[15];
  const float* g2_b    = (const float*)d_in[16];
  const float* bn2_g   = (const float*)d_in[17];
  const float* bn2_b   = (const float*)d_in[18];
  const float* out_W1  = (const float*)d_in[19];
  const float* out_b1  = (const float*)d_in[20];
  const float* out_W2  = (const float*)d_in[21];
  const float* out_b2  = (const float*)d_in[22];
  const float* out_W3  = (const float*)d_in[23];
  const float* out_b3  = (const float*)d_in[24];
  float* outp = (float*)d_out;

  const int* srcp = edge;
  const int* dstp = edge + EE;

  // ---- workspace layout (~113 MB) ----
  const long BIGE = (long)NN * 256;              // 12.8M elems
  u16*   P0   = (u16*)d_ws;                      // x bf16
  u16*   P1   = P0 + BIGE;                       // h1 / h2 bf16
  u16*   P2   = P1 + BIGE;                       // gather out bf16
  u16*   P3   = P2 + BIGE;                       // gemm out bf16
  u16*   WT   = P3 + BIGE;                       // 65536 u16
  float* xl   = (float*)(WT + 65536);            // N*32
  float* dinv = xl + (long)NN * 32;              // N
  int*   rowptr = (int*)(dinv + NN);             // N+1
  int*   cursor = rowptr + NN + 1;               // N
  int*   eidx   = cursor + NN;                   // E
  float* enrm   = (float*)(eidx + EE);           // E
  int*   bsum   = (int*)(enrm + EE);             // NB
  int*   boff   = bsum + NB;                     // NB
  int*   degi = boff + NB;                       // N      <- zero region start
  float* stats = (float*)(degi + NN);            // 1280
  int*   cnt  = (int*)(stats + 1280);            // 64
  float* sp   = (float*)(cnt + 64);              // 2048
  unsigned* mxu = (unsigned*)(sp + 2048);        // 2048
  float* rbias = (float*)(mxu + 2048);           // 512    <- zero region end

  const size_t zero_bytes = (size_t)(NN + 1280 + 64 + 2048 + 2048 + 512) * 4;
  hipMemsetAsync(degi, 0, zero_bytes, stream);

  k_convin<<<NN / 8, 256, 0, stream>>>(X, P0, W_in, b_in);
  k_deg<<<(EE + 255) / 256, 256, 0, stream>>>(dstp, degi);
  k_dinv<<<(NN + 255) / 256, 256, 0, stream>>>(degi, dinv);
  k_psum<<<NB, 256, 0, stream>>>(degi, bsum);
  k_bscan<<<1, 256, 0, stream>>>(bsum, boff);
  k_scan2<<<NB, 256, 0, stream>>>(degi, boff, rowptr, cursor);
  k_fill<<<(EE + 255) / 256, 256, 0, stream>>>(srcp, dstp, dinv, cursor, eidx, enrm);

  for (int l = 0; l < 2; ++l) {
    const float* g1Wl = g1_W + l * 9216;
    const float* g1bl = g1_b + l * 96;
    const float* g2Wl = g2_W + l * 9216;
    const float* g2bl = g2_b + l * 96;
    const float* gWl  = gcn_W + l * 65536;
    float* st = stats + l * 640;  // [bn0s1 32][bn0s2 32][bn1s1 256][bn1s2 256][bn2s1 32][bn2s2 32]
    float* rbl = rbias + l * 256;

    // gated conv 1 (packed VALU, swizzled xs) + bn0 stats
    k_gatedv<0><<<NGATED, 256, 0, stream>>>(P0, P1, g1Wl, g1bl,
                                            nullptr, nullptr, nullptr, nullptr, 0.0f,
                                            st + 0, st + 32);
    // fold bn0 into W (transposed bf16) + row bias, bn0-finalize inlined (1 launch)
    k_wprep<<<24, 256, 0, stream>>>(gWl, st + 0, st + 32, bn0_g + l * 32, bn0_b + l * 32,
                                    WT, rbl);
    // MFMA GEMM: P3 = P1 @ Wfold + rb
    k_gemmm<<<(NN + 127) / 128, 512, 0, stream>>>(P1, WT, rbl, P3);
    // GCN aggregation: CSR gather (self-loop included)
    k_gather<<<(NN + 3) / 4, 256, 0, stream>>>(P3, P2, rowptr, eidx, enrm, dinv);
    // bn1 stats
    k_colstats<<<512, 256, 0, stream>>>(P2, NN, st + 64, st + 320);
    // gated conv 2 (bn1-finalize inlined from raw stats) + bn2 stats
    k_gatedv<1><<<NGATED, 256, 0, stream>>>(P2, P1, g2Wl, g2bl,
                                            st + 64, st + 320,
                                            bn1_g + l * 256, bn1_b + l * 256,
                                            1.0f / (float)NN,
                                            st + 576, st + 608);
    // finalize: bn2 (inlined) + residual(x) + (relu in-place | t=7 slice)
    k_final<<<NN / 8, 256, 0, stream>>>(P0, P1, res_W + l * 1024, res_b + l * 32,
                                        st + 576, st + 608,
                                        bn2_g + l * 32, bn2_b + l * 32,
                                        xl, (l == 0) ? 0 : 1);
  }

  k_pool<<<(NN + 255) / 256, 256, 0, stream>>>(xl, graphs, cnt, sp, mxu);
  k_head<<<64, 128, 0, stream>>>(cnt, sp, mxu, out_W1, out_b1, out_W2, out_b2,
                                 out_W3, out_b3, outp);

  (void)in_sizes; (void)n_in; (void)out_size; (void)ws_size;
}

// Round 11
// 760.257 us; speedup vs baseline: 6.0718x; 1.0970x over previous
//
#include <hip/hip_runtime.h>
#include <hip/hip_bf16.h>

#define NN 50000
#define EE 400000
#define EPSF 1e-5f
#define NB 196   // (NN+255)/256
#define NGATED 1280   // 5 blocks/CU x 256 CU

typedef unsigned short u16;
typedef __attribute__((ext_vector_type(8))) short bf16x8;
typedef __attribute__((ext_vector_type(4))) float f32x4;
typedef __attribute__((ext_vector_type(2))) float f32x2;

__device__ __forceinline__ float b2f(u16 u) { return __uint_as_float(((unsigned)u) << 16); }
__device__ __forceinline__ u16 f2b(float f) {
  unsigned x = __float_as_uint(f);
  unsigned r = x + 0x7FFFu + ((x >> 16) & 1u);   // RNE
  return (u16)(r >> 16);
}
__device__ __forceinline__ unsigned pack2(float lo, float hi) {
  return (unsigned)f2b(lo) | ((unsigned)f2b(hi) << 16);
}
__device__ __forceinline__ f32x2 mk2(float a, float b) { f32x2 r; r.x = a; r.y = b; return r; }
__device__ __forceinline__ void gl16(const void* g, void* l) {
  __builtin_amdgcn_global_load_lds(
      (const __attribute__((address_space(1))) void*)g,
      (__attribute__((address_space(3))) void*)l, 16, 0, 0);
}

// ---------------------------------------------------------------- conv_in
__global__ __launch_bounds__(256) void k_convin(
    const float* __restrict__ X, u16* __restrict__ out,
    const float* __restrict__ Wi, const float* __restrict__ bi)
{
  __shared__ float xs[1024];
  __shared__ float wi[16 * 33];
  const int tid = threadIdx.x;
  for (int idx = tid; idx < 512; idx += 256) {
    int co = idx >> 4, ci = idx & 15;
    wi[ci * 33 + co] = Wi[idx];
  }
  const long xbase = (long)blockIdx.x * 1024;
  ((float4*)xs)[tid] = ((const float4*)(X + xbase))[tid];
  __syncthreads();
  const int nl = tid >> 5, c = tid & 31;
  float acc[8];
  {
    float bc = bi[c];
#pragma unroll
    for (int t = 0; t < 8; ++t) acc[t] = bc;
  }
  const float* xrow = xs + (nl << 7);
  for (int ci = 0; ci < 16; ++ci) {
    float w = wi[ci * 33 + c];
    float4 xa = *(const float4*)(xrow + ci * 8);
    float4 xb = *(const float4*)(xrow + ci * 8 + 4);
    acc[0] += xa.x * w; acc[1] += xa.y * w; acc[2] += xa.z * w; acc[3] += xa.w * w;
    acc[4] += xb.x * w; acc[5] += xb.y * w; acc[6] += xb.z * w; acc[7] += xb.w * w;
  }
  uint4 o;
  o.x = pack2(acc[0], acc[1]); o.y = pack2(acc[2], acc[3]);
  o.z = pack2(acc[4], acc[5]); o.w = pack2(acc[6], acc[7]);
  *(uint4*)(out + (long)blockIdx.x * 2048 + tid * 8) = o;
}

// ---------------------------------------------------------------- degree / dinv
__global__ void k_deg(const int* __restrict__ dst, int* __restrict__ degi)
{
  int e = blockIdx.x * 256 + threadIdx.x;
  if (e < EE) atomicAdd(degi + dst[e], 1);
}
__global__ void k_dinv(const int* __restrict__ degi, float* __restrict__ dinv)
{
  int n = blockIdx.x * 256 + threadIdx.x;
  if (n < NN) dinv[n] = rsqrtf((float)degi[n] + 1.0f);
}

// ---------------------------------------------------------------- CSR build
__global__ __launch_bounds__(256) void k_psum(const int* __restrict__ degi,
                                              int* __restrict__ bsum)
{
  __shared__ int red[4];
  const int tid = threadIdx.x;
  int i = blockIdx.x * 256 + tid;
  int v = (i < NN) ? degi[i] : 0;
#pragma unroll
  for (int d = 32; d >= 1; d >>= 1) v += __shfl_down(v, d);
  if ((tid & 63) == 0) red[tid >> 6] = v;
  __syncthreads();
  if (tid == 0) bsum[blockIdx.x] = red[0] + red[1] + red[2] + red[3];
}

__global__ __launch_bounds__(256) void k_bscan(const int* __restrict__ bsum,
                                               int* __restrict__ boff)
{
  __shared__ int wsum[4];
  const int tid = threadIdx.x, lane = tid & 63, wv = tid >> 6;
  int v = (tid < NB) ? bsum[tid] : 0;
  int s = v;
#pragma unroll
  for (int d = 1; d < 64; d <<= 1) { int t = __shfl_up(s, d); if (lane >= d) s += t; }
  if (lane == 63) wsum[wv] = s;
  __syncthreads();
  int wo = 0;
  for (int w = 0; w < wv; ++w) wo += wsum[w];
  if (tid < NB) boff[tid] = wo + s - v;
}

__global__ __launch_bounds__(256) void k_scan2(const int* __restrict__ degi,
                                               const int* __restrict__ boff,
                                               int* __restrict__ rowptr,
                                               int* __restrict__ cursor)
{
  __shared__ int wsum[4];
  const int tid = threadIdx.x, lane = tid & 63, wv = tid >> 6;
  int i = blockIdx.x * 256 + tid;
  int v = (i < NN) ? degi[i] : 0;
  int s = v;
#pragma unroll
  for (int d = 1; d < 64; d <<= 1) { int t = __shfl_up(s, d); if (lane >= d) s += t; }
  if (lane == 63) wsum[wv] = s;
  __syncthreads();
  int wo = 0;
  for (int w = 0; w < wv; ++w) wo += wsum[w];
  int excl = boff[blockIdx.x] + wo + (s - v);
  if (i < NN) { rowptr[i] = excl; cursor[i] = excl; }
  if (i == NN) rowptr[NN] = excl;
}

__global__ void k_fill(const int* __restrict__ src, const int* __restrict__ dst,
                       const float* __restrict__ dinv,
                       int* __restrict__ cursor,
                       int* __restrict__ eidx, float* __restrict__ enrm)
{
  int e = blockIdx.x * 256 + threadIdx.x;
  if (e < EE) {
    int s = src[e], d = dst[e];
    int p = atomicAdd(cursor + d, 1);
    eidx[p] = s;
    enrm[p] = dinv[s] * dinv[d];
  }
}

// ---------------------------------------------------------------- GCN gather (bf16 in, bf16 out)
__global__ __launch_bounds__(256) void k_gather(
    const u16* __restrict__ hw, u16* __restrict__ out,
    const int* __restrict__ rowptr, const int* __restrict__ eidx,
    const float* __restrict__ enrm, const float* __restrict__ dinv)
{
  const int wid = (blockIdx.x << 2) + (threadIdx.x >> 6);
  if (wid >= NN) return;
  const int lane = threadIdx.x & 63;
  const int c0 = lane << 2;
  float a0, a1, a2, a3;
  {
    float d2 = dinv[wid]; d2 *= d2;
    uint2 v = *(const uint2*)(hw + (long)wid * 256 + c0);
    a0 = d2 * b2f((u16)(v.x & 0xFFFF)); a1 = d2 * b2f((u16)(v.x >> 16));
    a2 = d2 * b2f((u16)(v.y & 0xFFFF)); a3 = d2 * b2f((u16)(v.y >> 16));
  }
  int p = rowptr[wid];
  const int end = rowptr[wid + 1];
  for (; p + 1 < end; p += 2) {
    int s0 = eidx[p], s1 = eidx[p + 1];
    float n0 = enrm[p], n1 = enrm[p + 1];
    uint2 v0 = *(const uint2*)(hw + (long)s0 * 256 + c0);
    uint2 v1 = *(const uint2*)(hw + (long)s1 * 256 + c0);
    a0 += n0 * b2f((u16)(v0.x & 0xFFFF)) + n1 * b2f((u16)(v1.x & 0xFFFF));
    a1 += n0 * b2f((u16)(v0.x >> 16))    + n1 * b2f((u16)(v1.x >> 16));
    a2 += n0 * b2f((u16)(v0.y & 0xFFFF)) + n1 * b2f((u16)(v1.y & 0xFFFF));
    a3 += n0 * b2f((u16)(v0.y >> 16))    + n1 * b2f((u16)(v1.y >> 16));
  }
  if (p < end) {
    int s0 = eidx[p];
    float n0 = enrm[p];
    uint2 v0 = *(const uint2*)(hw + (long)s0 * 256 + c0);
    a0 += n0 * b2f((u16)(v0.x & 0xFFFF));
    a1 += n0 * b2f((u16)(v0.x >> 16));
    a2 += n0 * b2f((u16)(v0.y & 0xFFFF));
    a3 += n0 * b2f((u16)(v0.y >> 16));
  }
  uint2 o; o.x = pack2(a0, a1); o.y = pack2(a2, a3);
  *(uint2*)(out + (long)wid * 256 + c0) = o;
}

// ---------------------------------------------------------------- gated conv (forced v_pk_fma_f32 + async prefetch)
// out(bf16) = relu(P * sigmoid(Q) + R); k=3 pad=1 over t; per-channel stats.
template<int FOLD>
__global__ __launch_bounds__(256) void k_gatedv(
    const u16* __restrict__ in, u16* __restrict__ out,
    const float* __restrict__ Wg,   // (3,32,32,3)
    const float* __restrict__ bg,   // (3,32)
    const float* __restrict__ s1in, const float* __restrict__ s2in,  // raw stats (256) or null
    const float* __restrict__ gin, const float* __restrict__ bin,    // bn gamma/beta (256) or null
    float cntInv,
    float* __restrict__ s1, float* __restrict__ s2)                  // [32] out stats
{
  __shared__ float xs[2048];            // 8 KB (swizzled 16B slots)
  __shared__ unsigned wlA[3072];        // (w0|w1<<16) [conv][ci][co], 12 KB
  __shared__ u16 wlB[3072];             // w2 bf16 [conv][ci][co], 6 KB
  __shared__ float red1[128], red2[128];
  const int tid = threadIdx.x;

  // stage weights once per block
  for (int idx = tid; idx < 3072; idx += 256) {
    int conv = idx >> 10;
    int r = idx & 1023;
    int co = r >> 5, ci = r & 31;
    const float* wsrc = Wg + (((conv << 5) + co) * 32 + ci) * 3;
    float w0 = wsrc[0], w1 = wsrc[1], w2 = wsrc[2];
    int di = (conv << 10) + (ci << 5) + co;
    wlA[di] = pack2(w0, w1);
    wlB[di] = f2b(w2);
  }

  const int nl = tid >> 5, c = tid & 31;
  const float bP = bg[c], bQ = bg[32 + c], bR = bg[64 + c];
  float affr[8], bffr[8];
  if (FOLD) {
    const int f0 = c << 3;
#pragma unroll
    for (int j = 0; j < 8; ++j) {
      float m = s1in[f0 + j] * cntInv;
      float var = s2in[f0 + j] * cntInv - m * m;
      float A = gin[f0 + j] / sqrtf(var + EPSF);
      affr[j] = A;
      bffr[j] = bin[f0 + j] - m * A;
    }
  }
  float gsum = 0.0f, gsq = 0.0f;
  const int swa = c >> 2;               // 0..7 swizzle key
  const int NT = NN / 8;

  long tile = blockIdx.x;
  uint4 v = *((const uint4*)(in + tile * 2048) + tid);   // prefetch tile 0

  for (; tile < NT; tile += gridDim.x) {
    __syncthreads();                    // xs free from previous tile (1st iter: weights done)
    {
      float d[8];
      d[0] = b2f((u16)(v.x & 0xFFFF)); d[1] = b2f((u16)(v.x >> 16));
      d[2] = b2f((u16)(v.y & 0xFFFF)); d[3] = b2f((u16)(v.y >> 16));
      d[4] = b2f((u16)(v.z & 0xFFFF)); d[5] = b2f((u16)(v.z >> 16));
      d[6] = b2f((u16)(v.w & 0xFFFF)); d[7] = b2f((u16)(v.w >> 16));
      if (FOLD) {
#pragma unroll
        for (int j = 0; j < 8; ++j) d[j] = fmaf(affr[j], d[j], bffr[j]);
      }
      float4* xw = (float4*)xs + (nl << 6);
      xw[(2 * c) ^ swa]     = make_float4(d[0], d[1], d[2], d[3]);
      xw[(2 * c + 1) ^ swa] = make_float4(d[4], d[5], d[6], d[7]);
    }
    __syncthreads();

    // issue next tile's global load early: latency hides under compute (T14)
    {
      long nxt = tile + gridDim.x;
      if (nxt < NT) v = *((const uint4*)(in + nxt * 2048) + tid);
    }

    f32x2 aP[4], aQ[4], aR[4];
#pragma unroll
    for (int j = 0; j < 4; ++j) {
      aP[j] = mk2(bP, bP); aQ[j] = mk2(bQ, bQ); aR[j] = mk2(bR, bR);
    }
    const float4* xrow = (const float4*)xs + (nl << 6);
    for (int ci = 0; ci < 32; ++ci) {
      const int a = ci >> 2;
      float4 xa = xrow[(2 * ci) ^ a];
      float4 xb = xrow[(2 * ci + 1) ^ a];
      f32x2 p0 = mk2(xa.x, xa.y), p1 = mk2(xa.z, xa.w);
      f32x2 p2 = mk2(xb.x, xb.y), p3 = mk2(xb.z, xb.w);
      f32x2 A0  = mk2(0.0f, xa.x);
      f32x2 s01 = mk2(xa.y, xa.z);
      f32x2 s23 = mk2(xa.w, xb.x);
      f32x2 s45 = mk2(xb.y, xb.z);
      f32x2 c3  = mk2(xb.w, 0.0f);
      const int wi = (ci << 5) + c;
#define CONV3(ACC, OFF)                                                        \
      {                                                                        \
        unsigned wA = wlA[wi + OFF];                                           \
        float w0 = __uint_as_float(wA << 16);                                  \
        float w1 = __uint_as_float(wA & 0xFFFF0000u);                          \
        float w2 = b2f(wlB[wi + OFF]);                                         \
        f32x2 W0 = mk2(w0, w0), W1 = mk2(w1, w1), W2 = mk2(w2, w2);            \
        ACC[0] = __builtin_elementwise_fma(s01, W2,                            \
                 __builtin_elementwise_fma(p0, W1,                             \
                 __builtin_elementwise_fma(A0, W0, ACC[0])));                  \
        ACC[1] = __builtin_elementwise_fma(s23, W2,                            \
                 __builtin_elementwise_fma(p1, W1,                             \
                 __builtin_elementwise_fma(s01, W0, ACC[1])));                 \
        ACC[2] = __builtin_elementwise_fma(s45, W2,                            \
                 __builtin_elementwise_fma(p2, W1,                             \
                 __builtin_elementwise_fma(s23, W0, ACC[2])));                 \
        ACC[3] = __builtin_elementwise_fma(c3, W2,                             \
                 __builtin_elementwise_fma(p3, W1,                             \
                 __builtin_elementwise_fma(s45, W0, ACC[3])));                 \
      }
      CONV3(aP, 0)
      CONV3(aQ, 1024)
      CONV3(aR, 2048)
#undef CONV3
    }
    float hv[8];
#pragma unroll
    for (int j = 0; j < 4; ++j) {
#pragma unroll
      for (int h2 = 0; h2 < 2; ++h2) {
        float pp = h2 ? aP[j].y : aP[j].x;
        float qq = h2 ? aQ[j].y : aQ[j].x;
        float rr = h2 ? aR[j].y : aR[j].x;
        float q = __builtin_amdgcn_rcpf(1.0f + __expf(-qq));
        float h = fmaxf(fmaf(pp, q, rr), 0.0f);
        hv[j * 2 + h2] = h; gsum += h; gsq += h * h;
      }
    }
    uint4 o;
    o.x = pack2(hv[0], hv[1]); o.y = pack2(hv[2], hv[3]);
    o.z = pack2(hv[4], hv[5]); o.w = pack2(hv[6], hv[7]);
    *(uint4*)(out + tile * 2048 + tid * 8) = o;
  }

  // one block-level stats reduction at the end
  float o1 = gsum + __shfl_down(gsum, 32);
  float o2 = gsq + __shfl_down(gsq, 32);
  int wave = tid >> 6, lane = tid & 63;
  if (lane < 32) { red1[wave * 32 + lane] = o1; red2[wave * 32 + lane] = o2; }
  __syncthreads();
  if (tid < 32) {
    float a = red1[tid] + red1[32 + tid] + red1[64 + tid] + red1[96 + tid];
    float b = red2[tid] + red2[32 + tid] + red2[64 + tid] + red2[96 + tid];
    atomicAdd(s1 + tid, a);
    atomicAdd(s2 + tid, b);
  }
}

// ---------------------------------------------------------------- W prep: fold bn0 into W (blocks 0..15)
// and compute row bias (blocks 16..23). bn0 finalize inlined from raw stats.
__global__ __launch_bounds__(256) void k_wprep(
    const float* __restrict__ W, const float* __restrict__ st1, const float* __restrict__ st2,
    const float* __restrict__ g0, const float* __restrict__ b0,
    u16* __restrict__ WT, float* __restrict__ rb)
{
  __shared__ float tile[64][68];
  __shared__ float affl[64];
  const int b = blockIdx.x;
  const int t = threadIdx.x;
  const float ci400 = 1.0f / 400000.0f;
  if (b < 16) {
    const int kx = (b & 3) * 64, jx = (b >> 2) * 64;
    if (t < 64) {
      int cch = (kx + t) >> 3;
      float m = st1[cch] * ci400;
      float var = st2[cch] * ci400 - m * m;
      affl[t] = g0[cch] / sqrtf(var + EPSF);
    }
    {
      int r = t >> 2, c0 = (t & 3) * 16;
#pragma unroll
      for (int i = 0; i < 4; ++i) {
        float4 v = *(const float4*)(W + (long)(kx + r) * 256 + jx + c0 + i * 4);
        tile[r][c0 + i * 4 + 0] = v.x; tile[r][c0 + i * 4 + 1] = v.y;
        tile[r][c0 + i * 4 + 2] = v.z; tile[r][c0 + i * 4 + 3] = v.w;
      }
    }
    __syncthreads();
    {
      int jl = t >> 2, k0 = (t & 3) * 16;
      u16 tmp[16];
#pragma unroll
      for (int kk = 0; kk < 16; ++kk)
        tmp[kk] = f2b(affl[k0 + kk] * tile[k0 + kk][jl]);
      u16* dst = WT + (long)(jx + jl) * 256 + kx + k0;
      *(uint4*)dst = ((uint4*)tmp)[0];
      *(uint4*)(dst + 8) = ((uint4*)tmp)[1];
    }
  } else {
    const int k0 = (b - 16) * 32;
    if (t < 32) {
      int cch = (k0 + t) >> 3;
      float m = st1[cch] * ci400;
      float var = st2[cch] * ci400 - m * m;
      float A = g0[cch] / sqrtf(var + EPSF);
      affl[t] = b0[cch] - m * A;   // bff
    }
    __syncthreads();
    float s = 0.0f;
    for (int kk = 0; kk < 32; ++kk) s += affl[kk] * W[(long)(k0 + kk) * 256 + t];
    atomicAdd(rb + t, s);
  }
}

// ---------------------------------------------------------------- MFMA GEMM: out = A @ WT^T + rb
__global__ __launch_bounds__(512, 2) void k_gemmm(
    const u16* __restrict__ A, const u16* __restrict__ WT,
    const float* __restrict__ rowbias, u16* __restrict__ Out)
{
  __shared__ u16 At[128 * 64];   // [row][k 64], 16B-chunk XOR-swizzled by row&7
  __shared__ u16 Bt[256 * 64];   // [j][k 64], same swizzle
  const int tid = threadIdx.x, l = tid & 63, w = tid >> 6;
  const long n0 = (long)blockIdx.x * 128;
  const int wr = (w & 1) << 6, wc = (w >> 1) << 6;
  f32x4 acc[4][4];
#pragma unroll
  for (int i = 0; i < 4; ++i)
#pragma unroll
    for (int j = 0; j < 4; ++j) acc[i][j] = (f32x4){0.f, 0.f, 0.f, 0.f};
  float rb[4];
#pragma unroll
  for (int cf = 0; cf < 4; ++cf) rb[cf] = rowbias[wc + (cf << 4) + (l & 15)];

  for (int kt = 0; kt < 4; ++kt) {
    if (kt) __syncthreads();
#pragma unroll
    for (int i = 0; i < 2; ++i) {
      int row = (w << 4) + (i << 3) + (l >> 3);
      int sg = (l & 7) ^ (row & 7);
      long n = n0 + row; if (n >= NN) n = NN - 1;
      gl16(A + n * 256 + kt * 64 + sg * 8, At + ((w << 4) + (i << 3)) * 64);
    }
#pragma unroll
    for (int i = 0; i < 4; ++i) {
      int row = (w << 5) + (i << 3) + (l >> 3);
      int sg = (l & 7) ^ (row & 7);
      gl16(WT + (long)row * 256 + kt * 64 + sg * 8, Bt + ((w << 5) + (i << 3)) * 64);
    }
    __syncthreads();
#pragma unroll
    for (int ks = 0; ks < 2; ++ks) {
      bf16x8 af[4], bf[4];
#pragma unroll
      for (int rf = 0; rf < 4; ++rf) {
        int row = wr + (rf << 4) + (l & 15);
        int slot = ((ks << 2) + (l >> 4)) ^ (row & 7);
        af[rf] = *(const bf16x8*)(At + row * 64 + (slot << 3));
      }
#pragma unroll
      for (int cf = 0; cf < 4; ++cf) {
        int row = wc + (cf << 4) + (l & 15);
        int slot = ((ks << 2) + (l >> 4)) ^ (row & 7);
        bf[cf] = *(const bf16x8*)(Bt + row * 64 + (slot << 3));
      }
#pragma unroll
      for (int rf = 0; rf < 4; ++rf)
#pragma unroll
        for (int cf = 0; cf < 4; ++cf)
          acc[rf][cf] = __builtin_amdgcn_mfma_f32_16x16x32_bf16(
              af[rf], bf[cf], acc[rf][cf], 0, 0, 0);
    }
  }
#pragma unroll
  for (int rf = 0; rf < 4; ++rf)
#pragma unroll
    for (int reg = 0; reg < 4; ++reg) {
      long n = n0 + wr + (rf << 4) + ((l >> 4) << 2) + reg;
      if (n < NN) {
        u16* orow = Out + n * 256 + wc + (l & 15);
#pragma unroll
        for (int cf = 0; cf < 4; ++cf)
          orow[cf << 4] = f2b(acc[rf][cf][reg] + rb[cf]);
      }
    }
}

// ---------------------------------------------------------------- per-feature col stats (bf16 in)
__global__ void k_colstats(const u16* __restrict__ x, int rows,
                           float* __restrict__ s1, float* __restrict__ s2)
{
  int f = threadIdx.x;
  float a = 0.0f, b = 0.0f;
  for (int n = blockIdx.x; n < rows; n += gridDim.x) {
    float v = b2f(x[(long)n * 256 + f]);
    a += v; b += v * v;
  }
  atomicAdd(s1 + f, a);
  atomicAdd(s2 + f, b);
}

// ---------------------------------------------------------------- finalize layer (bn2 finalize inlined)
__global__ __launch_bounds__(256) void k_final(
    u16* __restrict__ x, const u16* __restrict__ h2,
    const float* __restrict__ resW, const float* __restrict__ resb,
    const float* __restrict__ st1, const float* __restrict__ st2,
    const float* __restrict__ g2, const float* __restrict__ b2g,
    float* __restrict__ xl, int mode)
{
  __shared__ float xs[2048];
  __shared__ float wr[32 * 33];
  __shared__ float a2l[32], b2l[32];
  const int tid = threadIdx.x;
  for (int idx = tid; idx < 1024; idx += 256) {
    int co = idx >> 5, ci = idx & 31;
    wr[ci * 33 + co] = resW[idx];
  }
  if (tid < 32) {
    const float ci400 = 1.0f / 400000.0f;
    float m = st1[tid] * ci400;
    float var = st2[tid] * ci400 - m * m;
    float A = g2[tid] / sqrtf(var + EPSF);
    a2l[tid] = A;
    b2l[tid] = b2g[tid] - m * A;
  }
  const long base = (long)blockIdx.x * 2048;
  {
    const uint4 v = *((const uint4*)(x + base) + tid);
    float* d = xs + tid * 8;
    d[0] = b2f((u16)(v.x & 0xFFFF)); d[1] = b2f((u16)(v.x >> 16));
    d[2] = b2f((u16)(v.y & 0xFFFF)); d[3] = b2f((u16)(v.y >> 16));
    d[4] = b2f((u16)(v.z & 0xFFFF)); d[5] = b2f((u16)(v.z >> 16));
    d[6] = b2f((u16)(v.w & 0xFFFF)); d[7] = b2f((u16)(v.w >> 16));
  }
  __syncthreads();
  const int nl = tid >> 5, c = tid & 31;
  float r[8];
  {
    float rb = resb[c];
#pragma unroll
    for (int t = 0; t < 8; ++t) r[t] = rb;
  }
  const float* xrow = xs + (nl << 8);
  for (int ci = 0; ci < 32; ++ci) {
    float w = wr[ci * 33 + c];
    float4 xa = *(const float4*)(xrow + ci * 8);
    float4 xb = *(const float4*)(xrow + ci * 8 + 4);
    r[0] += xa.x * w; r[1] += xa.y * w; r[2] += xa.z * w; r[3] += xa.w * w;
    r[4] += xb.x * w; r[5] += xb.y * w; r[6] += xb.z * w; r[7] += xb.w * w;
  }
  float a2 = a2l[c], b2 = b2l[c];
  float hv[8];
  {
    const uint4 v = *((const uint4*)(h2 + base) + tid);
    hv[0] = b2f((u16)(v.x & 0xFFFF)); hv[1] = b2f((u16)(v.x >> 16));
    hv[2] = b2f((u16)(v.y & 0xFFFF)); hv[3] = b2f((u16)(v.y >> 16));
    hv[4] = b2f((u16)(v.z & 0xFFFF)); hv[5] = b2f((u16)(v.z >> 16));
    hv[6] = b2f((u16)(v.w & 0xFFFF)); hv[7] = b2f((u16)(v.w >> 16));
  }
  if (mode == 0) {
    uint4 o;
    float ov[8];
#pragma unroll
    for (int t = 0; t < 8; ++t) ov[t] = fmaxf(fmaf(a2, hv[t], b2) + r[t], 0.0f);
    o.x = pack2(ov[0], ov[1]); o.y = pack2(ov[2], ov[3]);
    o.z = pack2(ov[4], ov[5]); o.w = pack2(ov[6], ov[7]);
    *(uint4*)(x + base + tid * 8) = o;
  } else {
    float v = fmaf(a2, hv[7], b2) + r[7];
    int n = blockIdx.x * 8 + nl;
    xl[n * 32 + c] = v;
  }
}

// ---------------------------------------------------------------- pooling (sorted graphs)
__global__ __launch_bounds__(256) void k_pool(
    const float* __restrict__ xl, const int* __restrict__ graphs,
    int* __restrict__ cnt, float* __restrict__ sp, unsigned* __restrict__ mxu)
{
  __shared__ float lsum[64 * 32];
  __shared__ unsigned lmax[64 * 32];
  __shared__ int lcnt[64];
  const int tid = threadIdx.x;
  const int n0 = blockIdx.x << 8;
  const int nend = min(n0 + 256, NN);
  const int gmin = graphs[n0];
  const int gmax = graphs[nend - 1];
  const int span = gmax - gmin + 1;
  for (int i = tid; i < span * 32; i += 256) { lsum[i] = 0.0f; lmax[i] = 0u; }
  for (int i = tid; i < span; i += 256) lcnt[i] = 0;
  __syncthreads();
  const int c = tid & 31;
  const int nbase = n0 + ((tid >> 5) << 5);
  int curg = -1; float s = 0.0f; unsigned m = 0u; int cn = 0;
  for (int i = 0; i < 32; ++i) {
    int n = nbase + i;
    if (n >= nend) break;
    int g = graphs[n];
    float v = xl[(n << 5) + c];
    unsigned u = __float_as_uint(v);
    u = (u & 0x80000000u) ? ~u : (u | 0x80000000u);
    if (g != curg) {
      if (curg >= 0) {
        atomicAdd(&lsum[((curg - gmin) << 5) + c], s);
        atomicMax(&lmax[((curg - gmin) << 5) + c], m);
        if (c == 0) atomicAdd(&lcnt[curg - gmin], cn);
      }
      curg = g; s = v; m = u; cn = 1;
    } else {
      s += v; m = (u > m) ? u : m; cn++;
    }
  }
  if (curg >= 0) {
    atomicAdd(&lsum[((curg - gmin) << 5) + c], s);
    atomicMax(&lmax[((curg - gmin) << 5) + c], m);
    if (c == 0) atomicAdd(&lcnt[curg - gmin], cn);
  }
  __syncthreads();
  for (int i = tid; i < span * 32; i += 256) {
    atomicAdd(sp + (gmin << 5) + i, lsum[i]);
    atomicMax(mxu + (gmin << 5) + i, lmax[i]);
  }
  for (int i = tid; i < span; i += 256)
    if (lcnt[i]) atomicAdd(cnt + gmin + i, lcnt[i]);
}

// ---------------------------------------------------------------- MLP head
__global__ __launch_bounds__(128) void k_head(
    const int* __restrict__ cnt, const float* __restrict__ sp,
    const unsigned* __restrict__ mxu,
    const float* __restrict__ W1, const float* __restrict__ b1,
    const float* __restrict__ W2, const float* __restrict__ b2,
    const float* __restrict__ W3, const float* __restrict__ b3,
    float* __restrict__ out)
{
  __shared__ float xg[96], hh1[128], hh2[64];
  const int g = blockIdx.x, tid = threadIdx.x;
  if (tid < 32) {
    float s = sp[g * 32 + tid];
    int cn = cnt[g];
    float mean = s / fmaxf((float)cn, 1.0f);
    float mx = 0.0f;
    if (cn > 0) {
      unsigned u = mxu[g * 32 + tid];
      unsigned ub = (u & 0x80000000u) ? (u ^ 0x80000000u) : ~u;
      mx = __uint_as_float(ub);
    }
    xg[tid] = mean; xg[32 + tid] = mx; xg[64 + tid] = s;
  }
  __syncthreads();
  {
    float a = b1[tid];
    for (int k = 0; k < 96; ++k) a += xg[k] * W1[k * 128 + tid];
    hh1[tid] = fmaxf(a, 0.0f);
  }
  __syncthreads();
  if (tid < 64) {
    float a = b2[tid];
    for (int k = 0; k < 128; ++k) a += hh1[k] * W2[k * 64 + tid];
    hh2[tid] = fmaxf(a, 0.0f);
  }
  __syncthreads();
  if (tid < 64) {
    float p = hh2[tid] * W3[tid];
    for (int off = 32; off; off >>= 1) p += __shfl_down(p, off);
    if (tid == 0) out[g] = p + b3[0];
  }
}

// ================================================================ launch
extern "C" void kernel_launch(void* const* d_in, const int* in_sizes, int n_in,
                              void* d_out, int out_size, void* d_ws, size_t ws_size,
                              hipStream_t stream)
{
  const float* X       = (const float*)d_in[0];
  const int*   edge    = (const int*)d_in[1];
  const int*   graphs  = (const int*)d_in[2];
  const float* W_in    = (const float*)d_in[3];
  const float* b_in    = (const float*)d_in[4];
  const float* res_W   = (const float*)d_in[5];
  const float* res_b   = (const float*)d_in[6];
  const float* g1_W    = (const float*)d_in[7];
  const float* g1_b    = (const float*)d_in[8];
  const float* bn0_g   = (const float*)d_in[9];
  const float* bn0_b   = (const float*)d_in[10];
  const float* gcn_W   = (const float*)d_in[11];
  // d_in[12] = gcn_b: cancels in bn1 (per-feature shift removed by mean over axis 0)
  const float* bn1_g   = (const float*)d_in[13];
  const float* bn1_b   = (const float*)d_in[14];
  const float* g2_W    = (const float*)d_in[15];
  const float* g2_b    = (const float*)d_in[16];
  const float* bn2_g   = (const float*)d_in[17];
  const float* bn2_b   = (const float*)d_in[18];
  const float* out_W1  = (const float*)d_in[19];
  const float* out_b1  = (const float*)d_in[20];
  const float* out_W2  = (const float*)d_in[21];
  const float* out_b2  = (const float*)d_in[22];
  const float* out_W3  = (const float*)d_in[23];
  const float* out_b3  = (const float*)d_in[24];
  float* outp = (float*)d_out;

  const int* srcp = edge;
  const int* dstp = edge + EE;

  // ---- workspace layout (~113 MB) ----
  const long BIGE = (long)NN * 256;              // 12.8M elems
  u16*   P0   = (u16*)d_ws;                      // x bf16
  u16*   P1   = P0 + BIGE;                       // h1 / h2 bf16
  u16*   P2   = P1 + BIGE;                       // gather out bf16
  u16*   P3   = P2 + BIGE;                       // gemm out bf16
  u16*   WT   = P3 + BIGE;                       // 65536 u16
  float* xl   = (float*)(WT + 65536);            // N*32
  float* dinv = xl + (long)NN * 32;              // N
  int*   rowptr = (int*)(dinv + NN);             // N+1
  int*   cursor = rowptr + NN + 1;               // N
  int*   eidx   = cursor + NN;                   // E
  float* enrm   = (float*)(eidx + EE);           // E
  int*   bsum   = (int*)(enrm + EE);             // NB
  int*   boff   = bsum + NB;                     // NB
  int*   degi = boff + NB;                       // N      <- zero region start
  float* stats = (float*)(degi + NN);            // 1280
  int*   cnt  = (int*)(stats + 1280);            // 64
  float* sp   = (float*)(cnt + 64);              // 2048
  unsigned* mxu = (unsigned*)(sp + 2048);        // 2048
  float* rbias = (float*)(mxu + 2048);           // 512    <- zero region end

  const size_t zero_bytes = (size_t)(NN + 1280 + 64 + 2048 + 2048 + 512) * 4;
  hipMemsetAsync(degi, 0, zero_bytes, stream);

  k_convin<<<NN / 8, 256, 0, stream>>>(X, P0, W_in, b_in);
  k_deg<<<(EE + 255) / 256, 256, 0, stream>>>(dstp, degi);
  k_dinv<<<(NN + 255) / 256, 256, 0, stream>>>(degi, dinv);
  k_psum<<<NB, 256, 0, stream>>>(degi, bsum);
  k_bscan<<<1, 256, 0, stream>>>(bsum, boff);
  k_scan2<<<NB, 256, 0, stream>>>(degi, boff, rowptr, cursor);
  k_fill<<<(EE + 255) / 256, 256, 0, stream>>>(srcp, dstp, dinv, cursor, eidx, enrm);

  for (int l = 0; l < 2; ++l) {
    const float* g1Wl = g1_W + l * 9216;
    const float* g1bl = g1_b + l * 96;
    const float* g2Wl = g2_W + l * 9216;
    const float* g2bl = g2_b + l * 96;
    const float* gWl  = gcn_W + l * 65536;
    float* st = stats + l * 640;  // [bn0s1 32][bn0s2 32][bn1s1 256][bn1s2 256][bn2s1 32][bn2s2 32]
    float* rbl = rbias + l * 256;

    // gated conv 1 (pk-FMA VALU, prefetch) + bn0 stats
    k_gatedv<0><<<NGATED, 256, 0, stream>>>(P0, P1, g1Wl, g1bl,
                                            nullptr, nullptr, nullptr, nullptr, 0.0f,
                                            st + 0, st + 32);
    // fold bn0 into W (transposed bf16) + row bias, bn0-finalize inlined (1 launch)
    k_wprep<<<24, 256, 0, stream>>>(gWl, st + 0, st + 32, bn0_g + l * 32, bn0_b + l * 32,
                                    WT, rbl);
    // MFMA GEMM: P3 = P1 @ Wfold + rb
    k_gemmm<<<(NN + 127) / 128, 512, 0, stream>>>(P1, WT, rbl, P3);
    // GCN aggregation: CSR gather (self-loop included)
    k_gather<<<(NN + 3) / 4, 256, 0, stream>>>(P3, P2, rowptr, eidx, enrm, dinv);
    // bn1 stats
    k_colstats<<<512, 256, 0, stream>>>(P2, NN, st + 64, st + 320);
    // gated conv 2 (bn1-finalize inlined from raw stats) + bn2 stats
    k_gatedv<1><<<NGATED, 256, 0, stream>>>(P2, P1, g2Wl, g2bl,
                                            st + 64, st + 320,
                                            bn1_g + l * 256, bn1_b + l * 256,
                                            1.0f / (float)NN,
                                            st + 576, st + 608);
    // finalize: bn2 (inlined) + residual(x) + (relu in-place | t=7 slice)
    k_final<<<NN / 8, 256, 0, stream>>>(P0, P1, res_W + l * 1024, res_b + l * 32,
                                        st + 576, st + 608,
                                        bn2_g + l * 32, bn2_b + l * 32,
                                        xl, (l == 0) ? 0 : 1);
  }

  k_pool<<<(NN + 255) / 256, 256, 0, stream>>>(xl, graphs, cnt, sp, mxu);
  k_head<<<64, 128, 0, stream>>>(cnt, sp, mxu, out_W1, out_b1, out_W2, out_b2,
                                 out_W3, out_b3, outp);

  (void)in_sizes; (void)n_in; (void)out_size; (void)ws_size;
}

// Round 12
// 679.399 us; speedup vs baseline: 6.7945x; 1.1190x over previous
//
#include <hip/hip_runtime.h>
#include <hip/hip_bf16.h>

#define NN 50000
#define EE 400000
#define EPSF 1e-5f
#define NB 196   // (NN+255)/256
#define NGATED 1280   // 5 blocks/CU x 256 CU

typedef unsigned short u16;
typedef __attribute__((ext_vector_type(8))) short bf16x8;
typedef __attribute__((ext_vector_type(4))) float f32x4;
typedef __attribute__((ext_vector_type(2))) float f32x2;

__device__ __forceinline__ float b2f(u16 u) { return __uint_as_float(((unsigned)u) << 16); }
__device__ __forceinline__ u16 f2b(float f) {
  unsigned x = __float_as_uint(f);
  unsigned r = x + 0x7FFFu + ((x >> 16) & 1u);   // RNE
  return (u16)(r >> 16);
}
__device__ __forceinline__ unsigned pack2(float lo, float hi) {
  return (unsigned)f2b(lo) | ((unsigned)f2b(hi) << 16);
}
__device__ __forceinline__ f32x2 mk2(float a, float b) { f32x2 r; r.x = a; r.y = b; return r; }
__device__ __forceinline__ void gl16(const void* g, void* l) {
  __builtin_amdgcn_global_load_lds(
      (const __attribute__((address_space(1))) void*)g,
      (__attribute__((address_space(3))) void*)l, 16, 0, 0);
}

// ---------------------------------------------------------------- conv_in
__global__ __launch_bounds__(256) void k_convin(
    const float* __restrict__ X, u16* __restrict__ out,
    const float* __restrict__ Wi, const float* __restrict__ bi)
{
  __shared__ float xs[1024];
  __shared__ float wi[16 * 33];
  const int tid = threadIdx.x;
  for (int idx = tid; idx < 512; idx += 256) {
    int co = idx >> 4, ci = idx & 15;
    wi[ci * 33 + co] = Wi[idx];
  }
  const long xbase = (long)blockIdx.x * 1024;
  ((float4*)xs)[tid] = ((const float4*)(X + xbase))[tid];
  __syncthreads();
  const int nl = tid >> 5, c = tid & 31;
  float acc[8];
  {
    float bc = bi[c];
#pragma unroll
    for (int t = 0; t < 8; ++t) acc[t] = bc;
  }
  const float* xrow = xs + (nl << 7);
  for (int ci = 0; ci < 16; ++ci) {
    float w = wi[ci * 33 + c];
    float4 xa = *(const float4*)(xrow + ci * 8);
    float4 xb = *(const float4*)(xrow + ci * 8 + 4);
    acc[0] += xa.x * w; acc[1] += xa.y * w; acc[2] += xa.z * w; acc[3] += xa.w * w;
    acc[4] += xb.x * w; acc[5] += xb.y * w; acc[6] += xb.z * w; acc[7] += xb.w * w;
  }
  uint4 o;
  o.x = pack2(acc[0], acc[1]); o.y = pack2(acc[2], acc[3]);
  o.z = pack2(acc[4], acc[5]); o.w = pack2(acc[6], acc[7]);
  *(uint4*)(out + (long)blockIdx.x * 2048 + tid * 8) = o;
}

// ---------------------------------------------------------------- degree / dinv
__global__ void k_deg(const int* __restrict__ dst, int* __restrict__ degi)
{
  int e = blockIdx.x * 256 + threadIdx.x;
  if (e < EE) atomicAdd(degi + dst[e], 1);
}
__global__ void k_dinv(const int* __restrict__ degi, float* __restrict__ dinv)
{
  int n = blockIdx.x * 256 + threadIdx.x;
  if (n < NN) dinv[n] = rsqrtf((float)degi[n] + 1.0f);
}

// ---------------------------------------------------------------- CSR build
__global__ __launch_bounds__(256) void k_psum(const int* __restrict__ degi,
                                              int* __restrict__ bsum)
{
  __shared__ int red[4];
  const int tid = threadIdx.x;
  int i = blockIdx.x * 256 + tid;
  int v = (i < NN) ? degi[i] : 0;
#pragma unroll
  for (int d = 32; d >= 1; d >>= 1) v += __shfl_down(v, d);
  if ((tid & 63) == 0) red[tid >> 6] = v;
  __syncthreads();
  if (tid == 0) bsum[blockIdx.x] = red[0] + red[1] + red[2] + red[3];
}

__global__ __launch_bounds__(256) void k_bscan(const int* __restrict__ bsum,
                                               int* __restrict__ boff)
{
  __shared__ int wsum[4];
  const int tid = threadIdx.x, lane = tid & 63, wv = tid >> 6;
  int v = (tid < NB) ? bsum[tid] : 0;
  int s = v;
#pragma unroll
  for (int d = 1; d < 64; d <<= 1) { int t = __shfl_up(s, d); if (lane >= d) s += t; }
  if (lane == 63) wsum[wv] = s;
  __syncthreads();
  int wo = 0;
  for (int w = 0; w < wv; ++w) wo += wsum[w];
  if (tid < NB) boff[tid] = wo + s - v;
}

__global__ __launch_bounds__(256) void k_scan2(const int* __restrict__ degi,
                                               const int* __restrict__ boff,
                                               int* __restrict__ rowptr,
                                               int* __restrict__ cursor)
{
  __shared__ int wsum[4];
  const int tid = threadIdx.x, lane = tid & 63, wv = tid >> 6;
  int i = blockIdx.x * 256 + tid;
  int v = (i < NN) ? degi[i] : 0;
  int s = v;
#pragma unroll
  for (int d = 1; d < 64; d <<= 1) { int t = __shfl_up(s, d); if (lane >= d) s += t; }
  if (lane == 63) wsum[wv] = s;
  __syncthreads();
  int wo = 0;
  for (int w = 0; w < wv; ++w) wo += wsum[w];
  int excl = boff[blockIdx.x] + wo + (s - v);
  if (i < NN) { rowptr[i] = excl; cursor[i] = excl; }
  if (i == NN) rowptr[NN] = excl;
}

__global__ void k_fill(const int* __restrict__ src, const int* __restrict__ dst,
                       const float* __restrict__ dinv,
                       int* __restrict__ cursor,
                       int* __restrict__ eidx, float* __restrict__ enrm)
{
  int e = blockIdx.x * 256 + threadIdx.x;
  if (e < EE) {
    int s = src[e], d = dst[e];
    int p = atomicAdd(cursor + d, 1);
    eidx[p] = s;
    enrm[p] = dinv[s] * dinv[d];
  }
}

// ---------------------------------------------------------------- GCN gather (bf16 in, bf16 out, 4-wide)
__global__ __launch_bounds__(256) void k_gather(
    const u16* __restrict__ hw, u16* __restrict__ out,
    const int* __restrict__ rowptr, const int* __restrict__ eidx,
    const float* __restrict__ enrm, const float* __restrict__ dinv)
{
  const int wid = (blockIdx.x << 2) + (threadIdx.x >> 6);
  if (wid >= NN) return;
  const int lane = threadIdx.x & 63;
  const int c0 = lane << 2;
  float a0, a1, a2, a3;
  {
    float d2 = dinv[wid]; d2 *= d2;
    uint2 v = *(const uint2*)(hw + (long)wid * 256 + c0);
    a0 = d2 * b2f((u16)(v.x & 0xFFFF)); a1 = d2 * b2f((u16)(v.x >> 16));
    a2 = d2 * b2f((u16)(v.y & 0xFFFF)); a3 = d2 * b2f((u16)(v.y >> 16));
  }
  int p = rowptr[wid];
  const int end = rowptr[wid + 1];
  for (; p + 3 < end; p += 4) {
    int s0 = eidx[p], s1 = eidx[p + 1], s2 = eidx[p + 2], s3 = eidx[p + 3];
    float n0 = enrm[p], n1 = enrm[p + 1], n2 = enrm[p + 2], n3 = enrm[p + 3];
    uint2 v0 = *(const uint2*)(hw + (long)s0 * 256 + c0);
    uint2 v1 = *(const uint2*)(hw + (long)s1 * 256 + c0);
    uint2 v2 = *(const uint2*)(hw + (long)s2 * 256 + c0);
    uint2 v3 = *(const uint2*)(hw + (long)s3 * 256 + c0);
    a0 += n0 * b2f((u16)(v0.x & 0xFFFF)) + n1 * b2f((u16)(v1.x & 0xFFFF))
        + n2 * b2f((u16)(v2.x & 0xFFFF)) + n3 * b2f((u16)(v3.x & 0xFFFF));
    a1 += n0 * b2f((u16)(v0.x >> 16))    + n1 * b2f((u16)(v1.x >> 16))
        + n2 * b2f((u16)(v2.x >> 16))    + n3 * b2f((u16)(v3.x >> 16));
    a2 += n0 * b2f((u16)(v0.y & 0xFFFF)) + n1 * b2f((u16)(v1.y & 0xFFFF))
        + n2 * b2f((u16)(v2.y & 0xFFFF)) + n3 * b2f((u16)(v3.y & 0xFFFF));
    a3 += n0 * b2f((u16)(v0.y >> 16))    + n1 * b2f((u16)(v1.y >> 16))
        + n2 * b2f((u16)(v2.y >> 16))    + n3 * b2f((u16)(v3.y >> 16));
  }
  for (; p < end; ++p) {
    int s0 = eidx[p];
    float n0 = enrm[p];
    uint2 v0 = *(const uint2*)(hw + (long)s0 * 256 + c0);
    a0 += n0 * b2f((u16)(v0.x & 0xFFFF));
    a1 += n0 * b2f((u16)(v0.x >> 16));
    a2 += n0 * b2f((u16)(v0.y & 0xFFFF));
    a3 += n0 * b2f((u16)(v0.y >> 16));
  }
  uint2 o; o.x = pack2(a0, a1); o.y = pack2(a2, a3);
  *(uint2*)(out + (long)wid * 256 + c0) = o;
}

// ---------------------------------------------------------------- gated conv (pk-FMA, packed weight reads)
// out(bf16) = relu(P * sigmoid(Q) + R); k=3 pad=1 over t; per-channel stats.
template<int FOLD>
__global__ __launch_bounds__(256) void k_gatedv(
    const u16* __restrict__ in, u16* __restrict__ out,
    const float* __restrict__ Wg,   // (3,32,32,3)
    const float* __restrict__ bg,   // (3,32)
    const float* __restrict__ s1in, const float* __restrict__ s2in,  // raw stats (256) or null
    const float* __restrict__ gin, const float* __restrict__ bin,    // bn gamma/beta (256) or null
    float cntInv,
    float* __restrict__ s1, float* __restrict__ s2)                  // [32] out stats
{
  __shared__ float xs[2048];            // 8 KB (swizzled 16B slots)
  __shared__ uint4 wl4[1024];           // [ci][co] {Pw01,Qw01,Rw01,Pw2|Qw2<<16}, 16 KB
  __shared__ u16 wl2[1024];             // Rw2 bf16, 2 KB
  __shared__ float red1[128], red2[128];
  const int tid = threadIdx.x;

  // stage weights once per block (packed)
  for (int idx = tid; idx < 1024; idx += 256) {
    int co = idx >> 5, ci = idx & 31;
    const float* pw = Wg + co * 96 + ci * 3;          // P
    const float* qw = pw + 3072;                      // Q
    const float* rw = pw + 6144;                      // R
    uint4 wv;
    wv.x = pack2(pw[0], pw[1]);
    wv.y = pack2(qw[0], qw[1]);
    wv.z = pack2(rw[0], rw[1]);
    wv.w = pack2(pw[2], qw[2]);
    int di = (ci << 5) + co;
    wl4[di] = wv;
    wl2[di] = f2b(rw[2]);
  }

  const int nl = tid >> 5, c = tid & 31;
  const float bP = bg[c], bQ = bg[32 + c], bR = bg[64 + c];
  float affr[8], bffr[8];
  if (FOLD) {
    const int f0 = c << 3;
#pragma unroll
    for (int j = 0; j < 8; ++j) {
      float m = s1in[f0 + j] * cntInv;
      float var = s2in[f0 + j] * cntInv - m * m;
      float A = gin[f0 + j] / sqrtf(var + EPSF);
      affr[j] = A;
      bffr[j] = bin[f0 + j] - m * A;
    }
  }
  float gsum = 0.0f, gsq = 0.0f;
  const int swa = c >> 2;               // 0..7 swizzle key
  const int NT = NN / 8;

  long tile = blockIdx.x;
  uint4 v = *((const uint4*)(in + tile * 2048) + tid);   // prefetch tile 0

  for (; tile < NT; tile += gridDim.x) {
    __syncthreads();                    // xs free from previous tile (1st iter: weights done)
    {
      float d[8];
      d[0] = b2f((u16)(v.x & 0xFFFF)); d[1] = b2f((u16)(v.x >> 16));
      d[2] = b2f((u16)(v.y & 0xFFFF)); d[3] = b2f((u16)(v.y >> 16));
      d[4] = b2f((u16)(v.z & 0xFFFF)); d[5] = b2f((u16)(v.z >> 16));
      d[6] = b2f((u16)(v.w & 0xFFFF)); d[7] = b2f((u16)(v.w >> 16));
      if (FOLD) {
#pragma unroll
        for (int j = 0; j < 8; ++j) d[j] = fmaf(affr[j], d[j], bffr[j]);
      }
      float4* xw = (float4*)xs + (nl << 6);
      xw[(2 * c) ^ swa]     = make_float4(d[0], d[1], d[2], d[3]);
      xw[(2 * c + 1) ^ swa] = make_float4(d[4], d[5], d[6], d[7]);
    }
    __syncthreads();

    // issue next tile's global load early: latency hides under compute (T14)
    {
      long nxt = tile + gridDim.x;
      if (nxt < NT) v = *((const uint4*)(in + nxt * 2048) + tid);
    }

    f32x2 aP[4], aQ[4], aR[4];
#pragma unroll
    for (int j = 0; j < 4; ++j) {
      aP[j] = mk2(bP, bP); aQ[j] = mk2(bQ, bQ); aR[j] = mk2(bR, bR);
    }
    const float4* xrow = (const float4*)xs + (nl << 6);
    for (int ci = 0; ci < 32; ++ci) {
      const int a = ci >> 2;
      float4 xa = xrow[(2 * ci) ^ a];
      float4 xb = xrow[(2 * ci + 1) ^ a];
      f32x2 p0 = mk2(xa.x, xa.y), p1 = mk2(xa.z, xa.w);
      f32x2 p2 = mk2(xb.x, xb.y), p3 = mk2(xb.z, xb.w);
      f32x2 A0  = mk2(0.0f, xa.x);
      f32x2 s01 = mk2(xa.y, xa.z);
      f32x2 s23 = mk2(xa.w, xb.x);
      f32x2 s45 = mk2(xb.y, xb.z);
      f32x2 c3  = mk2(xb.w, 0.0f);
      const int wi = (ci << 5) + c;
      const uint4 wA = wl4[wi];
      const float rw2 = b2f(wl2[wi]);
#define CONV3(ACC, W01, W2F)                                                   \
      {                                                                        \
        float w0 = __uint_as_float((W01) << 16);                               \
        float w1 = __uint_as_float((W01) & 0xFFFF0000u);                       \
        float w2 = (W2F);                                                      \
        f32x2 W0 = mk2(w0, w0), W1 = mk2(w1, w1), W2 = mk2(w2, w2);            \
        ACC[0] = __builtin_elementwise_fma(s01, W2,                            \
                 __builtin_elementwise_fma(p0, W1,                             \
                 __builtin_elementwise_fma(A0, W0, ACC[0])));                  \
        ACC[1] = __builtin_elementwise_fma(s23, W2,                            \
                 __builtin_elementwise_fma(p1, W1,                             \
                 __builtin_elementwise_fma(s01, W0, ACC[1])));                 \
        ACC[2] = __builtin_elementwise_fma(s45, W2,                            \
                 __builtin_elementwise_fma(p2, W1,                             \
                 __builtin_elementwise_fma(s23, W0, ACC[2])));                 \
        ACC[3] = __builtin_elementwise_fma(c3, W2,                             \
                 __builtin_elementwise_fma(p3, W1,                             \
                 __builtin_elementwise_fma(s45, W0, ACC[3])));                 \
      }
      CONV3(aP, wA.x, __uint_as_float(wA.w << 16))
      CONV3(aQ, wA.y, __uint_as_float(wA.w & 0xFFFF0000u))
      CONV3(aR, wA.z, rw2)
#undef CONV3
    }
    float hv[8];
#pragma unroll
    for (int j = 0; j < 4; ++j) {
#pragma unroll
      for (int h2 = 0; h2 < 2; ++h2) {
        float pp = h2 ? aP[j].y : aP[j].x;
        float qq = h2 ? aQ[j].y : aQ[j].x;
        float rr = h2 ? aR[j].y : aR[j].x;
        float q = __builtin_amdgcn_rcpf(1.0f + __expf(-qq));
        float h = fmaxf(fmaf(pp, q, rr), 0.0f);
        hv[j * 2 + h2] = h; gsum += h; gsq += h * h;
      }
    }
    uint4 o;
    o.x = pack2(hv[0], hv[1]); o.y = pack2(hv[2], hv[3]);
    o.z = pack2(hv[4], hv[5]); o.w = pack2(hv[6], hv[7]);
    *(uint4*)(out + tile * 2048 + tid * 8) = o;
  }

  // one block-level stats reduction at the end
  float o1 = gsum + __shfl_down(gsum, 32);
  float o2 = gsq + __shfl_down(gsq, 32);
  int wave = tid >> 6, lane = tid & 63;
  if (lane < 32) { red1[wave * 32 + lane] = o1; red2[wave * 32 + lane] = o2; }
  __syncthreads();
  if (tid < 32) {
    float a = red1[tid] + red1[32 + tid] + red1[64 + tid] + red1[96 + tid];
    float b = red2[tid] + red2[32 + tid] + red2[64 + tid] + red2[96 + tid];
    atomicAdd(s1 + tid, a);
    atomicAdd(s2 + tid, b);
  }
}

// ---------------------------------------------------------------- W prep: fold bn0 into W (blocks 0..15)
// and compute row bias (blocks 16..23). bn0 finalize inlined from raw stats.
__global__ __launch_bounds__(256) void k_wprep(
    const float* __restrict__ W, const float* __restrict__ st1, const float* __restrict__ st2,
    const float* __restrict__ g0, const float* __restrict__ b0,
    u16* __restrict__ WT, float* __restrict__ rb)
{
  __shared__ float tile[64][68];
  __shared__ float affl[64];
  const int b = blockIdx.x;
  const int t = threadIdx.x;
  const float ci400 = 1.0f / 400000.0f;
  if (b < 16) {
    const int kx = (b & 3) * 64, jx = (b >> 2) * 64;
    if (t < 64) {
      int cch = (kx + t) >> 3;
      float m = st1[cch] * ci400;
      float var = st2[cch] * ci400 - m * m;
      affl[t] = g0[cch] / sqrtf(var + EPSF);
    }
    {
      int r = t >> 2, c0 = (t & 3) * 16;
#pragma unroll
      for (int i = 0; i < 4; ++i) {
        float4 v = *(const float4*)(W + (long)(kx + r) * 256 + jx + c0 + i * 4);
        tile[r][c0 + i * 4 + 0] = v.x; tile[r][c0 + i * 4 + 1] = v.y;
        tile[r][c0 + i * 4 + 2] = v.z; tile[r][c0 + i * 4 + 3] = v.w;
      }
    }
    __syncthreads();
    {
      int jl = t >> 2, k0 = (t & 3) * 16;
      u16 tmp[16];
#pragma unroll
      for (int kk = 0; kk < 16; ++kk)
        tmp[kk] = f2b(affl[k0 + kk] * tile[k0 + kk][jl]);
      u16* dst = WT + (long)(jx + jl) * 256 + kx + k0;
      *(uint4*)dst = ((uint4*)tmp)[0];
      *(uint4*)(dst + 8) = ((uint4*)tmp)[1];
    }
  } else {
    const int k0 = (b - 16) * 32;
    if (t < 32) {
      int cch = (k0 + t) >> 3;
      float m = st1[cch] * ci400;
      float var = st2[cch] * ci400 - m * m;
      float A = g0[cch] / sqrtf(var + EPSF);
      affl[t] = b0[cch] - m * A;   // bff
    }
    __syncthreads();
    float s = 0.0f;
    for (int kk = 0; kk < 32; ++kk) s += affl[kk] * W[(long)(k0 + kk) * 256 + t];
    atomicAdd(rb + t, s);
  }
}

// ---------------------------------------------------------------- MFMA GEMM: out = A @ WT^T + rb
__global__ __launch_bounds__(512, 2) void k_gemmm(
    const u16* __restrict__ A, const u16* __restrict__ WT,
    const float* __restrict__ rowbias, u16* __restrict__ Out)
{
  __shared__ u16 At[128 * 64];   // [row][k 64], 16B-chunk XOR-swizzled by row&7
  __shared__ u16 Bt[256 * 64];   // [j][k 64], same swizzle
  const int tid = threadIdx.x, l = tid & 63, w = tid >> 6;
  const long n0 = (long)blockIdx.x * 128;
  const int wr = (w & 1) << 6, wc = (w >> 1) << 6;
  f32x4 acc[4][4];
#pragma unroll
  for (int i = 0; i < 4; ++i)
#pragma unroll
    for (int j = 0; j < 4; ++j) acc[i][j] = (f32x4){0.f, 0.f, 0.f, 0.f};
  float rb[4];
#pragma unroll
  for (int cf = 0; cf < 4; ++cf) rb[cf] = rowbias[wc + (cf << 4) + (l & 15)];

  for (int kt = 0; kt < 4; ++kt) {
    if (kt) __syncthreads();
#pragma unroll
    for (int i = 0; i < 2; ++i) {
      int row = (w << 4) + (i << 3) + (l >> 3);
      int sg = (l & 7) ^ (row & 7);
      long n = n0 + row; if (n >= NN) n = NN - 1;
      gl16(A + n * 256 + kt * 64 + sg * 8, At + ((w << 4) + (i << 3)) * 64);
    }
#pragma unroll
    for (int i = 0; i < 4; ++i) {
      int row = (w << 5) + (i << 3) + (l >> 3);
      int sg = (l & 7) ^ (row & 7);
      gl16(WT + (long)row * 256 + kt * 64 + sg * 8, Bt + ((w << 5) + (i << 3)) * 64);
    }
    __syncthreads();
#pragma unroll
    for (int ks = 0; ks < 2; ++ks) {
      bf16x8 af[4], bf[4];
#pragma unroll
      for (int rf = 0; rf < 4; ++rf) {
        int row = wr + (rf << 4) + (l & 15);
        int slot = ((ks << 2) + (l >> 4)) ^ (row & 7);
        af[rf] = *(const bf16x8*)(At + row * 64 + (slot << 3));
      }
#pragma unroll
      for (int cf = 0; cf < 4; ++cf) {
        int row = wc + (cf << 4) + (l & 15);
        int slot = ((ks << 2) + (l >> 4)) ^ (row & 7);
        bf[cf] = *(const bf16x8*)(Bt + row * 64 + (slot << 3));
      }
#pragma unroll
      for (int rf = 0; rf < 4; ++rf)
#pragma unroll
        for (int cf = 0; cf < 4; ++cf)
          acc[rf][cf] = __builtin_amdgcn_mfma_f32_16x16x32_bf16(
              af[rf], bf[cf], acc[rf][cf], 0, 0, 0);
    }
  }
#pragma unroll
  for (int rf = 0; rf < 4; ++rf)
#pragma unroll
    for (int reg = 0; reg < 4; ++reg) {
      long n = n0 + wr + (rf << 4) + ((l >> 4) << 2) + reg;
      if (n < NN) {
        u16* orow = Out + n * 256 + wc + (l & 15);
#pragma unroll
        for (int cf = 0; cf < 4; ++cf)
          orow[cf << 4] = f2b(acc[rf][cf][reg] + rb[cf]);
      }
    }
}

// ---------------------------------------------------------------- per-feature col stats (vectorized bf16)
// 256 blocks; thread = (rofs = tid>>5, fgrp = tid&31); uint4 loads (8 features).
__global__ __launch_bounds__(256) void k_colstats(
    const u16* __restrict__ x, float* __restrict__ s1, float* __restrict__ s2)
{
  __shared__ float ls1[2048], ls2[2048];   // [rofs 8][feature 256]
  const int tid = threadIdx.x;
  const int fgrp = tid & 31, rofs = tid >> 5;
  float a[8], b[8];
#pragma unroll
  for (int j = 0; j < 8; ++j) { a[j] = 0.0f; b[j] = 0.0f; }
  for (int n = (blockIdx.x << 3) + rofs; n < NN; n += 2048) {
    uint4 v = *(const uint4*)(x + (long)n * 256 + (fgrp << 3));
    const unsigned uu[4] = {v.x, v.y, v.z, v.w};
#pragma unroll
    for (int k = 0; k < 4; ++k) {
      float lo = b2f((u16)(uu[k] & 0xFFFF));
      float hi = b2f((u16)(uu[k] >> 16));
      a[2 * k] += lo;     b[2 * k] += lo * lo;
      a[2 * k + 1] += hi; b[2 * k + 1] += hi * hi;
    }
  }
#pragma unroll
  for (int j = 0; j < 8; ++j) {
    ls1[rofs * 256 + (fgrp << 3) + j] = a[j];
    ls2[rofs * 256 + (fgrp << 3) + j] = b[j];
  }
  __syncthreads();
  {
    int f = tid;
    float sa = 0.0f, sb = 0.0f;
#pragma unroll
    for (int r = 0; r < 8; ++r) { sa += ls1[r * 256 + f]; sb += ls2[r * 256 + f]; }
    atomicAdd(s1 + f, sa);
    atomicAdd(s2 + f, sb);
  }
}

// ---------------------------------------------------------------- finalize layer (bn2 finalize inlined)
__global__ __launch_bounds__(256) void k_final(
    u16* __restrict__ x, const u16* __restrict__ h2,
    const float* __restrict__ resW, const float* __restrict__ resb,
    const float* __restrict__ st1, const float* __restrict__ st2,
    const float* __restrict__ g2, const float* __restrict__ b2g,
    float* __restrict__ xl, int mode)
{
  __shared__ float xs[2048];
  __shared__ float wr[32 * 33];
  __shared__ float a2l[32], b2l[32];
  const int tid = threadIdx.x;
  for (int idx = tid; idx < 1024; idx += 256) {
    int co = idx >> 5, ci = idx & 31;
    wr[ci * 33 + co] = resW[idx];
  }
  if (tid < 32) {
    const float ci400 = 1.0f / 400000.0f;
    float m = st1[tid] * ci400;
    float var = st2[tid] * ci400 - m * m;
    float A = g2[tid] / sqrtf(var + EPSF);
    a2l[tid] = A;
    b2l[tid] = b2g[tid] - m * A;
  }
  const long base = (long)blockIdx.x * 2048;
  {
    const uint4 v = *((const uint4*)(x + base) + tid);
    float* d = xs + tid * 8;
    d[0] = b2f((u16)(v.x & 0xFFFF)); d[1] = b2f((u16)(v.x >> 16));
    d[2] = b2f((u16)(v.y & 0xFFFF)); d[3] = b2f((u16)(v.y >> 16));
    d[4] = b2f((u16)(v.z & 0xFFFF)); d[5] = b2f((u16)(v.z >> 16));
    d[6] = b2f((u16)(v.w & 0xFFFF)); d[7] = b2f((u16)(v.w >> 16));
  }
  __syncthreads();
  const int nl = tid >> 5, c = tid & 31;
  float r[8];
  {
    float rb = resb[c];
#pragma unroll
    for (int t = 0; t < 8; ++t) r[t] = rb;
  }
  const float* xrow = xs + (nl << 8);
  for (int ci = 0; ci < 32; ++ci) {
    float w = wr[ci * 33 + c];
    float4 xa = *(const float4*)(xrow + ci * 8);
    float4 xb = *(const float4*)(xrow + ci * 8 + 4);
    r[0] += xa.x * w; r[1] += xa.y * w; r[2] += xa.z * w; r[3] += xa.w * w;
    r[4] += xb.x * w; r[5] += xb.y * w; r[6] += xb.z * w; r[7] += xb.w * w;
  }
  float a2 = a2l[c], b2 = b2l[c];
  float hv[8];
  {
    const uint4 v = *((const uint4*)(h2 + base) + tid);
    hv[0] = b2f((u16)(v.x & 0xFFFF)); hv[1] = b2f((u16)(v.x >> 16));
    hv[2] = b2f((u16)(v.y & 0xFFFF)); hv[3] = b2f((u16)(v.y >> 16));
    hv[4] = b2f((u16)(v.z & 0xFFFF)); hv[5] = b2f((u16)(v.z >> 16));
    hv[6] = b2f((u16)(v.w & 0xFFFF)); hv[7] = b2f((u16)(v.w >> 16));
  }
  if (mode == 0) {
    uint4 o;
    float ov[8];
#pragma unroll
    for (int t = 0; t < 8; ++t) ov[t] = fmaxf(fmaf(a2, hv[t], b2) + r[t], 0.0f);
    o.x = pack2(ov[0], ov[1]); o.y = pack2(ov[2], ov[3]);
    o.z = pack2(ov[4], ov[5]); o.w = pack2(ov[6], ov[7]);
    *(uint4*)(x + base + tid * 8) = o;
  } else {
    float v = fmaf(a2, hv[7], b2) + r[7];
    int n = blockIdx.x * 8 + nl;
    xl[n * 32 + c] = v;
  }
}

// ---------------------------------------------------------------- pooling (sorted graphs)
__global__ __launch_bounds__(256) void k_pool(
    const float* __restrict__ xl, const int* __restrict__ graphs,
    int* __restrict__ cnt, float* __restrict__ sp, unsigned* __restrict__ mxu)
{
  __shared__ float lsum[64 * 32];
  __shared__ unsigned lmax[64 * 32];
  __shared__ int lcnt[64];
  const int tid = threadIdx.x;
  const int n0 = blockIdx.x << 8;
  const int nend = min(n0 + 256, NN);
  const int gmin = graphs[n0];
  const int gmax = graphs[nend - 1];
  const int span = gmax - gmin + 1;
  for (int i = tid; i < span * 32; i += 256) { lsum[i] = 0.0f; lmax[i] = 0u; }
  for (int i = tid; i < span; i += 256) lcnt[i] = 0;
  __syncthreads();
  const int c = tid & 31;
  const int nbase = n0 + ((tid >> 5) << 5);
  int curg = -1; float s = 0.0f; unsigned m = 0u; int cn = 0;
  for (int i = 0; i < 32; ++i) {
    int n = nbase + i;
    if (n >= nend) break;
    int g = graphs[n];
    float v = xl[(n << 5) + c];
    unsigned u = __float_as_uint(v);
    u = (u & 0x80000000u) ? ~u : (u | 0x80000000u);
    if (g != curg) {
      if (curg >= 0) {
        atomicAdd(&lsum[((curg - gmin) << 5) + c], s);
        atomicMax(&lmax[((curg - gmin) << 5) + c], m);
        if (c == 0) atomicAdd(&lcnt[curg - gmin], cn);
      }
      curg = g; s = v; m = u; cn = 1;
    } else {
      s += v; m = (u > m) ? u : m; cn++;
    }
  }
  if (curg >= 0) {
    atomicAdd(&lsum[((curg - gmin) << 5) + c], s);
    atomicMax(&lmax[((curg - gmin) << 5) + c], m);
    if (c == 0) atomicAdd(&lcnt[curg - gmin], cn);
  }
  __syncthreads();
  for (int i = tid; i < span * 32; i += 256) {
    atomicAdd(sp + (gmin << 5) + i, lsum[i]);
    atomicMax(mxu + (gmin << 5) + i, lmax[i]);
  }
  for (int i = tid; i < span; i += 256)
    if (lcnt[i]) atomicAdd(cnt + gmin + i, lcnt[i]);
}

// ---------------------------------------------------------------- MLP head
__global__ __launch_bounds__(128) void k_head(
    const int* __restrict__ cnt, const float* __restrict__ sp,
    const unsigned* __restrict__ mxu,
    const float* __restrict__ W1, const float* __restrict__ b1,
    const float* __restrict__ W2, const float* __restrict__ b2,
    const float* __restrict__ W3, const float* __restrict__ b3,
    float* __restrict__ out)
{
  __shared__ float xg[96], hh1[128], hh2[64];
  const int g = blockIdx.x, tid = threadIdx.x;
  if (tid < 32) {
    float s = sp[g * 32 + tid];
    int cn = cnt[g];
    float mean = s / fmaxf((float)cn, 1.0f);
    float mx = 0.0f;
    if (cn > 0) {
      unsigned u = mxu[g * 32 + tid];
      unsigned ub = (u & 0x80000000u) ? (u ^ 0x80000000u) : ~u;
      mx = __uint_as_float(ub);
    }
    xg[tid] = mean; xg[32 + tid] = mx; xg[64 + tid] = s;
  }
  __syncthreads();
  {
    float a = b1[tid];
    for (int k = 0; k < 96; ++k) a += xg[k] * W1[k * 128 + tid];
    hh1[tid] = fmaxf(a, 0.0f);
  }
  __syncthreads();
  if (tid < 64) {
    float a = b2[tid];
    for (int k = 0; k < 128; ++k) a += hh1[k] * W2[k * 64 + tid];
    hh2[tid] = fmaxf(a, 0.0f);
  }
  __syncthreads();
  if (tid < 64) {
    float p = hh2[tid] * W3[tid];
    for (int off = 32; off; off >>= 1) p += __shfl_down(p, off);
    if (tid == 0) out[g] = p + b3[0];
  }
}

// ================================================================ launch
extern "C" void kernel_launch(void* const* d_in, const int* in_sizes, int n_in,
                              void* d_out, int out_size, void* d_ws, size_t ws_size,
                              hipStream_t stream)
{
  const float* X       = (const float*)d_in[0];
  const int*   edge    = (const int*)d_in[1];
  const int*   graphs  = (const int*)d_in[2];
  const float* W_in    = (const float*)d_in[3];
  const float* b_in    = (const float*)d_in[4];
  const float* res_W   = (const float*)d_in[5];
  const float* res_b   = (const float*)d_in[6];
  const float* g1_W    = (const float*)d_in[7];
  const float* g1_b    = (const float*)d_in[8];
  const float* bn0_g   = (const float*)d_in[9];
  const float* bn0_b   = (const float*)d_in[10];
  const float* gcn_W   = (const float*)d_in[11];
  // d_in[12] = gcn_b: cancels in bn1 (per-feature shift removed by mean over axis 0)
  const float* bn1_g   = (const float*)d_in[13];
  const float* bn1_b   = (const float*)d_in[14];
  const float* g2_W    = (const float*)d_in[15];
  const float* g2_b    = (const float*)d_in[16];
  const float* bn2_g   = (const float*)d_in[17];
  const float* bn2_b   = (const float*)d_in[18];
  const float* out_W1  = (const float*)d_in[19];
  const float* out_b1  = (const float*)d_in[20];
  const float* out_W2  = (const float*)d_in[21];
  const float* out_b2  = (const float*)d_in[22];
  const float* out_W3  = (const float*)d_in[23];
  const float* out_b3  = (const float*)d_in[24];
  float* outp = (float*)d_out;

  const int* srcp = edge;
  const int* dstp = edge + EE;

  // ---- workspace layout (~113 MB) ----
  const long BIGE = (long)NN * 256;              // 12.8M elems
  u16*   P0   = (u16*)d_ws;                      // x bf16
  u16*   P1   = P0 + BIGE;                       // h1 / h2 bf16
  u16*   P2   = P1 + BIGE;                       // gather out bf16
  u16*   P3   = P2 + BIGE;                       // gemm out bf16
  u16*   WT   = P3 + BIGE;                       // 65536 u16
  float* xl   = (float*)(WT + 65536);            // N*32
  float* dinv = xl + (long)NN * 32;              // N
  int*   rowptr = (int*)(dinv + NN);             // N+1
  int*   cursor = rowptr + NN + 1;               // N
  int*   eidx   = cursor + NN;                   // E
  float* enrm   = (float*)(eidx + EE);           // E
  int*   bsum   = (int*)(enrm + EE);             // NB
  int*   boff   = bsum + NB;                     // NB
  int*   degi = boff + NB;                       // N      <- zero region start
  float* stats = (float*)(degi + NN);            // 1280
  int*   cnt  = (int*)(stats + 1280);            // 64
  float* sp   = (float*)(cnt + 64);              // 2048
  unsigned* mxu = (unsigned*)(sp + 2048);        // 2048
  float* rbias = (float*)(mxu + 2048);           // 512    <- zero region end

  const size_t zero_bytes = (size_t)(NN + 1280 + 64 + 2048 + 2048 + 512) * 4;
  hipMemsetAsync(degi, 0, zero_bytes, stream);

  k_convin<<<NN / 8, 256, 0, stream>>>(X, P0, W_in, b_in);
  k_deg<<<(EE + 255) / 256, 256, 0, stream>>>(dstp, degi);
  k_dinv<<<(NN + 255) / 256, 256, 0, stream>>>(degi, dinv);
  k_psum<<<NB, 256, 0, stream>>>(degi, bsum);
  k_bscan<<<1, 256, 0, stream>>>(bsum, boff);
  k_scan2<<<NB, 256, 0, stream>>>(degi, boff, rowptr, cursor);
  k_fill<<<(EE + 255) / 256, 256, 0, stream>>>(srcp, dstp, dinv, cursor, eidx, enrm);

  for (int l = 0; l < 2; ++l) {
    const float* g1Wl = g1_W + l * 9216;
    const float* g1bl = g1_b + l * 96;
    const float* g2Wl = g2_W + l * 9216;
    const float* g2bl = g2_b + l * 96;
    const float* gWl  = gcn_W + l * 65536;
    float* st = stats + l * 640;  // [bn0s1 32][bn0s2 32][bn1s1 256][bn1s2 256][bn2s1 32][bn2s2 32]
    float* rbl = rbias + l * 256;

    // gated conv 1 (pk-FMA VALU, packed weights, prefetch) + bn0 stats
    k_gatedv<0><<<NGATED, 256, 0, stream>>>(P0, P1, g1Wl, g1bl,
                                            nullptr, nullptr, nullptr, nullptr, 0.0f,
                                            st + 0, st + 32);
    // fold bn0 into W (transposed bf16) + row bias, bn0-finalize inlined (1 launch)
    k_wprep<<<24, 256, 0, stream>>>(gWl, st + 0, st + 32, bn0_g + l * 32, bn0_b + l * 32,
                                    WT, rbl);
    // MFMA GEMM: P3 = P1 @ Wfold + rb
    k_gemmm<<<(NN + 127) / 128, 512, 0, stream>>>(P1, WT, rbl, P3);
    // GCN aggregation: CSR gather (self-loop included, 4-wide)
    k_gather<<<(NN + 3) / 4, 256, 0, stream>>>(P3, P2, rowptr, eidx, enrm, dinv);
    // bn1 stats (vectorized)
    k_colstats<<<256, 256, 0, stream>>>(P2, st + 64, st + 320);
    // gated conv 2 (bn1-finalize inlined from raw stats) + bn2 stats
    k_gatedv<1><<<NGATED, 256, 0, stream>>>(P2, P1, g2Wl, g2bl,
                                            st + 64, st + 320,
                                            bn1_g + l * 256, bn1_b + l * 256,
                                            1.0f / (float)NN,
                                            st + 576, st + 608);
    // finalize: bn2 (inlined) + residual(x) + (relu in-place | t=7 slice)
    k_final<<<NN / 8, 256, 0, stream>>>(P0, P1, res_W + l * 1024, res_b + l * 32,
                                        st + 576, st + 608,
                                        bn2_g + l * 32, bn2_b + l * 32,
                                        xl, (l == 0) ? 0 : 1);
  }

  k_pool<<<(NN + 255) / 256, 256, 0, stream>>>(xl, graphs, cnt, sp, mxu);
  k_head<<<64, 128, 0, stream>>>(cnt, sp, mxu, out_W1, out_b1, out_W2, out_b2,
                                 out_W3, out_b3, outp);

  (void)in_sizes; (void)n_in; (void)out_size; (void)ws_size;
}

// Round 13
// 670.992 us; speedup vs baseline: 6.8796x; 1.0125x over previous
//
#include <hip/hip_runtime.h>
#include <hip/hip_bf16.h>

#define NN 50000
#define EE 400000
#define EPSF 1e-5f
#define NB 196   // (NN+255)/256
#define NGATED 1536   // 6 blocks/CU x 256 CU

typedef unsigned short u16;
typedef __attribute__((ext_vector_type(8))) short bf16x8;
typedef __attribute__((ext_vector_type(4))) float f32x4;
typedef __attribute__((ext_vector_type(2))) float f32x2;

__device__ __forceinline__ float b2f(u16 u) { return __uint_as_float(((unsigned)u) << 16); }
__device__ __forceinline__ u16 f2b(float f) {
  unsigned x = __float_as_uint(f);
  unsigned r = x + 0x7FFFu + ((x >> 16) & 1u);   // RNE
  return (u16)(r >> 16);
}
__device__ __forceinline__ unsigned pack2(float lo, float hi) {
  return (unsigned)f2b(lo) | ((unsigned)f2b(hi) << 16);
}
__device__ __forceinline__ f32x2 mk2(float a, float b) { f32x2 r; r.x = a; r.y = b; return r; }
__device__ __forceinline__ void gl16(const void* g, void* l) {
  __builtin_amdgcn_global_load_lds(
      (const __attribute__((address_space(1))) void*)g,
      (__attribute__((address_space(3))) void*)l, 16, 0, 0);
}

// ---------------------------------------------------------------- conv_in
__global__ __launch_bounds__(256) void k_convin(
    const float* __restrict__ X, u16* __restrict__ out,
    const float* __restrict__ Wi, const float* __restrict__ bi)
{
  __shared__ float xs[1024];
  __shared__ float wi[16 * 33];
  const int tid = threadIdx.x;
  for (int idx = tid; idx < 512; idx += 256) {
    int co = idx >> 4, ci = idx & 15;
    wi[ci * 33 + co] = Wi[idx];
  }
  const long xbase = (long)blockIdx.x * 1024;
  ((float4*)xs)[tid] = ((const float4*)(X + xbase))[tid];
  __syncthreads();
  const int nl = tid >> 5, c = tid & 31;
  float acc[8];
  {
    float bc = bi[c];
#pragma unroll
    for (int t = 0; t < 8; ++t) acc[t] = bc;
  }
  const float* xrow = xs + (nl << 7);
  for (int ci = 0; ci < 16; ++ci) {
    float w = wi[ci * 33 + c];
    float4 xa = *(const float4*)(xrow + ci * 8);
    float4 xb = *(const float4*)(xrow + ci * 8 + 4);
    acc[0] += xa.x * w; acc[1] += xa.y * w; acc[2] += xa.z * w; acc[3] += xa.w * w;
    acc[4] += xb.x * w; acc[5] += xb.y * w; acc[6] += xb.z * w; acc[7] += xb.w * w;
  }
  uint4 o;
  o.x = pack2(acc[0], acc[1]); o.y = pack2(acc[2], acc[3]);
  o.z = pack2(acc[4], acc[5]); o.w = pack2(acc[6], acc[7]);
  *(uint4*)(out + (long)blockIdx.x * 2048 + tid * 8) = o;
}

// ---------------------------------------------------------------- degree / dinv
__global__ void k_deg(const int* __restrict__ dst, int* __restrict__ degi)
{
  int e = blockIdx.x * 256 + threadIdx.x;
  if (e < EE) atomicAdd(degi + dst[e], 1);
}
__global__ void k_dinv(const int* __restrict__ degi, float* __restrict__ dinv)
{
  int n = blockIdx.x * 256 + threadIdx.x;
  if (n < NN) dinv[n] = rsqrtf((float)degi[n] + 1.0f);
}

// ---------------------------------------------------------------- CSR build
__global__ __launch_bounds__(256) void k_psum(const int* __restrict__ degi,
                                              int* __restrict__ bsum)
{
  __shared__ int red[4];
  const int tid = threadIdx.x;
  int i = blockIdx.x * 256 + tid;
  int v = (i < NN) ? degi[i] : 0;
#pragma unroll
  for (int d = 32; d >= 1; d >>= 1) v += __shfl_down(v, d);
  if ((tid & 63) == 0) red[tid >> 6] = v;
  __syncthreads();
  if (tid == 0) bsum[blockIdx.x] = red[0] + red[1] + red[2] + red[3];
}

__global__ __launch_bounds__(256) void k_bscan(const int* __restrict__ bsum,
                                               int* __restrict__ boff)
{
  __shared__ int wsum[4];
  const int tid = threadIdx.x, lane = tid & 63, wv = tid >> 6;
  int v = (tid < NB) ? bsum[tid] : 0;
  int s = v;
#pragma unroll
  for (int d = 1; d < 64; d <<= 1) { int t = __shfl_up(s, d); if (lane >= d) s += t; }
  if (lane == 63) wsum[wv] = s;
  __syncthreads();
  int wo = 0;
  for (int w = 0; w < wv; ++w) wo += wsum[w];
  if (tid < NB) boff[tid] = wo + s - v;
}

__global__ __launch_bounds__(256) void k_scan2(const int* __restrict__ degi,
                                               const int* __restrict__ boff,
                                               int* __restrict__ rowptr,
                                               int* __restrict__ cursor)
{
  __shared__ int wsum[4];
  const int tid = threadIdx.x, lane = tid & 63, wv = tid >> 6;
  int i = blockIdx.x * 256 + tid;
  int v = (i < NN) ? degi[i] : 0;
  int s = v;
#pragma unroll
  for (int d = 1; d < 64; d <<= 1) { int t = __shfl_up(s, d); if (lane >= d) s += t; }
  if (lane == 63) wsum[wv] = s;
  __syncthreads();
  int wo = 0;
  for (int w = 0; w < wv; ++w) wo += wsum[w];
  int excl = boff[blockIdx.x] + wo + (s - v);
  if (i < NN) { rowptr[i] = excl; cursor[i] = excl; }
  if (i == NN) rowptr[NN] = excl;
}

__global__ void k_fill(const int* __restrict__ src, const int* __restrict__ dst,
                       const float* __restrict__ dinv,
                       int* __restrict__ cursor,
                       int* __restrict__ eidx, float* __restrict__ enrm)
{
  int e = blockIdx.x * 256 + threadIdx.x;
  if (e < EE) {
    int s = src[e], d = dst[e];
    int p = atomicAdd(cursor + d, 1);
    eidx[p] = s;
    enrm[p] = dinv[s] * dinv[d];
  }
}

// ---------------------------------------------------------------- GCN gather (bf16 in, bf16 out, 4-wide)
__global__ __launch_bounds__(256) void k_gather(
    const u16* __restrict__ hw, u16* __restrict__ out,
    const int* __restrict__ rowptr, const int* __restrict__ eidx,
    const float* __restrict__ enrm, const float* __restrict__ dinv)
{
  const int wid = (blockIdx.x << 2) + (threadIdx.x >> 6);
  if (wid >= NN) return;
  const int lane = threadIdx.x & 63;
  const int c0 = lane << 2;
  float a0, a1, a2, a3;
  {
    float d2 = dinv[wid]; d2 *= d2;
    uint2 v = *(const uint2*)(hw + (long)wid * 256 + c0);
    a0 = d2 * b2f((u16)(v.x & 0xFFFF)); a1 = d2 * b2f((u16)(v.x >> 16));
    a2 = d2 * b2f((u16)(v.y & 0xFFFF)); a3 = d2 * b2f((u16)(v.y >> 16));
  }
  int p = rowptr[wid];
  const int end = rowptr[wid + 1];
  for (; p + 3 < end; p += 4) {
    int s0 = eidx[p], s1 = eidx[p + 1], s2 = eidx[p + 2], s3 = eidx[p + 3];
    float n0 = enrm[p], n1 = enrm[p + 1], n2 = enrm[p + 2], n3 = enrm[p + 3];
    uint2 v0 = *(const uint2*)(hw + (long)s0 * 256 + c0);
    uint2 v1 = *(const uint2*)(hw + (long)s1 * 256 + c0);
    uint2 v2 = *(const uint2*)(hw + (long)s2 * 256 + c0);
    uint2 v3 = *(const uint2*)(hw + (long)s3 * 256 + c0);
    a0 += n0 * b2f((u16)(v0.x & 0xFFFF)) + n1 * b2f((u16)(v1.x & 0xFFFF))
        + n2 * b2f((u16)(v2.x & 0xFFFF)) + n3 * b2f((u16)(v3.x & 0xFFFF));
    a1 += n0 * b2f((u16)(v0.x >> 16))    + n1 * b2f((u16)(v1.x >> 16))
        + n2 * b2f((u16)(v2.x >> 16))    + n3 * b2f((u16)(v3.x >> 16));
    a2 += n0 * b2f((u16)(v0.y & 0xFFFF)) + n1 * b2f((u16)(v1.y & 0xFFFF))
        + n2 * b2f((u16)(v2.y & 0xFFFF)) + n3 * b2f((u16)(v3.y & 0xFFFF));
    a3 += n0 * b2f((u16)(v0.y >> 16))    + n1 * b2f((u16)(v1.y >> 16))
        + n2 * b2f((u16)(v2.y >> 16))    + n3 * b2f((u16)(v3.y >> 16));
  }
  for (; p < end; ++p) {
    int s0 = eidx[p];
    float n0 = enrm[p];
    uint2 v0 = *(const uint2*)(hw + (long)s0 * 256 + c0);
    a0 += n0 * b2f((u16)(v0.x & 0xFFFF));
    a1 += n0 * b2f((u16)(v0.x >> 16));
    a2 += n0 * b2f((u16)(v0.y & 0xFFFF));
    a3 += n0 * b2f((u16)(v0.y >> 16));
  }
  uint2 o; o.x = pack2(a0, a1); o.y = pack2(a2, a3);
  *(uint2*)(out + (long)wid * 256 + c0) = o;
}

// ---------------------------------------------------------------- gated conv (pk-FMA, 26KB LDS -> 6 blocks/CU)
// out(bf16) = relu(P * sigmoid(Q) + R); k=3 pad=1 over t; per-channel stats.
// wl2 storage is reused for the final block reduction (disjoint lifetimes).
template<int FOLD>
__global__ __launch_bounds__(256) void k_gatedv(
    const u16* __restrict__ in, u16* __restrict__ out,
    const float* __restrict__ Wg,   // (3,32,32,3)
    const float* __restrict__ bg,   // (3,32)
    const float* __restrict__ s1in, const float* __restrict__ s2in,  // raw stats (256) or null
    const float* __restrict__ gin, const float* __restrict__ bin,    // bn gamma/beta (256) or null
    float cntInv,
    float* __restrict__ s1, float* __restrict__ s2)                  // [32] out stats
{
  __shared__ float xs[2048];            // 8 KB (swizzled 16B slots)
  __shared__ uint4 wl4[1024];           // [ci][co] {Pw01,Qw01,Rw01,Pw2|Qw2<<16}, 16 KB
  __shared__ u16 wl2[1024];             // Rw2 bf16, 2 KB -- reused as red[] after loop
  const int tid = threadIdx.x;

  // stage weights once per block (packed)
  for (int idx = tid; idx < 1024; idx += 256) {
    int co = idx >> 5, ci = idx & 31;
    const float* pw = Wg + co * 96 + ci * 3;          // P
    const float* qw = pw + 3072;                      // Q
    const float* rw = pw + 6144;                      // R
    uint4 wv;
    wv.x = pack2(pw[0], pw[1]);
    wv.y = pack2(qw[0], qw[1]);
    wv.z = pack2(rw[0], rw[1]);
    wv.w = pack2(pw[2], qw[2]);
    int di = (ci << 5) + co;
    wl4[di] = wv;
    wl2[di] = f2b(rw[2]);
  }

  const int nl = tid >> 5, c = tid & 31;
  const float bP = bg[c], bQ = bg[32 + c], bR = bg[64 + c];
  float affr[8], bffr[8];
  if (FOLD) {
    const int f0 = c << 3;
#pragma unroll
    for (int j = 0; j < 8; ++j) {
      float m = s1in[f0 + j] * cntInv;
      float var = s2in[f0 + j] * cntInv - m * m;
      float A = gin[f0 + j] / sqrtf(var + EPSF);
      affr[j] = A;
      bffr[j] = bin[f0 + j] - m * A;
    }
  }
  float gsum = 0.0f, gsq = 0.0f;
  const int swa = c >> 2;               // 0..7 swizzle key
  const int NT = NN / 8;

  long tile = blockIdx.x;
  uint4 v = *((const uint4*)(in + tile * 2048) + tid);   // prefetch tile 0

  for (; tile < NT; tile += gridDim.x) {
    __syncthreads();                    // xs free from previous tile (1st iter: weights done)
    {
      float d[8];
      d[0] = b2f((u16)(v.x & 0xFFFF)); d[1] = b2f((u16)(v.x >> 16));
      d[2] = b2f((u16)(v.y & 0xFFFF)); d[3] = b2f((u16)(v.y >> 16));
      d[4] = b2f((u16)(v.z & 0xFFFF)); d[5] = b2f((u16)(v.z >> 16));
      d[6] = b2f((u16)(v.w & 0xFFFF)); d[7] = b2f((u16)(v.w >> 16));
      if (FOLD) {
#pragma unroll
        for (int j = 0; j < 8; ++j) d[j] = fmaf(affr[j], d[j], bffr[j]);
      }
      float4* xw = (float4*)xs + (nl << 6);
      xw[(2 * c) ^ swa]     = make_float4(d[0], d[1], d[2], d[3]);
      xw[(2 * c + 1) ^ swa] = make_float4(d[4], d[5], d[6], d[7]);
    }
    __syncthreads();

    // issue next tile's global load early: latency hides under compute (T14)
    {
      long nxt = tile + gridDim.x;
      if (nxt < NT) v = *((const uint4*)(in + nxt * 2048) + tid);
    }

    f32x2 aP[4], aQ[4], aR[4];
#pragma unroll
    for (int j = 0; j < 4; ++j) {
      aP[j] = mk2(bP, bP); aQ[j] = mk2(bQ, bQ); aR[j] = mk2(bR, bR);
    }
    const float4* xrow = (const float4*)xs + (nl << 6);
    for (int ci = 0; ci < 32; ++ci) {
      const int a = ci >> 2;
      float4 xa = xrow[(2 * ci) ^ a];
      float4 xb = xrow[(2 * ci + 1) ^ a];
      f32x2 p0 = mk2(xa.x, xa.y), p1 = mk2(xa.z, xa.w);
      f32x2 p2 = mk2(xb.x, xb.y), p3 = mk2(xb.z, xb.w);
      f32x2 A0  = mk2(0.0f, xa.x);
      f32x2 s01 = mk2(xa.y, xa.z);
      f32x2 s23 = mk2(xa.w, xb.x);
      f32x2 s45 = mk2(xb.y, xb.z);
      f32x2 c3  = mk2(xb.w, 0.0f);
      const int wi = (ci << 5) + c;
      const uint4 wA = wl4[wi];
      const float rw2 = b2f(wl2[wi]);
#define CONV3(ACC, W01, W2F)                                                   \
      {                                                                        \
        float w0 = __uint_as_float((W01) << 16);                               \
        float w1 = __uint_as_float((W01) & 0xFFFF0000u);                       \
        float w2 = (W2F);                                                      \
        f32x2 W0 = mk2(w0, w0), W1 = mk2(w1, w1), W2 = mk2(w2, w2);            \
        ACC[0] = __builtin_elementwise_fma(s01, W2,                            \
                 __builtin_elementwise_fma(p0, W1,                             \
                 __builtin_elementwise_fma(A0, W0, ACC[0])));                  \
        ACC[1] = __builtin_elementwise_fma(s23, W2,                            \
                 __builtin_elementwise_fma(p1, W1,                             \
                 __builtin_elementwise_fma(s01, W0, ACC[1])));                 \
        ACC[2] = __builtin_elementwise_fma(s45, W2,                            \
                 __builtin_elementwise_fma(p2, W1,                             \
                 __builtin_elementwise_fma(s23, W0, ACC[2])));                 \
        ACC[3] = __builtin_elementwise_fma(c3, W2,                             \
                 __builtin_elementwise_fma(p3, W1,                             \
                 __builtin_elementwise_fma(s45, W0, ACC[3])));                 \
      }
      CONV3(aP, wA.x, __uint_as_float(wA.w << 16))
      CONV3(aQ, wA.y, __uint_as_float(wA.w & 0xFFFF0000u))
      CONV3(aR, wA.z, rw2)
#undef CONV3
    }
    float hv[8];
#pragma unroll
    for (int j = 0; j < 4; ++j) {
#pragma unroll
      for (int h2 = 0; h2 < 2; ++h2) {
        float pp = h2 ? aP[j].y : aP[j].x;
        float qq = h2 ? aQ[j].y : aQ[j].x;
        float rr = h2 ? aR[j].y : aR[j].x;
        float q = __builtin_amdgcn_rcpf(1.0f + __expf(-qq));
        float h = fmaxf(fmaf(pp, q, rr), 0.0f);
        hv[j * 2 + h2] = h; gsum += h; gsq += h * h;
      }
    }
    uint4 o;
    o.x = pack2(hv[0], hv[1]); o.y = pack2(hv[2], hv[3]);
    o.z = pack2(hv[4], hv[5]); o.w = pack2(hv[6], hv[7]);
    *(uint4*)(out + tile * 2048 + tid * 8) = o;
  }

  // block-level stats reduction; reuse wl2 storage (done with weights)
  __syncthreads();
  float* red1 = (float*)wl2;            // 128 floats
  float* red2 = red1 + 128;             // 128 floats (1024 u16 = 2048 B total)
  float o1 = gsum + __shfl_down(gsum, 32);
  float o2 = gsq + __shfl_down(gsq, 32);
  int wave = tid >> 6, lane = tid & 63;
  if (lane < 32) { red1[wave * 32 + lane] = o1; red2[wave * 32 + lane] = o2; }
  __syncthreads();
  if (tid < 32) {
    float a = red1[tid] + red1[32 + tid] + red1[64 + tid] + red1[96 + tid];
    float b = red2[tid] + red2[32 + tid] + red2[64 + tid] + red2[96 + tid];
    atomicAdd(s1 + tid, a);
    atomicAdd(s2 + tid, b);
  }
}

// ---------------------------------------------------------------- W prep: fold bn0 into W (blocks 0..15)
// and compute row bias (blocks 16..23). bn0 finalize inlined from raw stats.
__global__ __launch_bounds__(256) void k_wprep(
    const float* __restrict__ W, const float* __restrict__ st1, const float* __restrict__ st2,
    const float* __restrict__ g0, const float* __restrict__ b0,
    u16* __restrict__ WT, float* __restrict__ rb)
{
  __shared__ float tile[64][68];
  __shared__ float affl[64];
  const int b = blockIdx.x;
  const int t = threadIdx.x;
  const float ci400 = 1.0f / 400000.0f;
  if (b < 16) {
    const int kx = (b & 3) * 64, jx = (b >> 2) * 64;
    if (t < 64) {
      int cch = (kx + t) >> 3;
      float m = st1[cch] * ci400;
      float var = st2[cch] * ci400 - m * m;
      affl[t] = g0[cch] / sqrtf(var + EPSF);
    }
    {
      int r = t >> 2, c0 = (t & 3) * 16;
#pragma unroll
      for (int i = 0; i < 4; ++i) {
        float4 v = *(const float4*)(W + (long)(kx + r) * 256 + jx + c0 + i * 4);
        tile[r][c0 + i * 4 + 0] = v.x; tile[r][c0 + i * 4 + 1] = v.y;
        tile[r][c0 + i * 4 + 2] = v.z; tile[r][c0 + i * 4 + 3] = v.w;
      }
    }
    __syncthreads();
    {
      int jl = t >> 2, k0 = (t & 3) * 16;
      u16 tmp[16];
#pragma unroll
      for (int kk = 0; kk < 16; ++kk)
        tmp[kk] = f2b(affl[k0 + kk] * tile[k0 + kk][jl]);
      u16* dst = WT + (long)(jx + jl) * 256 + kx + k0;
      *(uint4*)dst = ((uint4*)tmp)[0];
      *(uint4*)(dst + 8) = ((uint4*)tmp)[1];
    }
  } else {
    const int k0 = (b - 16) * 32;
    if (t < 32) {
      int cch = (k0 + t) >> 3;
      float m = st1[cch] * ci400;
      float var = st2[cch] * ci400 - m * m;
      float A = g0[cch] / sqrtf(var + EPSF);
      affl[t] = b0[cch] - m * A;   // bff
    }
    __syncthreads();
    float s = 0.0f;
    for (int kk = 0; kk < 32; ++kk) s += affl[kk] * W[(long)(k0 + kk) * 256 + t];
    atomicAdd(rb + t, s);
  }
}

// ---------------------------------------------------------------- MFMA GEMM: out = A @ WT^T + rb
__global__ __launch_bounds__(512, 2) void k_gemmm(
    const u16* __restrict__ A, const u16* __restrict__ WT,
    const float* __restrict__ rowbias, u16* __restrict__ Out)
{
  __shared__ u16 At[128 * 64];   // [row][k 64], 16B-chunk XOR-swizzled by row&7
  __shared__ u16 Bt[256 * 64];   // [j][k 64], same swizzle
  const int tid = threadIdx.x, l = tid & 63, w = tid >> 6;
  const long n0 = (long)blockIdx.x * 128;
  const int wr = (w & 1) << 6, wc = (w >> 1) << 6;
  f32x4 acc[4][4];
#pragma unroll
  for (int i = 0; i < 4; ++i)
#pragma unroll
    for (int j = 0; j < 4; ++j) acc[i][j] = (f32x4){0.f, 0.f, 0.f, 0.f};
  float rb[4];
#pragma unroll
  for (int cf = 0; cf < 4; ++cf) rb[cf] = rowbias[wc + (cf << 4) + (l & 15)];

  for (int kt = 0; kt < 4; ++kt) {
    if (kt) __syncthreads();
#pragma unroll
    for (int i = 0; i < 2; ++i) {
      int row = (w << 4) + (i << 3) + (l >> 3);
      int sg = (l & 7) ^ (row & 7);
      long n = n0 + row; if (n >= NN) n = NN - 1;
      gl16(A + n * 256 + kt * 64 + sg * 8, At + ((w << 4) + (i << 3)) * 64);
    }
#pragma unroll
    for (int i = 0; i < 4; ++i) {
      int row = (w << 5) + (i << 3) + (l >> 3);
      int sg = (l & 7) ^ (row & 7);
      gl16(WT + (long)row * 256 + kt * 64 + sg * 8, Bt + ((w << 5) + (i << 3)) * 64);
    }
    __syncthreads();
#pragma unroll
    for (int ks = 0; ks < 2; ++ks) {
      bf16x8 af[4], bf[4];
#pragma unroll
      for (int rf = 0; rf < 4; ++rf) {
        int row = wr + (rf << 4) + (l & 15);
        int slot = ((ks << 2) + (l >> 4)) ^ (row & 7);
        af[rf] = *(const bf16x8*)(At + row * 64 + (slot << 3));
      }
#pragma unroll
      for (int cf = 0; cf < 4; ++cf) {
        int row = wc + (cf << 4) + (l & 15);
        int slot = ((ks << 2) + (l >> 4)) ^ (row & 7);
        bf[cf] = *(const bf16x8*)(Bt + row * 64 + (slot << 3));
      }
#pragma unroll
      for (int rf = 0; rf < 4; ++rf)
#pragma unroll
        for (int cf = 0; cf < 4; ++cf)
          acc[rf][cf] = __builtin_amdgcn_mfma_f32_16x16x32_bf16(
              af[rf], bf[cf], acc[rf][cf], 0, 0, 0);
    }
  }
#pragma unroll
  for (int rf = 0; rf < 4; ++rf)
#pragma unroll
    for (int reg = 0; reg < 4; ++reg) {
      long n = n0 + wr + (rf << 4) + ((l >> 4) << 2) + reg;
      if (n < NN) {
        u16* orow = Out + n * 256 + wc + (l & 15);
#pragma unroll
        for (int cf = 0; cf < 4; ++cf)
          orow[cf << 4] = f2b(acc[rf][cf][reg] + rb[cf]);
      }
    }
}

// ---------------------------------------------------------------- per-feature col stats (vectorized bf16)
__global__ __launch_bounds__(256) void k_colstats(
    const u16* __restrict__ x, float* __restrict__ s1, float* __restrict__ s2)
{
  __shared__ float ls1[2048], ls2[2048];   // [rofs 8][feature 256]
  const int tid = threadIdx.x;
  const int fgrp = tid & 31, rofs = tid >> 5;
  float a[8], b[8];
#pragma unroll
  for (int j = 0; j < 8; ++j) { a[j] = 0.0f; b[j] = 0.0f; }
  for (int n = (blockIdx.x << 3) + rofs; n < NN; n += 2048) {
    uint4 v = *(const uint4*)(x + (long)n * 256 + (fgrp << 3));
    const unsigned uu[4] = {v.x, v.y, v.z, v.w};
#pragma unroll
    for (int k = 0; k < 4; ++k) {
      float lo = b2f((u16)(uu[k] & 0xFFFF));
      float hi = b2f((u16)(uu[k] >> 16));
      a[2 * k] += lo;     b[2 * k] += lo * lo;
      a[2 * k + 1] += hi; b[2 * k + 1] += hi * hi;
    }
  }
#pragma unroll
  for (int j = 0; j < 8; ++j) {
    ls1[rofs * 256 + (fgrp << 3) + j] = a[j];
    ls2[rofs * 256 + (fgrp << 3) + j] = b[j];
  }
  __syncthreads();
  {
    int f = tid;
    float sa = 0.0f, sb = 0.0f;
#pragma unroll
    for (int r = 0; r < 8; ++r) { sa += ls1[r * 256 + f]; sb += ls2[r * 256 + f]; }
    atomicAdd(s1 + f, sa);
    atomicAdd(s2 + f, sb);
  }
}

// ---------------------------------------------------------------- finalize layer (bn2 finalize inlined)
__global__ __launch_bounds__(256) void k_final(
    u16* __restrict__ x, const u16* __restrict__ h2,
    const float* __restrict__ resW, const float* __restrict__ resb,
    const float* __restrict__ st1, const float* __restrict__ st2,
    const float* __restrict__ g2, const float* __restrict__ b2g,
    float* __restrict__ xl, int mode)
{
  __shared__ float xs[2048];
  __shared__ float wr[32 * 33];
  __shared__ float a2l[32], b2l[32];
  const int tid = threadIdx.x;
  for (int idx = tid; idx < 1024; idx += 256) {
    int co = idx >> 5, ci = idx & 31;
    wr[ci * 33 + co] = resW[idx];
  }
  if (tid < 32) {
    const float ci400 = 1.0f / 400000.0f;
    float m = st1[tid] * ci400;
    float var = st2[tid] * ci400 - m * m;
    float A = g2[tid] / sqrtf(var + EPSF);
    a2l[tid] = A;
    b2l[tid] = b2g[tid] - m * A;
  }
  const long base = (long)blockIdx.x * 2048;
  {
    const uint4 v = *((const uint4*)(x + base) + tid);
    float* d = xs + tid * 8;
    d[0] = b2f((u16)(v.x & 0xFFFF)); d[1] = b2f((u16)(v.x >> 16));
    d[2] = b2f((u16)(v.y & 0xFFFF)); d[3] = b2f((u16)(v.y >> 16));
    d[4] = b2f((u16)(v.z & 0xFFFF)); d[5] = b2f((u16)(v.z >> 16));
    d[6] = b2f((u16)(v.w & 0xFFFF)); d[7] = b2f((u16)(v.w >> 16));
  }
  __syncthreads();
  const int nl = tid >> 5, c = tid & 31;
  float r[8];
  {
    float rb = resb[c];
#pragma unroll
    for (int t = 0; t < 8; ++t) r[t] = rb;
  }
  const float* xrow = xs + (nl << 8);
  for (int ci = 0; ci < 32; ++ci) {
    float w = wr[ci * 33 + c];
    float4 xa = *(const float4*)(xrow + ci * 8);
    float4 xb = *(const float4*)(xrow + ci * 8 + 4);
    r[0] += xa.x * w; r[1] += xa.y * w; r[2] += xa.z * w; r[3] += xa.w * w;
    r[4] += xb.x * w; r[5] += xb.y * w; r[6] += xb.z * w; r[7] += xb.w * w;
  }
  float a2 = a2l[c], b2 = b2l[c];
  float hv[8];
  {
    const uint4 v = *((const uint4*)(h2 + base) + tid);
    hv[0] = b2f((u16)(v.x & 0xFFFF)); hv[1] = b2f((u16)(v.x >> 16));
    hv[2] = b2f((u16)(v.y & 0xFFFF)); hv[3] = b2f((u16)(v.y >> 16));
    hv[4] = b2f((u16)(v.z & 0xFFFF)); hv[5] = b2f((u16)(v.z >> 16));
    hv[6] = b2f((u16)(v.w & 0xFFFF)); hv[7] = b2f((u16)(v.w >> 16));
  }
  if (mode == 0) {
    uint4 o;
    float ov[8];
#pragma unroll
    for (int t = 0; t < 8; ++t) ov[t] = fmaxf(fmaf(a2, hv[t], b2) + r[t], 0.0f);
    o.x = pack2(ov[0], ov[1]); o.y = pack2(ov[2], ov[3]);
    o.z = pack2(ov[4], ov[5]); o.w = pack2(ov[6], ov[7]);
    *(uint4*)(x + base + tid * 8) = o;
  } else {
    float v = fmaf(a2, hv[7], b2) + r[7];
    int n = blockIdx.x * 8 + nl;
    xl[n * 32 + c] = v;
  }
}

// ---------------------------------------------------------------- pooling (sorted graphs)
__global__ __launch_bounds__(256) void k_pool(
    const float* __restrict__ xl, const int* __restrict__ graphs,
    int* __restrict__ cnt, float* __restrict__ sp, unsigned* __restrict__ mxu)
{
  __shared__ float lsum[64 * 32];
  __shared__ unsigned lmax[64 * 32];
  __shared__ int lcnt[64];
  const int tid = threadIdx.x;
  const int n0 = blockIdx.x << 8;
  const int nend = min(n0 + 256, NN);
  const int gmin = graphs[n0];
  const int gmax = graphs[nend - 1];
  const int span = gmax - gmin + 1;
  for (int i = tid; i < span * 32; i += 256) { lsum[i] = 0.0f; lmax[i] = 0u; }
  for (int i = tid; i < span; i += 256) lcnt[i] = 0;
  __syncthreads();
  const int c = tid & 31;
  const int nbase = n0 + ((tid >> 5) << 5);
  int curg = -1; float s = 0.0f; unsigned m = 0u; int cn = 0;
  for (int i = 0; i < 32; ++i) {
    int n = nbase + i;
    if (n >= nend) break;
    int g = graphs[n];
    float v = xl[(n << 5) + c];
    unsigned u = __float_as_uint(v);
    u = (u & 0x80000000u) ? ~u : (u | 0x80000000u);
    if (g != curg) {
      if (curg >= 0) {
        atomicAdd(&lsum[((curg - gmin) << 5) + c], s);
        atomicMax(&lmax[((curg - gmin) << 5) + c], m);
        if (c == 0) atomicAdd(&lcnt[curg - gmin], cn);
      }
      curg = g; s = v; m = u; cn = 1;
    } else {
      s += v; m = (u > m) ? u : m; cn++;
    }
  }
  if (curg >= 0) {
    atomicAdd(&lsum[((curg - gmin) << 5) + c], s);
    atomicMax(&lmax[((curg - gmin) << 5) + c], m);
    if (c == 0) atomicAdd(&lcnt[curg - gmin], cn);
  }
  __syncthreads();
  for (int i = tid; i < span * 32; i += 256) {
    atomicAdd(sp + (gmin << 5) + i, lsum[i]);
    atomicMax(mxu + (gmin << 5) + i, lmax[i]);
  }
  for (int i = tid; i < span; i += 256)
    if (lcnt[i]) atomicAdd(cnt + gmin + i, lcnt[i]);
}

// ---------------------------------------------------------------- MLP head
__global__ __launch_bounds__(128) void k_head(
    const int* __restrict__ cnt, const float* __restrict__ sp,
    const unsigned* __restrict__ mxu,
    const float* __restrict__ W1, const float* __restrict__ b1,
    const float* __restrict__ W2, const float* __restrict__ b2,
    const float* __restrict__ W3, const float* __restrict__ b3,
    float* __restrict__ out)
{
  __shared__ float xg[96], hh1[128], hh2[64];
  const int g = blockIdx.x, tid = threadIdx.x;
  if (tid < 32) {
    float s = sp[g * 32 + tid];
    int cn = cnt[g];
    float mean = s / fmaxf((float)cn, 1.0f);
    float mx = 0.0f;
    if (cn > 0) {
      unsigned u = mxu[g * 32 + tid];
      unsigned ub = (u & 0x80000000u) ? (u ^ 0x80000000u) : ~u;
      mx = __uint_as_float(ub);
    }
    xg[tid] = mean; xg[32 + tid] = mx; xg[64 + tid] = s;
  }
  __syncthreads();
  {
    float a = b1[tid];
    for (int k = 0; k < 96; ++k) a += xg[k] * W1[k * 128 + tid];
    hh1[tid] = fmaxf(a, 0.0f);
  }
  __syncthreads();
  if (tid < 64) {
    float a = b2[tid];
    for (int k = 0; k < 128; ++k) a += hh1[k] * W2[k * 64 + tid];
    hh2[tid] = fmaxf(a, 0.0f);
  }
  __syncthreads();
  if (tid < 64) {
    float p = hh2[tid] * W3[tid];
    for (int off = 32; off; off >>= 1) p += __shfl_down(p, off);
    if (tid == 0) out[g] = p + b3[0];
  }
}

// ================================================================ launch
extern "C" void kernel_launch(void* const* d_in, const int* in_sizes, int n_in,
                              void* d_out, int out_size, void* d_ws, size_t ws_size,
                              hipStream_t stream)
{
  const float* X       = (const float*)d_in[0];
  const int*   edge    = (const int*)d_in[1];
  const int*   graphs  = (const int*)d_in[2];
  const float* W_in    = (const float*)d_in[3];
  const float* b_in    = (const float*)d_in[4];
  const float* res_W   = (const float*)d_in[5];
  const float* res_b   = (const float*)d_in[6];
  const float* g1_W    = (const float*)d_in[7];
  const float* g1_b    = (const float*)d_in[8];
  const float* bn0_g   = (const float*)d_in[9];
  const float* bn0_b   = (const float*)d_in[10];
  const float* gcn_W   = (const float*)d_in[11];
  // d_in[12] = gcn_b: cancels in bn1 (per-feature shift removed by mean over axis 0)
  const float* bn1_g   = (const float*)d_in[13];
  const float* bn1_b   = (const float*)d_in[14];
  const float* g2_W    = (const float*)d_in[15];
  const float* g2_b    = (const float*)d_in[16];
  const float* bn2_g   = (const float*)d_in[17];
  const float* bn2_b   = (const float*)d_in[18];
  const float* out_W1  = (const float*)d_in[19];
  const float* out_b1  = (const float*)d_in[20];
  const float* out_W2  = (const float*)d_in[21];
  const float* out_b2  = (const float*)d_in[22];
  const float* out_W3  = (const float*)d_in[23];
  const float* out_b3  = (const float*)d_in[24];
  float* outp = (float*)d_out;

  const int* srcp = edge;
  const int* dstp = edge + EE;

  // ---- workspace layout (~113 MB) ----
  const long BIGE = (long)NN * 256;              // 12.8M elems
  u16*   P0   = (u16*)d_ws;                      // x bf16
  u16*   P1   = P0 + BIGE;                       // h1 / h2 bf16
  u16*   P2   = P1 + BIGE;                       // gather out bf16
  u16*   P3   = P2 + BIGE;                       // gemm out bf16
  u16*   WT   = P3 + BIGE;                       // 65536 u16
  float* xl   = (float*)(WT + 65536);            // N*32
  float* dinv = xl + (long)NN * 32;              // N
  int*   rowptr = (int*)(dinv + NN);             // N+1
  int*   cursor = rowptr + NN + 1;               // N
  int*   eidx   = cursor + NN;                   // E
  float* enrm   = (float*)(eidx + EE);           // E
  int*   bsum   = (int*)(enrm + EE);             // NB
  int*   boff   = bsum + NB;                     // NB
  int*   degi = boff + NB;                       // N      <- zero region start
  float* stats = (float*)(degi + NN);            // 1280
  int*   cnt  = (int*)(stats + 1280);            // 64
  float* sp   = (float*)(cnt + 64);              // 2048
  unsigned* mxu = (unsigned*)(sp + 2048);        // 2048
  float* rbias = (float*)(mxu + 2048);           // 512    <- zero region end

  const size_t zero_bytes = (size_t)(NN + 1280 + 64 + 2048 + 2048 + 512) * 4;
  hipMemsetAsync(degi, 0, zero_bytes, stream);

  k_convin<<<NN / 8, 256, 0, stream>>>(X, P0, W_in, b_in);
  k_deg<<<(EE + 255) / 256, 256, 0, stream>>>(dstp, degi);
  k_dinv<<<(NN + 255) / 256, 256, 0, stream>>>(degi, dinv);
  k_psum<<<NB, 256, 0, stream>>>(degi, bsum);
  k_bscan<<<1, 256, 0, stream>>>(bsum, boff);
  k_scan2<<<NB, 256, 0, stream>>>(degi, boff, rowptr, cursor);
  k_fill<<<(EE + 255) / 256, 256, 0, stream>>>(srcp, dstp, dinv, cursor, eidx, enrm);

  for (int l = 0; l < 2; ++l) {
    const float* g1Wl = g1_W + l * 9216;
    const float* g1bl = g1_b + l * 96;
    const float* g2Wl = g2_W + l * 9216;
    const float* g2bl = g2_b + l * 96;
    const float* gWl  = gcn_W + l * 65536;
    float* st = stats + l * 640;  // [bn0s1 32][bn0s2 32][bn1s1 256][bn1s2 256][bn2s1 32][bn2s2 32]
    float* rbl = rbias + l * 256;

    // gated conv 1 (pk-FMA VALU, 6 blocks/CU) + bn0 stats
    k_gatedv<0><<<NGATED, 256, 0, stream>>>(P0, P1, g1Wl, g1bl,
                                            nullptr, nullptr, nullptr, nullptr, 0.0f,
                                            st + 0, st + 32);
    // fold bn0 into W (transposed bf16) + row bias, bn0-finalize inlined (1 launch)
    k_wprep<<<24, 256, 0, stream>>>(gWl, st + 0, st + 32, bn0_g + l * 32, bn0_b + l * 32,
                                    WT, rbl);
    // MFMA GEMM: P3 = P1 @ Wfold + rb
    k_gemmm<<<(NN + 127) / 128, 512, 0, stream>>>(P1, WT, rbl, P3);
    // GCN aggregation: CSR gather (self-loop included, 4-wide)
    k_gather<<<(NN + 3) / 4, 256, 0, stream>>>(P3, P2, rowptr, eidx, enrm, dinv);
    // bn1 stats (vectorized)
    k_colstats<<<256, 256, 0, stream>>>(P2, st + 64, st + 320);
    // gated conv 2 (bn1-finalize inlined from raw stats) + bn2 stats
    k_gatedv<1><<<NGATED, 256, 0, stream>>>(P2, P1, g2Wl, g2bl,
                                            st + 64, st + 320,
                                            bn1_g + l * 256, bn1_b + l * 256,
                                            1.0f / (float)NN,
                                            st + 576, st + 608);
    // finalize: bn2 (inlined) + residual(x) + (relu in-place | t=7 slice)
    k_final<<<NN / 8, 256, 0, stream>>>(P0, P1, res_W + l * 1024, res_b + l * 32,
                                        st + 576, st + 608,
                                        bn2_g + l * 32, bn2_b + l * 32,
                                        xl, (l == 0) ? 0 : 1);
  }

  k_pool<<<(NN + 255) / 256, 256, 0, stream>>>(xl, graphs, cnt, sp, mxu);
  k_head<<<64, 128, 0, stream>>>(cnt, sp, mxu, out_W1, out_b1, out_W2, out_b2,
                                 out_W3, out_b3, outp);

  (void)in_sizes; (void)n_in; (void)out_size; (void)ws_size;
}